// Round 11
// baseline (312.271 us; speedup 1.0000x reference)
//
#include <hip/hip_runtime.h>
#include <math.h>

// Problem constants
#define BN     16384
#define INC    128
#define CH     512
#define ED     6240
#define KN     512      // NUM_EMB
#define DIN    64
#define DH     64
#define DY     32
#define NCW    195      // ED/32 k-chunks for Wf2/embed packing
#define CHP    (CH + 8) // padded LDS row stride (halves)
#define NZWE   24       // We K-slices (3-pass -> ~24.4 work units each)
#define NZG    8        // G  K-slices (1-pass -> ~24.4 work units each)

// d_out layout (float32): dec[16384*32] | diff[1] | embed_ind[16384] | perplexity[1]
#define OUT_DEC   0
#define OUT_DIFF  (BN*DY)
#define OUT_IND   (BN*DY + 1)
#define OUT_PERP  (BN*DY + 1 + BN)

typedef _Float16 half8 __attribute__((ext_vector_type(8)));
typedef float    f32x4 __attribute__((ext_vector_type(4)));
#define MFMA16(a, b, c) __builtin_amdgcn_mfma_f32_16x16x32_f16(a, b, c, 0, 0, 0)

// Packed fragment-tile layout: element (row r within 16-row tile `tile`,
// k-dim index d) lives at ((tile*NC + d/32)*64 + ((d%32)/8)*16 + (r%16))*8 + d%8.
__device__ __forceinline__ size_t paddr(int tile, int NC, int c, int lane, int e) {
    return ((size_t)(tile * NC + c) * 64 + lane) * 8 + e;
}

// ---------------------------------------------------------------------------
// packall (R16): vectorized-store packers.
// Block ranges: [0,1560) splitwf2 | [..,4680) embt | [..,4808) s2bep |
// [..,5320) xpack | [..,5384) wfxpack | [..,5388) wx2pack.
// ---------------------------------------------------------------------------
__global__ __launch_bounds__(256) void packall_kernel(
        const float* __restrict__ x,
        const float* __restrict__ Wf1, const float* __restrict__ Wx1,
        const float* __restrict__ bf1, const float* __restrict__ bx1,
        const float* __restrict__ Wx2,
        const float* __restrict__ Wf2, const float* __restrict__ bf2,
        const float* __restrict__ embed,
        _Float16* __restrict__ XPs, _Float16* __restrict__ XPl,
        _Float16* __restrict__ WfxPs, _Float16* __restrict__ WfxPl,
        float* __restrict__ bfx,
        _Float16* __restrict__ Wx2Ps, _Float16* __restrict__ Wx2Pl,
        _Float16* __restrict__ WfPs, _Float16* __restrict__ WfPl,
        _Float16* __restrict__ EmPs, _Float16* __restrict__ EmPl,
        float* __restrict__ s2p, float* __restrict__ bep,
        float* __restrict__ w0) {
    __shared__ __align__(16) char smem[16384];
    int id = blockIdx.x;
    int t = threadIdx.x;
    if (id < 1560) {
        // ---- splitwf2: Wf2 -> packed hi/lo (half8 stores) + w0 partials ----
        int bx = id % NCW, by = id / NCW;       // by in [0,8)
        int jl = t >> 2, e8 = t & 3;
        int j = by * 64 + jl;
        int d0 = bx * 32 + e8 * 8;
        float4 v0 = *(const float4*)&Wf2[(size_t)j * ED + d0];
        float4 v1 = *(const float4*)&Wf2[(size_t)j * ED + d0 + 4];
        float4 b0 = *(const float4*)&bf2[d0];
        float4 b1 = *(const float4*)&bf2[d0 + 4];
        float vv[8] = {v0.x, v0.y, v0.z, v0.w, v1.x, v1.y, v1.z, v1.w};
        float bb[8] = {b0.x, b0.y, b0.z, b0.w, b1.x, b1.y, b1.z, b1.w};
        half8 hh, ll;
        float s = 0.f;
        #pragma unroll
        for (int e = 0; e < 8; ++e) {
            float v = vv[e];
            _Float16 hi = (_Float16)v;
            hh[e] = hi;
            ll[e] = (_Float16)(v - (float)hi);
            s = fmaf(v, bb[e], s);
        }
        size_t a = paddr(j >> 4, NCW, bx, e8 * 16 + (j & 15), 0);
        *(half8*)(WfPs + a) = hh;
        *(half8*)(WfPl + a) = ll;
        s += __shfl_xor(s, 1);
        s += __shfl_xor(s, 2);
        if (e8 == 0) atomicAdd(&w0[j], s);
    } else if (id < 4680) {
        // ---- embt: embed transpose+split (half8 stores) ----
        float (*tile)[33] = (float(*)[33])smem; // tile[di][ki]
        int sub = id - 1560;
        int bx = sub % NCW, by = sub / NCW;
        int dl = t >> 5, kl = t & 31;
        #pragma unroll
        for (int r = 0; r < 4; ++r)
            tile[dl + 8 * r][kl] = embed[(size_t)(bx * 32 + dl + 8 * r) * KN
                                         + by * 32 + kl];
        __syncthreads();
        if (t < 128) {
            int g = t >> 5, kl2 = t & 31;       // g: d-group 0..3
            int k = by * 32 + kl2;
            half8 hh, ll;
            #pragma unroll
            for (int e = 0; e < 8; ++e) {
                float v = tile[g * 8 + e][kl2];
                _Float16 hi = (_Float16)v;
                hh[e] = hi;
                ll[e] = (_Float16)(v - (float)hi);
            }
            size_t a = paddr(k >> 4, NCW, bx, g * 16 + (k & 15), 0);
            *(half8*)(EmPs + a) = hh;
            *(half8*)(EmPl + a) = ll;
        }
    } else if (id < 4808) {
        // ---- s2bep: deterministic s2/be partials (fixed-order, no atomics) ----
        float (*rs)[33] = (float(*)[33])smem;
        float (*rb)[33] = (float(*)[33])(smem + 8 * 33 * 4);
        int sub = id - 4680;
        int bx = sub % 16, by = sub / 16;
        int kl = t & 31, dl = t >> 5;
        int kb = bx * 32;
        int d0 = by * 780;
        float s = 0.f, b = 0.f;
        for (int d = d0 + dl; d < d0 + 780; d += 8) {
            float e = embed[(size_t)d * KN + kb + kl];
            s = fmaf(e, e, s);
            b = fmaf(bf2[d], e, b);
        }
        rs[dl][kl] = s; rb[dl][kl] = b;
        __syncthreads();
        if (t < 32) {
            float ss = 0.f, bb = 0.f;
            #pragma unroll
            for (int i = 0; i < 8; ++i) { ss += rs[i][t]; bb += rb[i][t]; }
            s2p[by * KN + kb + t] = ss;
            bep[by * KN + kb + t] = bb;
        }
    } else if (id < 5320) {
        // ---- xpack: x -> XPs/XPl ----
        float (*xt)[INC] = (float(*)[INC])smem;
        int m0 = (id - 4808) * 32;
        for (int i = t; i < 32 * (INC / 4); i += 256) {
            int row = i >> 5, c4 = (i & 31) << 2;
            *(float4*)&xt[row][c4] = *(const float4*)&x[(size_t)(m0 + row) * INC + c4];
        }
        __syncthreads();
        int ta = m0 >> 4;
        #pragma unroll
        for (int i = 0; i < 2; ++i) {
            int idx = t + 256 * i;
            int tile2 = idx >> 8;
            int c = (idx >> 6) & 3;
            int lane = idx & 63;
            int m = tile2 * 16 + (lane & 15);
            int d0 = c * 32 + ((lane >> 4) << 3);
            half8 hh, ll;
            #pragma unroll
            for (int e = 0; e < 8; ++e) {
                float v = xt[m][d0 + e];
                _Float16 hi = (_Float16)v;
                hh[e] = hi;
                ll[e] = (_Float16)(v - (float)hi);
            }
            *(half8*)(XPs + paddr(ta + tile2, 4, c, lane, 0)) = hh;
            *(half8*)(XPl + paddr(ta + tile2, 4, c, lane, 0)) = ll;
        }
    } else if (id < 5384) {
        // ---- wfxpack: fused Wf1|Wx1 cols + bfx ----
        int tile = id - 5320;
        for (int i = t; i < 2048; i += 256) {
            int c = i >> 9, lane = (i >> 3) & 63, e = i & 7;
            int n = tile * 16 + (lane & 15);
            int d = c * 32 + ((lane >> 4) << 3) + e;
            float v = (n < 512) ? Wf1[(size_t)d * CH + n] : Wx1[(size_t)d * CH + n - 512];
            _Float16 hi = (_Float16)v;
            size_t a = paddr(tile, 4, c, lane, e);
            WfxPs[a] = hi;
            WfxPl[a] = (_Float16)(v - (float)hi);
        }
        if (tile == 0)
            for (int j = t; j < 512; j += 256) { bfx[j] = bf1[j]; bfx[512 + j] = bx1[j]; }
    } else {
        // ---- wx2pack ----
        int tile = id - 5384;
        for (int i = t; i < 8192; i += 256) {
            int c = i >> 9, lane = (i >> 3) & 63, e = i & 7;
            int n = tile * 16 + (lane & 15);
            int d = c * 32 + ((lane >> 4) << 3) + e;
            float v = Wx2[(size_t)d * DIN + n];
            _Float16 hi = (_Float16)v;
            size_t a = paddr(tile, 16, c, lane, e);
            Wx2Ps[a] = hi;
            Wx2Pl[a] = (_Float16)(v - (float)hi);
        }
    }
}

// ---------------------------------------------------------------------------
// Merged precompute GEMMs (R19): grid (4,4,32), block 512 -> 512 blocks =
// 2 blocks/CU. Work-balanced z-split: z<24 -> We slice (3-pass); z>=24 ->
// G slice (1-pass). Partials: (24+8) MB = 32 MB.
// ---------------------------------------------------------------------------
__global__ __launch_bounds__(512) void mfma_weg_kernel(
        const _Float16* __restrict__ WfPs, const _Float16* __restrict__ WfPl,
        const _Float16* __restrict__ EmPs, const _Float16* __restrict__ EmPl,
        float* __restrict__ WeP, float* __restrict__ GP) {
    int t = threadIdx.x;
    int w = t >> 6, L = t & 63;
    int lane16 = L & 15, quad = L >> 4;
    int m0 = blockIdx.x * 128 + (w & 3) * 32;
    int n0 = blockIdx.y * 128 + (w >> 2) * 64;
    int ta = m0 >> 4, tb = n0 >> 4;
    int zraw = blockIdx.z;
    bool isWe = zraw < NZWE;
    int z, c0, cnt;
    if (isWe) {
        z = zraw;
        int base = NCW / NZWE, rem = NCW % NZWE;    // 8, 3
        c0 = z * base + (z < rem ? z : rem);
        cnt = base + (z < rem ? 1 : 0);
    } else {
        z = zraw - NZWE;
        int base = NCW / NZG, rem = NCW % NZG;      // 24, 3
        c0 = z * base + (z < rem ? z : rem);
        cnt = base + (z < rem ? 1 : 0);
    }
    f32x4 acc[2][4];
    #pragma unroll
    for (int rt = 0; rt < 2; ++rt)
        #pragma unroll
        for (int tt = 0; tt < 4; ++tt) acc[rt][tt] = (f32x4){0.f, 0.f, 0.f, 0.f};
    if (isWe) {
        for (int ci = 0; ci < cnt; ++ci) {
            int c = c0 + ci;
            size_t oa0 = paddr(ta, NCW, c, L, 0), oa1 = paddr(ta + 1, NCW, c, L, 0);
            half8 A0h = *(const half8*)(WfPs + oa0);
            half8 A0l = *(const half8*)(WfPl + oa0);
            half8 A1h = *(const half8*)(WfPs + oa1);
            half8 A1l = *(const half8*)(WfPl + oa1);
            #pragma unroll
            for (int tt = 0; tt < 4; ++tt) {
                size_t ob = paddr(tb + tt, NCW, c, L, 0);
                half8 Bh = *(const half8*)(EmPs + ob);
                half8 Bl8 = *(const half8*)(EmPl + ob);
                acc[0][tt] = MFMA16(A0h, Bl8, MFMA16(A0l, Bh, MFMA16(A0h, Bh, acc[0][tt])));
                acc[1][tt] = MFMA16(A1h, Bl8, MFMA16(A1l, Bh, MFMA16(A1h, Bh, acc[1][tt])));
            }
        }
    } else {
        for (int ci = 0; ci < cnt; ++ci) {
            int c = c0 + ci;
            half8 A0h = *(const half8*)(WfPs + paddr(ta, NCW, c, L, 0));
            half8 A1h = *(const half8*)(WfPs + paddr(ta + 1, NCW, c, L, 0));
            #pragma unroll
            for (int tt = 0; tt < 4; ++tt) {
                half8 Bh = *(const half8*)(WfPs + paddr(tb + tt, NCW, c, L, 0));
                acc[0][tt] = MFMA16(A0h, Bh, acc[0][tt]);
                acc[1][tt] = MFMA16(A1h, Bh, acc[1][tt]);
            }
        }
    }
    float* C = (isWe ? WeP : GP) + (size_t)z * KN * KN;
    #pragma unroll
    for (int rt = 0; rt < 2; ++rt)
        #pragma unroll
        for (int tt = 0; tt < 4; ++tt)
            #pragma unroll
            for (int r = 0; r < 4; ++r)
                C[(size_t)(m0 + rt * 16 + quad * 4 + r) * KN
                  + n0 + tt * 16 + lane16] = acc[rt][tt][r];
}

// ---------------------------------------------------------------------------
// Merged reducers (R19): blocks [0,1024) wepack (24 partials, fixed order ->
// deterministic, transpose-pack to B-frags); [1024,2048) gred (8 partials,
// packs G to fp16-hi B-frags); block 2048 sbered.
// ---------------------------------------------------------------------------
__global__ __launch_bounds__(256) void wepackgred_kernel(
        const float* __restrict__ WeP, const float* __restrict__ GP,
        const float* __restrict__ s2p, const float* __restrict__ bep,
        _Float16* __restrict__ WePs, _Float16* __restrict__ WePl,
        _Float16* __restrict__ GhPs, float* __restrict__ s2,
        float* __restrict__ be) {
    int id = blockIdx.x;
    int t = threadIdx.x;
    if (id < 1024) {
        int g = id * 256 + t;                   // j*512 + k
        int j = g >> 9, k = g & 511;
        float v = 0.f;
        #pragma unroll
        for (int z = 0; z < NZWE; ++z) v += WeP[(size_t)z * KN * KN + g];
        _Float16 hi = (_Float16)v;
        size_t a = paddr(k >> 4, 16, j >> 5, ((j & 31) >> 3) * 16 + (k & 15), j & 7);
        WePs[a] = hi;
        WePl[a] = (_Float16)(v - (float)hi);
    } else if (id < 2048) {
        int g = (id - 1024) * 256 + t;          // m*512 + n (G symmetric)
        int m = g >> 9, n = g & 511;
        float v = 0.f;
        #pragma unroll
        for (int z = 0; z < NZG; ++z) v += GP[(size_t)z * KN * KN + g];
        GhPs[paddr(n >> 4, 16, m >> 5, ((m & 31) >> 3) * 16 + (n & 15), m & 7)]
            = (_Float16)v;
    } else {
        #pragma unroll
        for (int i = 0; i < 2; ++i) {
            int k = t + 256 * i;
            float s = 0.f, b = 0.f;
            #pragma unroll
            for (int y = 0; y < 8; ++y) {
                s += s2p[y * KN + k];
                b += bep[y * KN + k];
            }
            s2[k] = s;
            be[k] = b;
        }
    }
}

// ---------------------------------------------------------------------------
// Fused MFMA encoder + SCORE + hGh (R21 = R14 body + s_setprio elevation of
// the y=0 critical path). Co-resident heavy y=0 and light y=1 blocks are at
// different phases; setprio(1) around the score/hGh MFMA loops makes the CU
// scheduler favor the makespan-critical y=0 waves (T5 mechanism). No
// instruction/order changes -> bit-identical outputs.
// ---------------------------------------------------------------------------
__global__ __launch_bounds__(512) void enc1_kernel(
        const _Float16* __restrict__ XPs, const _Float16* __restrict__ XPl,
        const _Float16* __restrict__ WfxPs, const _Float16* __restrict__ WfxPl,
        const float* __restrict__ bfx,
        const _Float16* __restrict__ Wx2Ps, const _Float16* __restrict__ Wx2Pl,
        const float* __restrict__ bx2,
        const _Float16* __restrict__ WePs, const _Float16* __restrict__ WePl,
        const _Float16* __restrict__ GhPs,
        const float* __restrict__ s2, const float* __restrict__ be,
        float* __restrict__ colsum,
        float* __restrict__ EX,
        int* __restrict__ ind, float* __restrict__ out_ind,
        int* __restrict__ counts, float* __restrict__ diffsum) {
    __shared__ _Float16 hhi[32][CHP];
    __shared__ _Float16 hlo[32][CHP];
    __shared__ float redv[8][32];
    __shared__ int   redi[8][32];
    __shared__ float fin[32];
    __shared__ float gpart[8];
    int t = threadIdx.x;
    int w = t >> 6, L = t & 63;
    int l16 = L & 15, quad = L >> 4;
    int m0 = blockIdx.x * 32;
    int ta = m0 >> 4;
    int enc = blockIdx.y;
    int n0 = enc * 512 + w * 64;
    int tb = n0 >> 4;
    f32x4 acc[2][4];
    #pragma unroll
    for (int rt = 0; rt < 2; ++rt)
        #pragma unroll
        for (int tt = 0; tt < 4; ++tt) acc[rt][tt] = (f32x4){0.f, 0.f, 0.f, 0.f};
    #pragma unroll
    for (int c = 0; c < 4; ++c) {
        size_t oa0 = paddr(ta, 4, c, L, 0), oa1 = paddr(ta + 1, 4, c, L, 0);
        half8 A0h = *(const half8*)(XPs + oa0);
        half8 A0l = *(const half8*)(XPl + oa0);
        half8 A1h = *(const half8*)(XPs + oa1);
        half8 A1l = *(const half8*)(XPl + oa1);
        #pragma unroll
        for (int tt = 0; tt < 4; ++tt) {
            size_t ob = paddr(tb + tt, 4, c, L, 0);
            half8 Bh = *(const half8*)(WfxPs + ob);
            half8 Bl8 = *(const half8*)(WfxPl + ob);
            acc[0][tt] = MFMA16(A0h, Bl8, MFMA16(A0l, Bh, MFMA16(A0h, Bh, acc[0][tt])));
            acc[1][tt] = MFMA16(A1h, Bl8, MFMA16(A1l, Bh, MFMA16(A1h, Bh, acc[1][tt])));
        }
    }
    #pragma unroll
    for (int rt = 0; rt < 2; ++rt)
        #pragma unroll
        for (int tt = 0; tt < 4; ++tt) {
            int col = w * 64 + tt * 16 + l16;
            float bias = bfx[enc * 512 + col];
            #pragma unroll
            for (int r = 0; r < 4; ++r) {
                int row = rt * 16 + quad * 4 + r;
                float v = fmaxf(acc[rt][tt][r] + bias, 0.f);
                _Float16 hi = (_Float16)v;
                hhi[row][col] = hi;
                hlo[row][col] = (_Float16)(v - (float)hi);
            }
        }
    __syncthreads();
    if (enc == 0) {
        float s = 0.f;
        #pragma unroll
        for (int r = 0; r < 32; ++r) s += (float)hhi[r][t] + (float)hlo[r][t];
        atomicAdd(&colsum[t], s);
        int colbase = w * 64;
        int tbs = w * 4;
        float cks[4];
        #pragma unroll
        for (int tt = 0; tt < 4; ++tt) {
            int c = colbase + tt * 16 + l16;
            cks[tt] = 0.5f * s2[c] - be[c];
        }
        #pragma unroll
        for (int rt = 0; rt < 2; ++rt)
            #pragma unroll
            for (int tt = 0; tt < 4; ++tt) acc[rt][tt] = (f32x4){0.f, 0.f, 0.f, 0.f};
        const _Float16* hA0 = &hhi[l16][quad << 3];
        const _Float16* lA0 = &hlo[l16][quad << 3];
        const _Float16* hA1 = &hhi[16 + l16][quad << 3];
        const _Float16* lA1 = &hlo[16 + l16][quad << 3];
        __builtin_amdgcn_s_setprio(1);
        for (int c = 0; c < 16; ++c) {
            int d0 = c * 32;
            half8 A0h = *(const half8*)(hA0 + d0);
            half8 A0l = *(const half8*)(lA0 + d0);
            half8 A1h = *(const half8*)(hA1 + d0);
            half8 A1l = *(const half8*)(lA1 + d0);
            #pragma unroll
            for (int tt = 0; tt < 4; ++tt) {
                size_t ob = paddr(tbs + tt, 16, c, L, 0);
                half8 Bh = *(const half8*)(WePs + ob);
                half8 Bl8 = *(const half8*)(WePl + ob);
                acc[0][tt] = MFMA16(A0h, Bl8, MFMA16(A0l, Bh, MFMA16(A0h, Bh, acc[0][tt])));
                acc[1][tt] = MFMA16(A1h, Bl8, MFMA16(A1l, Bh, MFMA16(A1h, Bh, acc[1][tt])));
            }
        }
        __builtin_amdgcn_s_setprio(0);
        #pragma unroll
        for (int rt = 0; rt < 2; ++rt) {
            #pragma unroll
            for (int r = 0; r < 4; ++r) {
                float mv = cks[0] - acc[rt][0][r];
                int mi = colbase + l16;
                #pragma unroll
                for (int tt = 1; tt < 4; ++tt) {
                    float v = cks[tt] - acc[rt][tt][r];
                    int c = colbase + tt * 16 + l16;
                    if (v < mv || (v == mv && c < mi)) { mv = v; mi = c; }
                }
                #pragma unroll
                for (int d = 1; d < 16; d <<= 1) {
                    float ov = __shfl_xor(mv, d);
                    int oi = __shfl_xor(mi, d);
                    if (ov < mv || (ov == mv && oi < mi)) { mv = ov; mi = oi; }
                }
                if (l16 == 0) {
                    int row = rt * 16 + quad * 4 + r;
                    redv[w][row] = mv; redi[w][row] = mi;
                }
            }
        }
        // ---- hGh pass (separate loop, reuses acc after argmin consumed) ----
        #pragma unroll
        for (int rt = 0; rt < 2; ++rt)
            #pragma unroll
            for (int tt = 0; tt < 4; ++tt) acc[rt][tt] = (f32x4){0.f, 0.f, 0.f, 0.f};
        __builtin_amdgcn_s_setprio(1);
        for (int c = 0; c < 16; ++c) {
            int d0 = c * 32;
            half8 A0h = *(const half8*)(hA0 + d0);
            half8 A1h = *(const half8*)(hA1 + d0);
            #pragma unroll
            for (int tt = 0; tt < 4; ++tt) {
                half8 Gh = *(const half8*)(GhPs + paddr(tbs + tt, 16, c, L, 0));
                acc[0][tt] = MFMA16(A0h, Gh, acc[0][tt]);
                acc[1][tt] = MFMA16(A1h, Gh, acc[1][tt]);
            }
        }
        __builtin_amdgcn_s_setprio(0);
        float gs = 0.f;
        #pragma unroll
        for (int rt = 0; rt < 2; ++rt)
            #pragma unroll
            for (int tt = 0; tt < 4; ++tt) {
                int col = colbase + tt * 16 + l16;
                #pragma unroll
                for (int r = 0; r < 4; ++r) {
                    int row = rt * 16 + quad * 4 + r;
                    gs += acc[rt][tt][r] * (float)hhi[row][col];
                }
            }
        #pragma unroll
        for (int d = 1; d < 64; d <<= 1) gs += __shfl_xor(gs, d);
        if (L == 0) gpart[w] = gs;
        __syncthreads();
        if (t < 32) {
            float mv = redv[0][t]; int mi = redi[0][t];
            #pragma unroll
            for (int w2 = 1; w2 < 8; ++w2) {
                float ov = redv[w2][t]; int oi = redi[w2][t];
                if (ov < mv || (ov == mv && oi < mi)) { mv = ov; mi = oi; }
            }
            int b = m0 + t;
            ind[b] = mi;
            out_ind[b] = (float)mi;
            atomicAdd(&counts[mi], 1);
            fin[t] = 2.f * mv;
        }
        __syncthreads();
        if (t == 0) {
            float s = 0.f;
            #pragma unroll
            for (int i = 0; i < 32; ++i) s += fin[i];
            #pragma unroll
            for (int w2 = 0; w2 < 8; ++w2) s += gpart[w2];
            atomicAdd(diffsum, s);
        }
    } else {
        int rt = w & 1, ct = w >> 1;
        f32x4 eacc = (f32x4){0.f, 0.f, 0.f, 0.f};
        for (int c = 0; c < 16; ++c) {
            int d0 = c * 32 + (quad << 3);
            int m = rt * 16 + l16;
            half8 Ah = *(half8*)(&hhi[m][d0]);
            half8 Al = *(half8*)(&hlo[m][d0]);
            size_t ob = paddr(ct, 16, c, L, 0);
            half8 Bh = *(const half8*)(Wx2Ps + ob);
            half8 Bl8 = *(const half8*)(Wx2Pl + ob);
            eacc = MFMA16(Ah, Bl8, MFMA16(Al, Bh, MFMA16(Ah, Bh, eacc)));
        }
        int col = ct * 16 + l16;
        float bias = bx2[col];
        #pragma unroll
        for (int r = 0; r < 4; ++r) {
            int row = m0 + rt * 16 + quad * 4 + r;
            EX[(size_t)row * DIN + col] = eacc[r] + bias;
        }
    }
}

// ---------------------------------------------------------------------------
// Scatter: computes its own offsets scan from counts (deterministic int
// scan). Block-aggregated cursors.
// ---------------------------------------------------------------------------
__global__ __launch_bounds__(256) void scatter_kernel(const int* __restrict__ ind,
                                                      const int* __restrict__ counts,
                                                      int* __restrict__ cursors,
                                                      int* __restrict__ perm) {
    __shared__ int sc[KN], soff[KN], lcount[KN], lbase[KN], lcur[KN];
    int t = threadIdx.x;
    for (int i = t; i < KN; i += 256) {
        sc[i] = counts[i];
        lcount[i] = 0; lcur[i] = 0;
    }
    __syncthreads();
    #pragma unroll
    for (int half = 0; half < 2; ++half) {
        int i = t + 256 * half;
        int off = 0;
        for (int k = 0; k < i; ++k) off += sc[k];
        soff[i] = off;
    }
    int b = blockIdx.x * 256 + t;
    int k = ind[b];
    atomicAdd(&lcount[k], 1);
    __syncthreads();
    for (int i = t; i < KN; i += 256) {
        int c = lcount[i];
        if (c > 0) lbase[i] = atomicAdd(&cursors[i], c);
    }
    __syncthreads();
    int pos = soff[k] + lbase[k] + atomicAdd(&lcur[k], 1);
    perm[pos] = b;
}

// ---------------------------------------------------------------------------
// Decoder + fused finalize: blocks [0, BN/4) decode one wave per sample
// (load-balanced under histogram skew); block BN/4 runs finalize.
// ---------------------------------------------------------------------------
__global__ __launch_bounds__(256) void decode_kernel(const float* __restrict__ EX,
                                                     const int* __restrict__ perm,
                                                     const int* __restrict__ ind,
                                                     const float* __restrict__ W1,
                                                     const float* __restrict__ b1,
                                                     const float* __restrict__ W2,
                                                     const float* __restrict__ b2,
                                                     float* __restrict__ dec,
                                                     const int* __restrict__ counts,
                                                     const float* __restrict__ diffsum,
                                                     const float* __restrict__ colsum,
                                                     const float* __restrict__ w0,
                                                     const float* __restrict__ bf2,
                                                     float* __restrict__ out_diff,
                                                     float* __restrict__ out_perp) {
    if (blockIdx.x < BN / 4) {
        __shared__ float exs[4][DIN];
        __shared__ float h2s[4][DH];
        int t = threadIdx.x;
        int w = t >> 6, l = t & 63;
        int s = blockIdx.x * 4 + w;
        int b = perm[s];
        int k = ind[b];
        exs[w][l] = EX[(size_t)b * DIN + l];
        __syncthreads();
        const float* w1 = W1 + (size_t)k * (DIN * DH);
        float h = b1[(size_t)k * DH + l];
        #pragma unroll
        for (int j = 0; j < DIN; ++j)
            h = fmaf(exs[w][j], w1[(size_t)j * DH + l], h);
        h2s[w][l] = fmaxf(h, 0.f);
        __syncthreads();
        if (l < DY) {
            const float* w2 = W2 + (size_t)k * (DH * DY);
            float d = b2[(size_t)k * DY + l];
            #pragma unroll
            for (int j = 0; j < DH; ++j)
                d = fmaf(h2s[w][j], w2[(size_t)j * DY + l], d);
            dec[(size_t)b * DY + l] = d;
        }
        return;
    }
    // ---- finalize (single block) ----
    __shared__ float sf[256];
    int t = threadIdx.x;
    float term = 0.f, dotp = 0.f, bbp = 0.f;
    #pragma unroll
    for (int i = 0; i < 2; ++i) {
        int k = t + 256 * i;
        int c = counts[k];
        double p = (double)c / (double)BN;
        term += (float)(-p * log(p + 1e-10));
        dotp += colsum[k] * w0[k];
    }
    for (int d = t; d < ED; d += 256) { float v = bf2[d]; bbp = fmaf(v, v, bbp); }
    sf[t] = dotp; __syncthreads();
    for (int s = 128; s > 0; s >>= 1) { if (t < s) sf[t] += sf[t + s]; __syncthreads(); }
    float dot_all = sf[0];
    __syncthreads();
    sf[t] = bbp; __syncthreads();
    for (int s = 128; s > 0; s >>= 1) { if (t < s) sf[t] += sf[t + s]; __syncthreads(); }
    float bb = sf[0];
    __syncthreads();
    sf[t] = term; __syncthreads();
    for (int s = 128; s > 0; s >>= 1) { if (t < s) sf[t] += sf[t + s]; __syncthreads(); }
    if (t == 0) {
        *out_perp = expf(sf[0]);
        *out_diff = (diffsum[0] + 2.f * dot_all + (float)BN * bb) /
                    ((float)BN * (float)ED);
    }
}

// ---------------------------------------------------------------------------
extern "C" void kernel_launch(void* const* d_in, const int* in_sizes, int n_in,
                              void* d_out, int out_size, void* d_ws, size_t ws_size,
                              hipStream_t stream) {
    const float* x     = (const float*)d_in[0];
    const float* Wf1   = (const float*)d_in[1];
    const float* bf1   = (const float*)d_in[2];
    const float* Wf2   = (const float*)d_in[3];
    const float* bf2   = (const float*)d_in[4];
    const float* Wx1   = (const float*)d_in[5];
    const float* bx1   = (const float*)d_in[6];
    const float* Wx2   = (const float*)d_in[7];
    const float* bx2   = (const float*)d_in[8];
    const float* embed = (const float*)d_in[9];
    const float* W1    = (const float*)d_in[10];
    const float* b1    = (const float*)d_in[11];
    const float* W2    = (const float*)d_in[12];
    const float* b2    = (const float*)d_in[13];
    float* out = (float*)d_out;

    char* ws = (char*)d_ws;
    size_t off = 0;
    auto carve = [&](size_t bytes) -> void* {
        void* p = ws + off;
        off += (bytes + 255) & ~(size_t)255;
        return p;
    };
    _Float16* XPs   = (_Float16*)carve((size_t)BN * INC * 2);    // 4.2 MB
    _Float16* XPl   = (_Float16*)carve((size_t)BN * INC * 2);
    _Float16* WfxPs = (_Float16*)carve((size_t)1024 * INC * 2);
    _Float16* WfxPl = (_Float16*)carve((size_t)1024 * INC * 2);
    float*    bfx   = (float*)carve(1024 * 4);
    _Float16* Wx2Ps = (_Float16*)carve((size_t)DIN * CH * 2);
    _Float16* Wx2Pl = (_Float16*)carve((size_t)DIN * CH * 2);
    _Float16* WfPs  = (_Float16*)carve((size_t)CH * ED * 2);     // 6.4 MB
    _Float16* WfPl  = (_Float16*)carve((size_t)CH * ED * 2);
    _Float16* EmPs  = (_Float16*)carve((size_t)KN * ED * 2);
    _Float16* EmPl  = (_Float16*)carve((size_t)KN * ED * 2);
    // WeP[24] + GP[8] partial buffers (32 MB, dead after wepackgred).
    float*    WeP = (float*)carve((size_t)(NZWE + NZG) * KN * KN * 4);
    float*    GP  = WeP + (size_t)NZWE * KN * KN;
    _Float16* WePs = (_Float16*)carve((size_t)KN * CH * 2);
    _Float16* WePl = (_Float16*)carve((size_t)KN * CH * 2);
    _Float16* GhPs = (_Float16*)carve((size_t)KN * KN * 2);      // 0.5 MB
    float*    EX   = (float*)carve((size_t)BN * DIN * 4);        // 4.2 MB
    float*    s2p  = (float*)carve(8 * KN * 4);
    float*    bep  = (float*)carve(8 * KN * 4);
    float*    s2   = (float*)carve(KN * 4);
    float*    be   = (float*)carve(KN * 4);
    char* zbase = ws + off;                                      // ---- zero region ----
    float* w0    = (float*)carve(CH * 4);
    float* colsum= (float*)carve(CH * 4);
    int*   counts= (int*)carve(KN * 4);
    int*   cursors=(int*)carve(KN * 4);
    float* diffsum=(float*)carve(256);
    size_t zbytes = (size_t)(ws + off - zbase);                  // ---- end zero region ----
    int*   ind     = (int*)carve(BN * 4);
    int*   perm    = (int*)carve(BN * 4);
    (void)in_sizes; (void)n_in; (void)out_size; (void)ws_size;

    hipMemsetAsync(zbase, 0, zbytes, stream);
    packall_kernel<<<5388, 256, 0, stream>>>(x, Wf1, Wx1, bf1, bx1, Wx2, Wf2, bf2,
                                             embed, XPs, XPl, WfxPs, WfxPl, bfx,
                                             Wx2Ps, Wx2Pl, WfPs, WfPl, EmPs, EmPl,
                                             s2p, bep, w0);
    mfma_weg_kernel<<<dim3(4, 4, NZWE + NZG), 512, 0, stream>>>(WfPs, WfPl,
                                                                EmPs, EmPl,
                                                                WeP, GP);
    wepackgred_kernel<<<2049, 256, 0, stream>>>(WeP, GP, s2p, bep,
                                                WePs, WePl, GhPs, s2, be);
    enc1_kernel<<<dim3(BN / 32, 2), 512, 0, stream>>>(XPs, XPl, WfxPs, WfxPl, bfx,
                                                      Wx2Ps, Wx2Pl, bx2,
                                                      WePs, WePl, GhPs, s2, be,
                                                      colsum, EX,
                                                      ind, out + OUT_IND, counts,
                                                      diffsum);
    scatter_kernel<<<BN / 256, 256, 0, stream>>>(ind, counts, cursors, perm);
    decode_kernel<<<BN / 4 + 1, 256, 0, stream>>>(EX, perm, ind, W1, b1, W2, b2,
                                                  out + OUT_DEC,
                                                  counts, diffsum, colsum, w0, bf2,
                                                  out + OUT_DIFF, out + OUT_PERP);
}

// Round 12
// 309.990 us; speedup vs baseline: 1.0074x; 1.0074x over previous
//
#include <hip/hip_runtime.h>
#include <math.h>

// Problem constants
#define BN     16384
#define INC    128
#define CH     512
#define ED     6240
#define KN     512      // NUM_EMB
#define DIN    64
#define DH     64
#define DY     32
#define NCW    195      // ED/32 k-chunks for Wf2/embed packing
#define CHP    (CH + 8) // padded LDS row stride (halves)
#define NZWE   24       // We K-slices (3-pass -> ~24.4 work units each)
#define NZG    8        // G  K-slices (1-pass -> ~24.4 work units each)

// d_out layout (float32): dec[16384*32] | diff[1] | embed_ind[16384] | perplexity[1]
#define OUT_DEC   0
#define OUT_DIFF  (BN*DY)
#define OUT_IND   (BN*DY + 1)
#define OUT_PERP  (BN*DY + 1 + BN)

typedef _Float16 half8 __attribute__((ext_vector_type(8)));
typedef float    f32x4 __attribute__((ext_vector_type(4)));
#define MFMA16(a, b, c) __builtin_amdgcn_mfma_f32_16x16x32_f16(a, b, c, 0, 0, 0)

// Packed fragment-tile layout: element (row r within 16-row tile `tile`,
// k-dim index d) lives at ((tile*NC + d/32)*64 + ((d%32)/8)*16 + (r%16))*8 + d%8.
__device__ __forceinline__ size_t paddr(int tile, int NC, int c, int lane, int e) {
    return ((size_t)(tile * NC + c) * 64 + lane) * 8 + e;
}

// ---------------------------------------------------------------------------
// packall (R16): vectorized-store packers.
// Block ranges: [0,1560) splitwf2 | [..,4680) embt | [..,4808) s2bep |
// [..,5320) xpack | [..,5384) wfxpack | [..,5388) wx2pack.
// ---------------------------------------------------------------------------
__global__ __launch_bounds__(256) void packall_kernel(
        const float* __restrict__ x,
        const float* __restrict__ Wf1, const float* __restrict__ Wx1,
        const float* __restrict__ bf1, const float* __restrict__ bx1,
        const float* __restrict__ Wx2,
        const float* __restrict__ Wf2, const float* __restrict__ bf2,
        const float* __restrict__ embed,
        _Float16* __restrict__ XPs, _Float16* __restrict__ XPl,
        _Float16* __restrict__ WfxPs, _Float16* __restrict__ WfxPl,
        float* __restrict__ bfx,
        _Float16* __restrict__ Wx2Ps, _Float16* __restrict__ Wx2Pl,
        _Float16* __restrict__ WfPs, _Float16* __restrict__ WfPl,
        _Float16* __restrict__ EmPs, _Float16* __restrict__ EmPl,
        float* __restrict__ s2p, float* __restrict__ bep,
        float* __restrict__ w0) {
    __shared__ __align__(16) char smem[16384];
    int id = blockIdx.x;
    int t = threadIdx.x;
    if (id < 1560) {
        // ---- splitwf2: Wf2 -> packed hi/lo (half8 stores) + w0 partials ----
        int bx = id % NCW, by = id / NCW;       // by in [0,8)
        int jl = t >> 2, e8 = t & 3;
        int j = by * 64 + jl;
        int d0 = bx * 32 + e8 * 8;
        float4 v0 = *(const float4*)&Wf2[(size_t)j * ED + d0];
        float4 v1 = *(const float4*)&Wf2[(size_t)j * ED + d0 + 4];
        float4 b0 = *(const float4*)&bf2[d0];
        float4 b1 = *(const float4*)&bf2[d0 + 4];
        float vv[8] = {v0.x, v0.y, v0.z, v0.w, v1.x, v1.y, v1.z, v1.w};
        float bb[8] = {b0.x, b0.y, b0.z, b0.w, b1.x, b1.y, b1.z, b1.w};
        half8 hh, ll;
        float s = 0.f;
        #pragma unroll
        for (int e = 0; e < 8; ++e) {
            float v = vv[e];
            _Float16 hi = (_Float16)v;
            hh[e] = hi;
            ll[e] = (_Float16)(v - (float)hi);
            s = fmaf(v, bb[e], s);
        }
        size_t a = paddr(j >> 4, NCW, bx, e8 * 16 + (j & 15), 0);
        *(half8*)(WfPs + a) = hh;
        *(half8*)(WfPl + a) = ll;
        s += __shfl_xor(s, 1);
        s += __shfl_xor(s, 2);
        if (e8 == 0) atomicAdd(&w0[j], s);
    } else if (id < 4680) {
        // ---- embt: embed transpose+split (half8 stores) ----
        float (*tile)[33] = (float(*)[33])smem; // tile[di][ki]
        int sub = id - 1560;
        int bx = sub % NCW, by = sub / NCW;
        int dl = t >> 5, kl = t & 31;
        #pragma unroll
        for (int r = 0; r < 4; ++r)
            tile[dl + 8 * r][kl] = embed[(size_t)(bx * 32 + dl + 8 * r) * KN
                                         + by * 32 + kl];
        __syncthreads();
        if (t < 128) {
            int g = t >> 5, kl2 = t & 31;       // g: d-group 0..3
            int k = by * 32 + kl2;
            half8 hh, ll;
            #pragma unroll
            for (int e = 0; e < 8; ++e) {
                float v = tile[g * 8 + e][kl2];
                _Float16 hi = (_Float16)v;
                hh[e] = hi;
                ll[e] = (_Float16)(v - (float)hi);
            }
            size_t a = paddr(k >> 4, NCW, bx, g * 16 + (k & 15), 0);
            *(half8*)(EmPs + a) = hh;
            *(half8*)(EmPl + a) = ll;
        }
    } else if (id < 4808) {
        // ---- s2bep: deterministic s2/be partials (fixed-order, no atomics) ----
        float (*rs)[33] = (float(*)[33])smem;
        float (*rb)[33] = (float(*)[33])(smem + 8 * 33 * 4);
        int sub = id - 4680;
        int bx = sub % 16, by = sub / 16;
        int kl = t & 31, dl = t >> 5;
        int kb = bx * 32;
        int d0 = by * 780;
        float s = 0.f, b = 0.f;
        for (int d = d0 + dl; d < d0 + 780; d += 8) {
            float e = embed[(size_t)d * KN + kb + kl];
            s = fmaf(e, e, s);
            b = fmaf(bf2[d], e, b);
        }
        rs[dl][kl] = s; rb[dl][kl] = b;
        __syncthreads();
        if (t < 32) {
            float ss = 0.f, bb = 0.f;
            #pragma unroll
            for (int i = 0; i < 8; ++i) { ss += rs[i][t]; bb += rb[i][t]; }
            s2p[by * KN + kb + t] = ss;
            bep[by * KN + kb + t] = bb;
        }
    } else if (id < 5320) {
        // ---- xpack: x -> XPs/XPl ----
        float (*xt)[INC] = (float(*)[INC])smem;
        int m0 = (id - 4808) * 32;
        for (int i = t; i < 32 * (INC / 4); i += 256) {
            int row = i >> 5, c4 = (i & 31) << 2;
            *(float4*)&xt[row][c4] = *(const float4*)&x[(size_t)(m0 + row) * INC + c4];
        }
        __syncthreads();
        int ta = m0 >> 4;
        #pragma unroll
        for (int i = 0; i < 2; ++i) {
            int idx = t + 256 * i;
            int tile2 = idx >> 8;
            int c = (idx >> 6) & 3;
            int lane = idx & 63;
            int m = tile2 * 16 + (lane & 15);
            int d0 = c * 32 + ((lane >> 4) << 3);
            half8 hh, ll;
            #pragma unroll
            for (int e = 0; e < 8; ++e) {
                float v = xt[m][d0 + e];
                _Float16 hi = (_Float16)v;
                hh[e] = hi;
                ll[e] = (_Float16)(v - (float)hi);
            }
            *(half8*)(XPs + paddr(ta + tile2, 4, c, lane, 0)) = hh;
            *(half8*)(XPl + paddr(ta + tile2, 4, c, lane, 0)) = ll;
        }
    } else if (id < 5384) {
        // ---- wfxpack: fused Wf1|Wx1 cols + bfx ----
        int tile = id - 5320;
        for (int i = t; i < 2048; i += 256) {
            int c = i >> 9, lane = (i >> 3) & 63, e = i & 7;
            int n = tile * 16 + (lane & 15);
            int d = c * 32 + ((lane >> 4) << 3) + e;
            float v = (n < 512) ? Wf1[(size_t)d * CH + n] : Wx1[(size_t)d * CH + n - 512];
            _Float16 hi = (_Float16)v;
            size_t a = paddr(tile, 4, c, lane, e);
            WfxPs[a] = hi;
            WfxPl[a] = (_Float16)(v - (float)hi);
        }
        if (tile == 0)
            for (int j = t; j < 512; j += 256) { bfx[j] = bf1[j]; bfx[512 + j] = bx1[j]; }
    } else {
        // ---- wx2pack ----
        int tile = id - 5384;
        for (int i = t; i < 8192; i += 256) {
            int c = i >> 9, lane = (i >> 3) & 63, e = i & 7;
            int n = tile * 16 + (lane & 15);
            int d = c * 32 + ((lane >> 4) << 3) + e;
            float v = Wx2[(size_t)d * DIN + n];
            _Float16 hi = (_Float16)v;
            size_t a = paddr(tile, 16, c, lane, e);
            Wx2Ps[a] = hi;
            Wx2Pl[a] = (_Float16)(v - (float)hi);
        }
    }
}

// ---------------------------------------------------------------------------
// Merged precompute GEMMs (R19): grid (4,4,32), block 512 -> 512 blocks =
// 2 blocks/CU. Work-balanced z-split: z<24 -> We slice (3-pass); z>=24 ->
// G slice (1-pass). Partials: (24+8) MB = 32 MB.
// ---------------------------------------------------------------------------
__global__ __launch_bounds__(512) void mfma_weg_kernel(
        const _Float16* __restrict__ WfPs, const _Float16* __restrict__ WfPl,
        const _Float16* __restrict__ EmPs, const _Float16* __restrict__ EmPl,
        float* __restrict__ WeP, float* __restrict__ GP) {
    int t = threadIdx.x;
    int w = t >> 6, L = t & 63;
    int lane16 = L & 15, quad = L >> 4;
    int m0 = blockIdx.x * 128 + (w & 3) * 32;
    int n0 = blockIdx.y * 128 + (w >> 2) * 64;
    int ta = m0 >> 4, tb = n0 >> 4;
    int zraw = blockIdx.z;
    bool isWe = zraw < NZWE;
    int z, c0, cnt;
    if (isWe) {
        z = zraw;
        int base = NCW / NZWE, rem = NCW % NZWE;    // 8, 3
        c0 = z * base + (z < rem ? z : rem);
        cnt = base + (z < rem ? 1 : 0);
    } else {
        z = zraw - NZWE;
        int base = NCW / NZG, rem = NCW % NZG;      // 24, 3
        c0 = z * base + (z < rem ? z : rem);
        cnt = base + (z < rem ? 1 : 0);
    }
    f32x4 acc[2][4];
    #pragma unroll
    for (int rt = 0; rt < 2; ++rt)
        #pragma unroll
        for (int tt = 0; tt < 4; ++tt) acc[rt][tt] = (f32x4){0.f, 0.f, 0.f, 0.f};
    if (isWe) {
        for (int ci = 0; ci < cnt; ++ci) {
            int c = c0 + ci;
            size_t oa0 = paddr(ta, NCW, c, L, 0), oa1 = paddr(ta + 1, NCW, c, L, 0);
            half8 A0h = *(const half8*)(WfPs + oa0);
            half8 A0l = *(const half8*)(WfPl + oa0);
            half8 A1h = *(const half8*)(WfPs + oa1);
            half8 A1l = *(const half8*)(WfPl + oa1);
            #pragma unroll
            for (int tt = 0; tt < 4; ++tt) {
                size_t ob = paddr(tb + tt, NCW, c, L, 0);
                half8 Bh = *(const half8*)(EmPs + ob);
                half8 Bl8 = *(const half8*)(EmPl + ob);
                acc[0][tt] = MFMA16(A0h, Bl8, MFMA16(A0l, Bh, MFMA16(A0h, Bh, acc[0][tt])));
                acc[1][tt] = MFMA16(A1h, Bl8, MFMA16(A1l, Bh, MFMA16(A1h, Bh, acc[1][tt])));
            }
        }
    } else {
        for (int ci = 0; ci < cnt; ++ci) {
            int c = c0 + ci;
            half8 A0h = *(const half8*)(WfPs + paddr(ta, NCW, c, L, 0));
            half8 A1h = *(const half8*)(WfPs + paddr(ta + 1, NCW, c, L, 0));
            #pragma unroll
            for (int tt = 0; tt < 4; ++tt) {
                half8 Bh = *(const half8*)(WfPs + paddr(tb + tt, NCW, c, L, 0));
                acc[0][tt] = MFMA16(A0h, Bh, acc[0][tt]);
                acc[1][tt] = MFMA16(A1h, Bh, acc[1][tt]);
            }
        }
    }
    float* C = (isWe ? WeP : GP) + (size_t)z * KN * KN;
    #pragma unroll
    for (int rt = 0; rt < 2; ++rt)
        #pragma unroll
        for (int tt = 0; tt < 4; ++tt)
            #pragma unroll
            for (int r = 0; r < 4; ++r)
                C[(size_t)(m0 + rt * 16 + quad * 4 + r) * KN
                  + n0 + tt * 16 + lane16] = acc[rt][tt][r];
}

// ---------------------------------------------------------------------------
// Merged reducers (R19): blocks [0,1024) wepack (24 partials, fixed order ->
// deterministic, transpose-pack to B-frags); [1024,2048) gred (8 partials,
// packs G to fp16-hi B-frags); block 2048 sbered.
// ---------------------------------------------------------------------------
__global__ __launch_bounds__(256) void wepackgred_kernel(
        const float* __restrict__ WeP, const float* __restrict__ GP,
        const float* __restrict__ s2p, const float* __restrict__ bep,
        _Float16* __restrict__ WePs, _Float16* __restrict__ WePl,
        _Float16* __restrict__ GhPs, float* __restrict__ s2,
        float* __restrict__ be) {
    int id = blockIdx.x;
    int t = threadIdx.x;
    if (id < 1024) {
        int g = id * 256 + t;                   // j*512 + k
        int j = g >> 9, k = g & 511;
        float v = 0.f;
        #pragma unroll
        for (int z = 0; z < NZWE; ++z) v += WeP[(size_t)z * KN * KN + g];
        _Float16 hi = (_Float16)v;
        size_t a = paddr(k >> 4, 16, j >> 5, ((j & 31) >> 3) * 16 + (k & 15), j & 7);
        WePs[a] = hi;
        WePl[a] = (_Float16)(v - (float)hi);
    } else if (id < 2048) {
        int g = (id - 1024) * 256 + t;          // m*512 + n (G symmetric)
        int m = g >> 9, n = g & 511;
        float v = 0.f;
        #pragma unroll
        for (int z = 0; z < NZG; ++z) v += GP[(size_t)z * KN * KN + g];
        GhPs[paddr(n >> 4, 16, m >> 5, ((m & 31) >> 3) * 16 + (n & 15), m & 7)]
            = (_Float16)v;
    } else {
        #pragma unroll
        for (int i = 0; i < 2; ++i) {
            int k = t + 256 * i;
            float s = 0.f, b = 0.f;
            #pragma unroll
            for (int y = 0; y < 8; ++y) {
                s += s2p[y * KN + k];
                b += bep[y * KN + k];
            }
            s2[k] = s;
            be[k] = b;
        }
    }
}

// ---------------------------------------------------------------------------
// Fused MFMA encoder + SCORE + hGh (R19/R14 body, measured-best; setprio
// removed after R21 showed it regresses lockstep multi-wave GEMM blocks).
// y=0: h=relu(x@Wf1+bf1) -> LDS -> colsum, score GEMM h.We (B from L2) +
//      deterministic argmin + hGh pass reusing acc (diffsum).
// y=1: hx=relu(x@Wx1+bx1) -> LDS -> EX = hx@Wx2+bx2.
// ---------------------------------------------------------------------------
__global__ __launch_bounds__(512) void enc1_kernel(
        const _Float16* __restrict__ XPs, const _Float16* __restrict__ XPl,
        const _Float16* __restrict__ WfxPs, const _Float16* __restrict__ WfxPl,
        const float* __restrict__ bfx,
        const _Float16* __restrict__ Wx2Ps, const _Float16* __restrict__ Wx2Pl,
        const float* __restrict__ bx2,
        const _Float16* __restrict__ WePs, const _Float16* __restrict__ WePl,
        const _Float16* __restrict__ GhPs,
        const float* __restrict__ s2, const float* __restrict__ be,
        float* __restrict__ colsum,
        float* __restrict__ EX,
        int* __restrict__ ind, float* __restrict__ out_ind,
        int* __restrict__ counts, float* __restrict__ diffsum) {
    __shared__ _Float16 hhi[32][CHP];
    __shared__ _Float16 hlo[32][CHP];
    __shared__ float redv[8][32];
    __shared__ int   redi[8][32];
    __shared__ float fin[32];
    __shared__ float gpart[8];
    int t = threadIdx.x;
    int w = t >> 6, L = t & 63;
    int l16 = L & 15, quad = L >> 4;
    int m0 = blockIdx.x * 32;
    int ta = m0 >> 4;
    int enc = blockIdx.y;
    int n0 = enc * 512 + w * 64;
    int tb = n0 >> 4;
    f32x4 acc[2][4];
    #pragma unroll
    for (int rt = 0; rt < 2; ++rt)
        #pragma unroll
        for (int tt = 0; tt < 4; ++tt) acc[rt][tt] = (f32x4){0.f, 0.f, 0.f, 0.f};
    #pragma unroll
    for (int c = 0; c < 4; ++c) {
        size_t oa0 = paddr(ta, 4, c, L, 0), oa1 = paddr(ta + 1, 4, c, L, 0);
        half8 A0h = *(const half8*)(XPs + oa0);
        half8 A0l = *(const half8*)(XPl + oa0);
        half8 A1h = *(const half8*)(XPs + oa1);
        half8 A1l = *(const half8*)(XPl + oa1);
        #pragma unroll
        for (int tt = 0; tt < 4; ++tt) {
            size_t ob = paddr(tb + tt, 4, c, L, 0);
            half8 Bh = *(const half8*)(WfxPs + ob);
            half8 Bl8 = *(const half8*)(WfxPl + ob);
            acc[0][tt] = MFMA16(A0h, Bl8, MFMA16(A0l, Bh, MFMA16(A0h, Bh, acc[0][tt])));
            acc[1][tt] = MFMA16(A1h, Bl8, MFMA16(A1l, Bh, MFMA16(A1h, Bh, acc[1][tt])));
        }
    }
    #pragma unroll
    for (int rt = 0; rt < 2; ++rt)
        #pragma unroll
        for (int tt = 0; tt < 4; ++tt) {
            int col = w * 64 + tt * 16 + l16;
            float bias = bfx[enc * 512 + col];
            #pragma unroll
            for (int r = 0; r < 4; ++r) {
                int row = rt * 16 + quad * 4 + r;
                float v = fmaxf(acc[rt][tt][r] + bias, 0.f);
                _Float16 hi = (_Float16)v;
                hhi[row][col] = hi;
                hlo[row][col] = (_Float16)(v - (float)hi);
            }
        }
    __syncthreads();
    if (enc == 0) {
        float s = 0.f;
        #pragma unroll
        for (int r = 0; r < 32; ++r) s += (float)hhi[r][t] + (float)hlo[r][t];
        atomicAdd(&colsum[t], s);
        int colbase = w * 64;
        int tbs = w * 4;
        float cks[4];
        #pragma unroll
        for (int tt = 0; tt < 4; ++tt) {
            int c = colbase + tt * 16 + l16;
            cks[tt] = 0.5f * s2[c] - be[c];
        }
        #pragma unroll
        for (int rt = 0; rt < 2; ++rt)
            #pragma unroll
            for (int tt = 0; tt < 4; ++tt) acc[rt][tt] = (f32x4){0.f, 0.f, 0.f, 0.f};
        const _Float16* hA0 = &hhi[l16][quad << 3];
        const _Float16* lA0 = &hlo[l16][quad << 3];
        const _Float16* hA1 = &hhi[16 + l16][quad << 3];
        const _Float16* lA1 = &hlo[16 + l16][quad << 3];
        for (int c = 0; c < 16; ++c) {
            int d0 = c * 32;
            half8 A0h = *(const half8*)(hA0 + d0);
            half8 A0l = *(const half8*)(lA0 + d0);
            half8 A1h = *(const half8*)(hA1 + d0);
            half8 A1l = *(const half8*)(lA1 + d0);
            #pragma unroll
            for (int tt = 0; tt < 4; ++tt) {
                size_t ob = paddr(tbs + tt, 16, c, L, 0);
                half8 Bh = *(const half8*)(WePs + ob);
                half8 Bl8 = *(const half8*)(WePl + ob);
                acc[0][tt] = MFMA16(A0h, Bl8, MFMA16(A0l, Bh, MFMA16(A0h, Bh, acc[0][tt])));
                acc[1][tt] = MFMA16(A1h, Bl8, MFMA16(A1l, Bh, MFMA16(A1h, Bh, acc[1][tt])));
            }
        }
        #pragma unroll
        for (int rt = 0; rt < 2; ++rt) {
            #pragma unroll
            for (int r = 0; r < 4; ++r) {
                float mv = cks[0] - acc[rt][0][r];
                int mi = colbase + l16;
                #pragma unroll
                for (int tt = 1; tt < 4; ++tt) {
                    float v = cks[tt] - acc[rt][tt][r];
                    int c = colbase + tt * 16 + l16;
                    if (v < mv || (v == mv && c < mi)) { mv = v; mi = c; }
                }
                #pragma unroll
                for (int d = 1; d < 16; d <<= 1) {
                    float ov = __shfl_xor(mv, d);
                    int oi = __shfl_xor(mi, d);
                    if (ov < mv || (ov == mv && oi < mi)) { mv = ov; mi = oi; }
                }
                if (l16 == 0) {
                    int row = rt * 16 + quad * 4 + r;
                    redv[w][row] = mv; redi[w][row] = mi;
                }
            }
        }
        // ---- hGh pass (separate loop, reuses acc after argmin consumed) ----
        #pragma unroll
        for (int rt = 0; rt < 2; ++rt)
            #pragma unroll
            for (int tt = 0; tt < 4; ++tt) acc[rt][tt] = (f32x4){0.f, 0.f, 0.f, 0.f};
        for (int c = 0; c < 16; ++c) {
            int d0 = c * 32;
            half8 A0h = *(const half8*)(hA0 + d0);
            half8 A1h = *(const half8*)(hA1 + d0);
            #pragma unroll
            for (int tt = 0; tt < 4; ++tt) {
                half8 Gh = *(const half8*)(GhPs + paddr(tbs + tt, 16, c, L, 0));
                acc[0][tt] = MFMA16(A0h, Gh, acc[0][tt]);
                acc[1][tt] = MFMA16(A1h, Gh, acc[1][tt]);
            }
        }
        float gs = 0.f;
        #pragma unroll
        for (int rt = 0; rt < 2; ++rt)
            #pragma unroll
            for (int tt = 0; tt < 4; ++tt) {
                int col = colbase + tt * 16 + l16;
                #pragma unroll
                for (int r = 0; r < 4; ++r) {
                    int row = rt * 16 + quad * 4 + r;
                    gs += acc[rt][tt][r] * (float)hhi[row][col];
                }
            }
        #pragma unroll
        for (int d = 1; d < 64; d <<= 1) gs += __shfl_xor(gs, d);
        if (L == 0) gpart[w] = gs;
        __syncthreads();
        if (t < 32) {
            float mv = redv[0][t]; int mi = redi[0][t];
            #pragma unroll
            for (int w2 = 1; w2 < 8; ++w2) {
                float ov = redv[w2][t]; int oi = redi[w2][t];
                if (ov < mv || (ov == mv && oi < mi)) { mv = ov; mi = oi; }
            }
            int b = m0 + t;
            ind[b] = mi;
            out_ind[b] = (float)mi;
            atomicAdd(&counts[mi], 1);
            fin[t] = 2.f * mv;
        }
        __syncthreads();
        if (t == 0) {
            float s = 0.f;
            #pragma unroll
            for (int i = 0; i < 32; ++i) s += fin[i];
            #pragma unroll
            for (int w2 = 0; w2 < 8; ++w2) s += gpart[w2];
            atomicAdd(diffsum, s);
        }
    } else {
        int rt = w & 1, ct = w >> 1;
        f32x4 eacc = (f32x4){0.f, 0.f, 0.f, 0.f};
        for (int c = 0; c < 16; ++c) {
            int d0 = c * 32 + (quad << 3);
            int m = rt * 16 + l16;
            half8 Ah = *(half8*)(&hhi[m][d0]);
            half8 Al = *(half8*)(&hlo[m][d0]);
            size_t ob = paddr(ct, 16, c, L, 0);
            half8 Bh = *(const half8*)(Wx2Ps + ob);
            half8 Bl8 = *(const half8*)(Wx2Pl + ob);
            eacc = MFMA16(Ah, Bl8, MFMA16(Al, Bh, MFMA16(Ah, Bh, eacc)));
        }
        int col = ct * 16 + l16;
        float bias = bx2[col];
        #pragma unroll
        for (int r = 0; r < 4; ++r) {
            int row = m0 + rt * 16 + quad * 4 + r;
            EX[(size_t)row * DIN + col] = eacc[r] + bias;
        }
    }
}

// ---------------------------------------------------------------------------
// Scatter (R22): Hillis-Steele parallel prefix scan over counts (integer
// adds -> order-independent, bit-exact vs the old O(n^2) serial scan whose
// worst thread did 511 dependent LDS reads). Block-aggregated cursors.
// ---------------------------------------------------------------------------
__global__ __launch_bounds__(256) void scatter_kernel(const int* __restrict__ ind,
                                                      const int* __restrict__ counts,
                                                      int* __restrict__ cursors,
                                                      int* __restrict__ perm) {
    __shared__ int sc[KN], soff[KN], lcount[KN], lbase[KN], lcur[KN];
    int t = threadIdx.x;
    for (int i = t; i < KN; i += 256) {
        sc[i] = counts[i];
        lcount[i] = 0; lcur[i] = 0;
    }
    __syncthreads();
    // inclusive scan of sc[0..511], 2 elements/thread
    #pragma unroll
    for (int st = 1; st < KN; st <<= 1) {
        int i0 = t, i1 = t + 256;
        int v0 = (i0 >= st) ? sc[i0 - st] : 0;
        int v1 = (i1 >= st) ? sc[i1 - st] : 0;
        __syncthreads();
        sc[i0] += v0;
        sc[i1] += v1;
        __syncthreads();
    }
    #pragma unroll
    for (int half = 0; half < 2; ++half) {
        int i = t + 256 * half;
        soff[i] = (i == 0) ? 0 : sc[i - 1];
    }
    __syncthreads();
    int b = blockIdx.x * 256 + t;
    int k = ind[b];
    atomicAdd(&lcount[k], 1);
    __syncthreads();
    for (int i = t; i < KN; i += 256) {
        int c = lcount[i];
        if (c > 0) lbase[i] = atomicAdd(&cursors[i], c);
    }
    __syncthreads();
    int pos = soff[k] + lbase[k] + atomicAdd(&lcur[k], 1);
    perm[pos] = b;
}

// ---------------------------------------------------------------------------
// Decoder + fused finalize: blocks [0, BN/4) decode one wave per sample
// (load-balanced under histogram skew); block BN/4 runs finalize.
// ---------------------------------------------------------------------------
__global__ __launch_bounds__(256) void decode_kernel(const float* __restrict__ EX,
                                                     const int* __restrict__ perm,
                                                     const int* __restrict__ ind,
                                                     const float* __restrict__ W1,
                                                     const float* __restrict__ b1,
                                                     const float* __restrict__ W2,
                                                     const float* __restrict__ b2,
                                                     float* __restrict__ dec,
                                                     const int* __restrict__ counts,
                                                     const float* __restrict__ diffsum,
                                                     const float* __restrict__ colsum,
                                                     const float* __restrict__ w0,
                                                     const float* __restrict__ bf2,
                                                     float* __restrict__ out_diff,
                                                     float* __restrict__ out_perp) {
    if (blockIdx.x < BN / 4) {
        __shared__ float exs[4][DIN];
        __shared__ float h2s[4][DH];
        int t = threadIdx.x;
        int w = t >> 6, l = t & 63;
        int s = blockIdx.x * 4 + w;
        int b = perm[s];
        int k = ind[b];
        exs[w][l] = EX[(size_t)b * DIN + l];
        __syncthreads();
        const float* w1 = W1 + (size_t)k * (DIN * DH);
        float h = b1[(size_t)k * DH + l];
        #pragma unroll
        for (int j = 0; j < DIN; ++j)
            h = fmaf(exs[w][j], w1[(size_t)j * DH + l], h);
        h2s[w][l] = fmaxf(h, 0.f);
        __syncthreads();
        if (l < DY) {
            const float* w2 = W2 + (size_t)k * (DH * DY);
            float d = b2[(size_t)k * DY + l];
            #pragma unroll
            for (int j = 0; j < DH; ++j)
                d = fmaf(h2s[w][j], w2[(size_t)j * DY + l], d);
            dec[(size_t)b * DY + l] = d;
        }
        return;
    }
    // ---- finalize (single block) ----
    __shared__ float sf[256];
    int t = threadIdx.x;
    float term = 0.f, dotp = 0.f, bbp = 0.f;
    #pragma unroll
    for (int i = 0; i < 2; ++i) {
        int k = t + 256 * i;
        int c = counts[k];
        double p = (double)c / (double)BN;
        term += (float)(-p * log(p + 1e-10));
        dotp += colsum[k] * w0[k];
    }
    for (int d = t; d < ED; d += 256) { float v = bf2[d]; bbp = fmaf(v, v, bbp); }
    sf[t] = dotp; __syncthreads();
    for (int s = 128; s > 0; s >>= 1) { if (t < s) sf[t] += sf[t + s]; __syncthreads(); }
    float dot_all = sf[0];
    __syncthreads();
    sf[t] = bbp; __syncthreads();
    for (int s = 128; s > 0; s >>= 1) { if (t < s) sf[t] += sf[t + s]; __syncthreads(); }
    float bb = sf[0];
    __syncthreads();
    sf[t] = term; __syncthreads();
    for (int s = 128; s > 0; s >>= 1) { if (t < s) sf[t] += sf[t + s]; __syncthreads(); }
    if (t == 0) {
        *out_perp = expf(sf[0]);
        *out_diff = (diffsum[0] + 2.f * dot_all + (float)BN * bb) /
                    ((float)BN * (float)ED);
    }
}

// ---------------------------------------------------------------------------
extern "C" void kernel_launch(void* const* d_in, const int* in_sizes, int n_in,
                              void* d_out, int out_size, void* d_ws, size_t ws_size,
                              hipStream_t stream) {
    const float* x     = (const float*)d_in[0];
    const float* Wf1   = (const float*)d_in[1];
    const float* bf1   = (const float*)d_in[2];
    const float* Wf2   = (const float*)d_in[3];
    const float* bf2   = (const float*)d_in[4];
    const float* Wx1   = (const float*)d_in[5];
    const float* bx1   = (const float*)d_in[6];
    const float* Wx2   = (const float*)d_in[7];
    const float* bx2   = (const float*)d_in[8];
    const float* embed = (const float*)d_in[9];
    const float* W1    = (const float*)d_in[10];
    const float* b1    = (const float*)d_in[11];
    const float* W2    = (const float*)d_in[12];
    const float* b2    = (const float*)d_in[13];
    float* out = (float*)d_out;

    char* ws = (char*)d_ws;
    size_t off = 0;
    auto carve = [&](size_t bytes) -> void* {
        void* p = ws + off;
        off += (bytes + 255) & ~(size_t)255;
        return p;
    };
    _Float16* XPs   = (_Float16*)carve((size_t)BN * INC * 2);    // 4.2 MB
    _Float16* XPl   = (_Float16*)carve((size_t)BN * INC * 2);
    _Float16* WfxPs = (_Float16*)carve((size_t)1024 * INC * 2);
    _Float16* WfxPl = (_Float16*)carve((size_t)1024 * INC * 2);
    float*    bfx   = (float*)carve(1024 * 4);
    _Float16* Wx2Ps = (_Float16*)carve((size_t)DIN * CH * 2);
    _Float16* Wx2Pl = (_Float16*)carve((size_t)DIN * CH * 2);
    _Float16* WfPs  = (_Float16*)carve((size_t)CH * ED * 2);     // 6.4 MB
    _Float16* WfPl  = (_Float16*)carve((size_t)CH * ED * 2);
    _Float16* EmPs  = (_Float16*)carve((size_t)KN * ED * 2);
    _Float16* EmPl  = (_Float16*)carve((size_t)KN * ED * 2);
    // WeP[24] + GP[8] partial buffers (32 MB, dead after wepackgred).
    float*    WeP = (float*)carve((size_t)(NZWE + NZG) * KN * KN * 4);
    float*    GP  = WeP + (size_t)NZWE * KN * KN;
    _Float16* WePs = (_Float16*)carve((size_t)KN * CH * 2);
    _Float16* WePl = (_Float16*)carve((size_t)KN * CH * 2);
    _Float16* GhPs = (_Float16*)carve((size_t)KN * KN * 2);      // 0.5 MB
    float*    EX   = (float*)carve((size_t)BN * DIN * 4);        // 4.2 MB
    float*    s2p  = (float*)carve(8 * KN * 4);
    float*    bep  = (float*)carve(8 * KN * 4);
    float*    s2   = (float*)carve(KN * 4);
    float*    be   = (float*)carve(KN * 4);
    char* zbase = ws + off;                                      // ---- zero region ----
    float* w0    = (float*)carve(CH * 4);
    float* colsum= (float*)carve(CH * 4);
    int*   counts= (int*)carve(KN * 4);
    int*   cursors=(int*)carve(KN * 4);
    float* diffsum=(float*)carve(256);
    size_t zbytes = (size_t)(ws + off - zbase);                  // ---- end zero region ----
    int*   ind     = (int*)carve(BN * 4);
    int*   perm    = (int*)carve(BN * 4);
    (void)in_sizes; (void)n_in; (void)out_size; (void)ws_size;

    hipMemsetAsync(zbase, 0, zbytes, stream);
    packall_kernel<<<5388, 256, 0, stream>>>(x, Wf1, Wx1, bf1, bx1, Wx2, Wf2, bf2,
                                             embed, XPs, XPl, WfxPs, WfxPl, bfx,
                                             Wx2Ps, Wx2Pl, WfPs, WfPl, EmPs, EmPl,
                                             s2p, bep, w0);
    mfma_weg_kernel<<<dim3(4, 4, NZWE + NZG), 512, 0, stream>>>(WfPs, WfPl,
                                                                EmPs, EmPl,
                                                                WeP, GP);
    wepackgred_kernel<<<2049, 256, 0, stream>>>(WeP, GP, s2p, bep,
                                                WePs, WePl, GhPs, s2, be);
    enc1_kernel<<<dim3(BN / 32, 2), 512, 0, stream>>>(XPs, XPl, WfxPs, WfxPl, bfx,
                                                      Wx2Ps, Wx2Pl, bx2,
                                                      WePs, WePl, GhPs, s2, be,
                                                      colsum, EX,
                                                      ind, out + OUT_IND, counts,
                                                      diffsum);
    scatter_kernel<<<BN / 256, 256, 0, stream>>>(ind, counts, cursors, perm);
    decode_kernel<<<BN / 4 + 1, 256, 0, stream>>>(EX, perm, ind, W1, b1, W2, b2,
                                                  out + OUT_DEC,
                                                  counts, diffsum, colsum, w0, bf2,
                                                  out + OUT_DIFF, out + OUT_PERP);
}

// Round 13
// 306.836 us; speedup vs baseline: 1.0177x; 1.0103x over previous
//
#include <hip/hip_runtime.h>
#include <math.h>

// Problem constants
#define BN     16384
#define INC    128
#define CH     512
#define ED     6240
#define KN     512      // NUM_EMB
#define DIN    64
#define DH     64
#define DY     32
#define NCW    195      // ED/32 k-chunks for Wf2/embed packing
#define CHP    (CH + 8) // padded LDS row stride (halves)
#define NZWE   24       // We K-slices (3-pass -> ~24.4 work units each)
#define NZG    8       // G  K-slices (1-pass -> ~24.4 work units each)

// d_out layout (float32): dec[16384*32] | diff[1] | embed_ind[16384] | perplexity[1]
#define OUT_DEC   0
#define OUT_DIFF  (BN*DY)
#define OUT_IND   (BN*DY + 1)
#define OUT_PERP  (BN*DY + 1 + BN)

typedef _Float16 half8 __attribute__((ext_vector_type(8)));
typedef float    f32x4 __attribute__((ext_vector_type(4)));
#define MFMA16(a, b, c) __builtin_amdgcn_mfma_f32_16x16x32_f16(a, b, c, 0, 0, 0)

// Packed fragment-tile layout: element (row r within 16-row tile `tile`,
// k-dim index d) lives at ((tile*NC + d/32)*64 + ((d%32)/8)*16 + (r%16))*8 + d%8.
__device__ __forceinline__ size_t paddr(int tile, int NC, int c, int lane, int e) {
    return ((size_t)(tile * NC + c) * 64 + lane) * 8 + e;
}

// ---------------------------------------------------------------------------
// packall (R16): vectorized-store packers.
// Block ranges: [0,1560) splitwf2 | [..,4680) embt | [..,4808) s2bep |
// [..,5320) xpack | [..,5384) wfxpack | [..,5388) wx2pack.
// ---------------------------------------------------------------------------
__global__ __launch_bounds__(256) void packall_kernel(
        const float* __restrict__ x,
        const float* __restrict__ Wf1, const float* __restrict__ Wx1,
        const float* __restrict__ bf1, const float* __restrict__ bx1,
        const float* __restrict__ Wx2,
        const float* __restrict__ Wf2, const float* __restrict__ bf2,
        const float* __restrict__ embed,
        _Float16* __restrict__ XPs, _Float16* __restrict__ XPl,
        _Float16* __restrict__ WfxPs, _Float16* __restrict__ WfxPl,
        float* __restrict__ bfx,
        _Float16* __restrict__ Wx2Ps, _Float16* __restrict__ Wx2Pl,
        _Float16* __restrict__ WfPs, _Float16* __restrict__ WfPl,
        _Float16* __restrict__ EmPs, _Float16* __restrict__ EmPl,
        float* __restrict__ s2p, float* __restrict__ bep,
        float* __restrict__ w0) {
    __shared__ __align__(16) char smem[16384];
    int id = blockIdx.x;
    int t = threadIdx.x;
    if (id < 1560) {
        // ---- splitwf2: Wf2 -> packed hi/lo (half8 stores) + w0 partials ----
        int bx = id % NCW, by = id / NCW;       // by in [0,8)
        int jl = t >> 2, e8 = t & 3;
        int j = by * 64 + jl;
        int d0 = bx * 32 + e8 * 8;
        float4 v0 = *(const float4*)&Wf2[(size_t)j * ED + d0];
        float4 v1 = *(const float4*)&Wf2[(size_t)j * ED + d0 + 4];
        float4 b0 = *(const float4*)&bf2[d0];
        float4 b1 = *(const float4*)&bf2[d0 + 4];
        float vv[8] = {v0.x, v0.y, v0.z, v0.w, v1.x, v1.y, v1.z, v1.w};
        float bb[8] = {b0.x, b0.y, b0.z, b0.w, b1.x, b1.y, b1.z, b1.w};
        half8 hh, ll;
        float s = 0.f;
        #pragma unroll
        for (int e = 0; e < 8; ++e) {
            float v = vv[e];
            _Float16 hi = (_Float16)v;
            hh[e] = hi;
            ll[e] = (_Float16)(v - (float)hi);
            s = fmaf(v, bb[e], s);
        }
        size_t a = paddr(j >> 4, NCW, bx, e8 * 16 + (j & 15), 0);
        *(half8*)(WfPs + a) = hh;
        *(half8*)(WfPl + a) = ll;
        s += __shfl_xor(s, 1);
        s += __shfl_xor(s, 2);
        if (e8 == 0) atomicAdd(&w0[j], s);
    } else if (id < 4680) {
        // ---- embt: embed transpose+split (half8 stores) ----
        float (*tile)[33] = (float(*)[33])smem; // tile[di][ki]
        int sub = id - 1560;
        int bx = sub % NCW, by = sub / NCW;
        int dl = t >> 5, kl = t & 31;
        #pragma unroll
        for (int r = 0; r < 4; ++r)
            tile[dl + 8 * r][kl] = embed[(size_t)(bx * 32 + dl + 8 * r) * KN
                                         + by * 32 + kl];
        __syncthreads();
        if (t < 128) {
            int g = t >> 5, kl2 = t & 31;       // g: d-group 0..3
            int k = by * 32 + kl2;
            half8 hh, ll;
            #pragma unroll
            for (int e = 0; e < 8; ++e) {
                float v = tile[g * 8 + e][kl2];
                _Float16 hi = (_Float16)v;
                hh[e] = hi;
                ll[e] = (_Float16)(v - (float)hi);
            }
            size_t a = paddr(k >> 4, NCW, bx, g * 16 + (k & 15), 0);
            *(half8*)(EmPs + a) = hh;
            *(half8*)(EmPl + a) = ll;
        }
    } else if (id < 4808) {
        // ---- s2bep: deterministic s2/be partials (fixed-order, no atomics) ----
        float (*rs)[33] = (float(*)[33])smem;
        float (*rb)[33] = (float(*)[33])(smem + 8 * 33 * 4);
        int sub = id - 4680;
        int bx = sub % 16, by = sub / 16;
        int kl = t & 31, dl = t >> 5;
        int kb = bx * 32;
        int d0 = by * 780;
        float s = 0.f, b = 0.f;
        for (int d = d0 + dl; d < d0 + 780; d += 8) {
            float e = embed[(size_t)d * KN + kb + kl];
            s = fmaf(e, e, s);
            b = fmaf(bf2[d], e, b);
        }
        rs[dl][kl] = s; rb[dl][kl] = b;
        __syncthreads();
        if (t < 32) {
            float ss = 0.f, bb = 0.f;
            #pragma unroll
            for (int i = 0; i < 8; ++i) { ss += rs[i][t]; bb += rb[i][t]; }
            s2p[by * KN + kb + t] = ss;
            bep[by * KN + kb + t] = bb;
        }
    } else if (id < 5320) {
        // ---- xpack: x -> XPs/XPl ----
        float (*xt)[INC] = (float(*)[INC])smem;
        int m0 = (id - 4808) * 32;
        for (int i = t; i < 32 * (INC / 4); i += 256) {
            int row = i >> 5, c4 = (i & 31) << 2;
            *(float4*)&xt[row][c4] = *(const float4*)&x[(size_t)(m0 + row) * INC + c4];
        }
        __syncthreads();
        int ta = m0 >> 4;
        #pragma unroll
        for (int i = 0; i < 2; ++i) {
            int idx = t + 256 * i;
            int tile2 = idx >> 8;
            int c = (idx >> 6) & 3;
            int lane = idx & 63;
            int m = tile2 * 16 + (lane & 15);
            int d0 = c * 32 + ((lane >> 4) << 3);
            half8 hh, ll;
            #pragma unroll
            for (int e = 0; e < 8; ++e) {
                float v = xt[m][d0 + e];
                _Float16 hi = (_Float16)v;
                hh[e] = hi;
                ll[e] = (_Float16)(v - (float)hi);
            }
            *(half8*)(XPs + paddr(ta + tile2, 4, c, lane, 0)) = hh;
            *(half8*)(XPl + paddr(ta + tile2, 4, c, lane, 0)) = ll;
        }
    } else if (id < 5384) {
        // ---- wfxpack: fused Wf1|Wx1 cols + bfx ----
        int tile = id - 5320;
        for (int i = t; i < 2048; i += 256) {
            int c = i >> 9, lane = (i >> 3) & 63, e = i & 7;
            int n = tile * 16 + (lane & 15);
            int d = c * 32 + ((lane >> 4) << 3) + e;
            float v = (n < 512) ? Wf1[(size_t)d * CH + n] : Wx1[(size_t)d * CH + n - 512];
            _Float16 hi = (_Float16)v;
            size_t a = paddr(tile, 4, c, lane, e);
            WfxPs[a] = hi;
            WfxPl[a] = (_Float16)(v - (float)hi);
        }
        if (tile == 0)
            for (int j = t; j < 512; j += 256) { bfx[j] = bf1[j]; bfx[512 + j] = bx1[j]; }
    } else {
        // ---- wx2pack ----
        int tile = id - 5384;
        for (int i = t; i < 8192; i += 256) {
            int c = i >> 9, lane = (i >> 3) & 63, e = i & 7;
            int n = tile * 16 + (lane & 15);
            int d = c * 32 + ((lane >> 4) << 3) + e;
            float v = Wx2[(size_t)d * DIN + n];
            _Float16 hi = (_Float16)v;
            size_t a = paddr(tile, 16, c, lane, e);
            Wx2Ps[a] = hi;
            Wx2Pl[a] = (_Float16)(v - (float)hi);
        }
    }
}

// ---------------------------------------------------------------------------
// Merged precompute GEMMs (R19): grid (4,4,32), block 512 -> 512 blocks =
// 2 blocks/CU. Work-balanced z-split: z<24 -> We slice (3-pass); z>=24 ->
// G slice (1-pass). Partials: (24+8) MB = 32 MB.
// ---------------------------------------------------------------------------
__global__ __launch_bounds__(512) void mfma_weg_kernel(
        const _Float16* __restrict__ WfPs, const _Float16* __restrict__ WfPl,
        const _Float16* __restrict__ EmPs, const _Float16* __restrict__ EmPl,
        float* __restrict__ WeP, float* __restrict__ GP) {
    int t = threadIdx.x;
    int w = t >> 6, L = t & 63;
    int lane16 = L & 15, quad = L >> 4;
    int m0 = blockIdx.x * 128 + (w & 3) * 32;
    int n0 = blockIdx.y * 128 + (w >> 2) * 64;
    int ta = m0 >> 4, tb = n0 >> 4;
    int zraw = blockIdx.z;
    bool isWe = zraw < NZWE;
    int z, c0, cnt;
    if (isWe) {
        z = zraw;
        int base = NCW / NZWE, rem = NCW % NZWE;    // 8, 3
        c0 = z * base + (z < rem ? z : rem);
        cnt = base + (z < rem ? 1 : 0);
    } else {
        z = zraw - NZWE;
        int base = NCW / NZG, rem = NCW % NZG;      // 24, 3
        c0 = z * base + (z < rem ? z : rem);
        cnt = base + (z < rem ? 1 : 0);
    }
    f32x4 acc[2][4];
    #pragma unroll
    for (int rt = 0; rt < 2; ++rt)
        #pragma unroll
        for (int tt = 0; tt < 4; ++tt) acc[rt][tt] = (f32x4){0.f, 0.f, 0.f, 0.f};
    if (isWe) {
        for (int ci = 0; ci < cnt; ++ci) {
            int c = c0 + ci;
            size_t oa0 = paddr(ta, NCW, c, L, 0), oa1 = paddr(ta + 1, NCW, c, L, 0);
            half8 A0h = *(const half8*)(WfPs + oa0);
            half8 A0l = *(const half8*)(WfPl + oa0);
            half8 A1h = *(const half8*)(WfPs + oa1);
            half8 A1l = *(const half8*)(WfPl + oa1);
            #pragma unroll
            for (int tt = 0; tt < 4; ++tt) {
                size_t ob = paddr(tb + tt, NCW, c, L, 0);
                half8 Bh = *(const half8*)(EmPs + ob);
                half8 Bl8 = *(const half8*)(EmPl + ob);
                acc[0][tt] = MFMA16(A0h, Bl8, MFMA16(A0l, Bh, MFMA16(A0h, Bh, acc[0][tt])));
                acc[1][tt] = MFMA16(A1h, Bl8, MFMA16(A1l, Bh, MFMA16(A1h, Bh, acc[1][tt])));
            }
        }
    } else {
        for (int ci = 0; ci < cnt; ++ci) {
            int c = c0 + ci;
            half8 A0h = *(const half8*)(WfPs + paddr(ta, NCW, c, L, 0));
            half8 A1h = *(const half8*)(WfPs + paddr(ta + 1, NCW, c, L, 0));
            #pragma unroll
            for (int tt = 0; tt < 4; ++tt) {
                half8 Bh = *(const half8*)(WfPs + paddr(tb + tt, NCW, c, L, 0));
                acc[0][tt] = MFMA16(A0h, Bh, acc[0][tt]);
                acc[1][tt] = MFMA16(A1h, Bh, acc[1][tt]);
            }
        }
    }
    float* C = (isWe ? WeP : GP) + (size_t)z * KN * KN;
    #pragma unroll
    for (int rt = 0; rt < 2; ++rt)
        #pragma unroll
        for (int tt = 0; tt < 4; ++tt)
            #pragma unroll
            for (int r = 0; r < 4; ++r)
                C[(size_t)(m0 + rt * 16 + quad * 4 + r) * KN
                  + n0 + tt * 16 + lane16] = acc[rt][tt][r];
}

// ---------------------------------------------------------------------------
// Merged reducers (R23): blocks [0,1024) wepack (24 partials, fixed order ->
// deterministic; NOW writes the hi/lo pair INTERLEAVED into one buffer WeI:
// hi half8 at base*16, lo half8 at base*16+8 -> each (Bh,Bl) pair shares a
// 128B line so enc1's second load merges into the first's L2 miss);
// [1024,2048) gred (8 partials, packs G to fp16-hi B-frags); block 2048
// sbered.
// ---------------------------------------------------------------------------
__global__ __launch_bounds__(256) void wepackgred_kernel(
        const float* __restrict__ WeP, const float* __restrict__ GP,
        const float* __restrict__ s2p, const float* __restrict__ bep,
        _Float16* __restrict__ WeI,
        _Float16* __restrict__ GhPs, float* __restrict__ s2,
        float* __restrict__ be) {
    int id = blockIdx.x;
    int t = threadIdx.x;
    if (id < 1024) {
        int g = id * 256 + t;                   // j*512 + k
        int j = g >> 9, k = g & 511;
        float v = 0.f;
        #pragma unroll
        for (int z = 0; z < NZWE; ++z) v += WeP[(size_t)z * KN * KN + g];
        _Float16 hi = (_Float16)v;
        size_t a = paddr(k >> 4, 16, j >> 5, ((j & 31) >> 3) * 16 + (k & 15), j & 7);
        size_t ab = a & ~(size_t)7;             // half8 base
        size_t e  = a & 7;
        WeI[2 * ab + e]     = hi;
        WeI[2 * ab + 8 + e] = (_Float16)(v - (float)hi);
    } else if (id < 2048) {
        int g = (id - 1024) * 256 + t;          // m*512 + n (G symmetric)
        int m = g >> 9, n = g & 511;
        float v = 0.f;
        #pragma unroll
        for (int z = 0; z < NZG; ++z) v += GP[(size_t)z * KN * KN + g];
        GhPs[paddr(n >> 4, 16, m >> 5, ((m & 31) >> 3) * 16 + (n & 15), m & 7)]
            = (_Float16)v;
    } else {
        #pragma unroll
        for (int i = 0; i < 2; ++i) {
            int k = t + 256 * i;
            float s = 0.f, b = 0.f;
            #pragma unroll
            for (int y = 0; y < 8; ++y) {
                s += s2p[y * KN + k];
                b += bep[y * KN + k];
            }
            s2[k] = s;
            be[k] = b;
        }
    }
}

// ---------------------------------------------------------------------------
// Fused MFMA encoder + SCORE + hGh (R23 = R19 body with the score loop's
// B-pair read from the interleaved WeI buffer: Bh at ob*2, Bl at ob*2+8 —
// same values, same MFMA order -> bit-identical; halves the independent
// L2-miss count of the score loop's latency chain).
// y=0: h=relu(x@Wf1+bf1) -> LDS -> colsum, score GEMM h.We + argmin + hGh.
// y=1: hx=relu(x@Wx1+bx1) -> LDS -> EX = hx@Wx2+bx2.
// ---------------------------------------------------------------------------
__global__ __launch_bounds__(512) void enc1_kernel(
        const _Float16* __restrict__ XPs, const _Float16* __restrict__ XPl,
        const _Float16* __restrict__ WfxPs, const _Float16* __restrict__ WfxPl,
        const float* __restrict__ bfx,
        const _Float16* __restrict__ Wx2Ps, const _Float16* __restrict__ Wx2Pl,
        const float* __restrict__ bx2,
        const _Float16* __restrict__ WeI,
        const _Float16* __restrict__ GhPs,
        const float* __restrict__ s2, const float* __restrict__ be,
        float* __restrict__ colsum,
        float* __restrict__ EX,
        int* __restrict__ ind, float* __restrict__ out_ind,
        int* __restrict__ counts, float* __restrict__ diffsum) {
    __shared__ _Float16 hhi[32][CHP];
    __shared__ _Float16 hlo[32][CHP];
    __shared__ float redv[8][32];
    __shared__ int   redi[8][32];
    __shared__ float fin[32];
    __shared__ float gpart[8];
    int t = threadIdx.x;
    int w = t >> 6, L = t & 63;
    int l16 = L & 15, quad = L >> 4;
    int m0 = blockIdx.x * 32;
    int ta = m0 >> 4;
    int enc = blockIdx.y;
    int n0 = enc * 512 + w * 64;
    int tb = n0 >> 4;
    f32x4 acc[2][4];
    #pragma unroll
    for (int rt = 0; rt < 2; ++rt)
        #pragma unroll
        for (int tt = 0; tt < 4; ++tt) acc[rt][tt] = (f32x4){0.f, 0.f, 0.f, 0.f};
    #pragma unroll
    for (int c = 0; c < 4; ++c) {
        size_t oa0 = paddr(ta, 4, c, L, 0), oa1 = paddr(ta + 1, 4, c, L, 0);
        half8 A0h = *(const half8*)(XPs + oa0);
        half8 A0l = *(const half8*)(XPl + oa0);
        half8 A1h = *(const half8*)(XPs + oa1);
        half8 A1l = *(const half8*)(XPl + oa1);
        #pragma unroll
        for (int tt = 0; tt < 4; ++tt) {
            size_t ob = paddr(tb + tt, 4, c, L, 0);
            half8 Bh = *(const half8*)(WfxPs + ob);
            half8 Bl8 = *(const half8*)(WfxPl + ob);
            acc[0][tt] = MFMA16(A0h, Bl8, MFMA16(A0l, Bh, MFMA16(A0h, Bh, acc[0][tt])));
            acc[1][tt] = MFMA16(A1h, Bl8, MFMA16(A1l, Bh, MFMA16(A1h, Bh, acc[1][tt])));
        }
    }
    #pragma unroll
    for (int rt = 0; rt < 2; ++rt)
        #pragma unroll
        for (int tt = 0; tt < 4; ++tt) {
            int col = w * 64 + tt * 16 + l16;
            float bias = bfx[enc * 512 + col];
            #pragma unroll
            for (int r = 0; r < 4; ++r) {
                int row = rt * 16 + quad * 4 + r;
                float v = fmaxf(acc[rt][tt][r] + bias, 0.f);
                _Float16 hi = (_Float16)v;
                hhi[row][col] = hi;
                hlo[row][col] = (_Float16)(v - (float)hi);
            }
        }
    __syncthreads();
    if (enc == 0) {
        float s = 0.f;
        #pragma unroll
        for (int r = 0; r < 32; ++r) s += (float)hhi[r][t] + (float)hlo[r][t];
        atomicAdd(&colsum[t], s);
        int colbase = w * 64;
        int tbs = w * 4;
        float cks[4];
        #pragma unroll
        for (int tt = 0; tt < 4; ++tt) {
            int c = colbase + tt * 16 + l16;
            cks[tt] = 0.5f * s2[c] - be[c];
        }
        #pragma unroll
        for (int rt = 0; rt < 2; ++rt)
            #pragma unroll
            for (int tt = 0; tt < 4; ++tt) acc[rt][tt] = (f32x4){0.f, 0.f, 0.f, 0.f};
        const _Float16* hA0 = &hhi[l16][quad << 3];
        const _Float16* lA0 = &hlo[l16][quad << 3];
        const _Float16* hA1 = &hhi[16 + l16][quad << 3];
        const _Float16* lA1 = &hlo[16 + l16][quad << 3];
        for (int c = 0; c < 16; ++c) {
            int d0 = c * 32;
            half8 A0h = *(const half8*)(hA0 + d0);
            half8 A0l = *(const half8*)(lA0 + d0);
            half8 A1h = *(const half8*)(hA1 + d0);
            half8 A1l = *(const half8*)(lA1 + d0);
            #pragma unroll
            for (int tt = 0; tt < 4; ++tt) {
                size_t ob = paddr(tbs + tt, 16, c, L, 0) * 2;
                half8 Bh = *(const half8*)(WeI + ob);
                half8 Bl8 = *(const half8*)(WeI + ob + 8);
                acc[0][tt] = MFMA16(A0h, Bl8, MFMA16(A0l, Bh, MFMA16(A0h, Bh, acc[0][tt])));
                acc[1][tt] = MFMA16(A1h, Bl8, MFMA16(A1l, Bh, MFMA16(A1h, Bh, acc[1][tt])));
            }
        }
        #pragma unroll
        for (int rt = 0; rt < 2; ++rt) {
            #pragma unroll
            for (int r = 0; r < 4; ++r) {
                float mv = cks[0] - acc[rt][0][r];
                int mi = colbase + l16;
                #pragma unroll
                for (int tt = 1; tt < 4; ++tt) {
                    float v = cks[tt] - acc[rt][tt][r];
                    int c = colbase + tt * 16 + l16;
                    if (v < mv || (v == mv && c < mi)) { mv = v; mi = c; }
                }
                #pragma unroll
                for (int d = 1; d < 16; d <<= 1) {
                    float ov = __shfl_xor(mv, d);
                    int oi = __shfl_xor(mi, d);
                    if (ov < mv || (ov == mv && oi < mi)) { mv = ov; mi = oi; }
                }
                if (l16 == 0) {
                    int row = rt * 16 + quad * 4 + r;
                    redv[w][row] = mv; redi[w][row] = mi;
                }
            }
        }
        // ---- hGh pass (separate loop, reuses acc after argmin consumed) ----
        #pragma unroll
        for (int rt = 0; rt < 2; ++rt)
            #pragma unroll
            for (int tt = 0; tt < 4; ++tt) acc[rt][tt] = (f32x4){0.f, 0.f, 0.f, 0.f};
        for (int c = 0; c < 16; ++c) {
            int d0 = c * 32;
            half8 A0h = *(const half8*)(hA0 + d0);
            half8 A1h = *(const half8*)(hA1 + d0);
            #pragma unroll
            for (int tt = 0; tt < 4; ++tt) {
                half8 Gh = *(const half8*)(GhPs + paddr(tbs + tt, 16, c, L, 0));
                acc[0][tt] = MFMA16(A0h, Gh, acc[0][tt]);
                acc[1][tt] = MFMA16(A1h, Gh, acc[1][tt]);
            }
        }
        float gs = 0.f;
        #pragma unroll
        for (int rt = 0; rt < 2; ++rt)
            #pragma unroll
            for (int tt = 0; tt < 4; ++tt) {
                int col = colbase + tt * 16 + l16;
                #pragma unroll
                for (int r = 0; r < 4; ++r) {
                    int row = rt * 16 + quad * 4 + r;
                    gs += acc[rt][tt][r] * (float)hhi[row][col];
                }
            }
        #pragma unroll
        for (int d = 1; d < 64; d <<= 1) gs += __shfl_xor(gs, d);
        if (L == 0) gpart[w] = gs;
        __syncthreads();
        if (t < 32) {
            float mv = redv[0][t]; int mi = redi[0][t];
            #pragma unroll
            for (int w2 = 1; w2 < 8; ++w2) {
                float ov = redv[w2][t]; int oi = redi[w2][t];
                if (ov < mv || (ov == mv && oi < mi)) { mv = ov; mi = oi; }
            }
            int b = m0 + t;
            ind[b] = mi;
            out_ind[b] = (float)mi;
            atomicAdd(&counts[mi], 1);
            fin[t] = 2.f * mv;
        }
        __syncthreads();
        if (t == 0) {
            float s = 0.f;
            #pragma unroll
            for (int i = 0; i < 32; ++i) s += fin[i];
            #pragma unroll
            for (int w2 = 0; w2 < 8; ++w2) s += gpart[w2];
            atomicAdd(diffsum, s);
        }
    } else {
        int rt = w & 1, ct = w >> 1;
        f32x4 eacc = (f32x4){0.f, 0.f, 0.f, 0.f};
        for (int c = 0; c < 16; ++c) {
            int d0 = c * 32 + (quad << 3);
            int m = rt * 16 + l16;
            half8 Ah = *(half8*)(&hhi[m][d0]);
            half8 Al = *(half8*)(&hlo[m][d0]);
            size_t ob = paddr(ct, 16, c, L, 0);
            half8 Bh = *(const half8*)(Wx2Ps + ob);
            half8 Bl8 = *(const half8*)(Wx2Pl + ob);
            eacc = MFMA16(Ah, Bl8, MFMA16(Al, Bh, MFMA16(Ah, Bh, eacc)));
        }
        int col = ct * 16 + l16;
        float bias = bx2[col];
        #pragma unroll
        for (int r = 0; r < 4; ++r) {
            int row = m0 + rt * 16 + quad * 4 + r;
            EX[(size_t)row * DIN + col] = eacc[r] + bias;
        }
    }
}

// ---------------------------------------------------------------------------
// Scatter (R22): Hillis-Steele parallel prefix scan over counts (integer
// adds -> order-independent, bit-exact). Block-aggregated cursors.
// ---------------------------------------------------------------------------
__global__ __launch_bounds__(256) void scatter_kernel(const int* __restrict__ ind,
                                                      const int* __restrict__ counts,
                                                      int* __restrict__ cursors,
                                                      int* __restrict__ perm) {
    __shared__ int sc[KN], soff[KN], lcount[KN], lbase[KN], lcur[KN];
    int t = threadIdx.x;
    for (int i = t; i < KN; i += 256) {
        sc[i] = counts[i];
        lcount[i] = 0; lcur[i] = 0;
    }
    __syncthreads();
    // inclusive scan of sc[0..511], 2 elements/thread
    #pragma unroll
    for (int st = 1; st < KN; st <<= 1) {
        int i0 = t, i1 = t + 256;
        int v0 = (i0 >= st) ? sc[i0 - st] : 0;
        int v1 = (i1 >= st) ? sc[i1 - st] : 0;
        __syncthreads();
        sc[i0] += v0;
        sc[i1] += v1;
        __syncthreads();
    }
    #pragma unroll
    for (int half = 0; half < 2; ++half) {
        int i = t + 256 * half;
        soff[i] = (i == 0) ? 0 : sc[i - 1];
    }
    __syncthreads();
    int b = blockIdx.x * 256 + t;
    int k = ind[b];
    atomicAdd(&lcount[k], 1);
    __syncthreads();
    for (int i = t; i < KN; i += 256) {
        int c = lcount[i];
        if (c > 0) lbase[i] = atomicAdd(&cursors[i], c);
    }
    __syncthreads();
    int pos = soff[k] + lbase[k] + atomicAdd(&lcur[k], 1);
    perm[pos] = b;
}

// ---------------------------------------------------------------------------
// Decoder + fused finalize: blocks [0, BN/4) decode one wave per sample
// (load-balanced under histogram skew); block BN/4 runs finalize.
// ---------------------------------------------------------------------------
__global__ __launch_bounds__(256) void decode_kernel(const float* __restrict__ EX,
                                                     const int* __restrict__ perm,
                                                     const int* __restrict__ ind,
                                                     const float* __restrict__ W1,
                                                     const float* __restrict__ b1,
                                                     const float* __restrict__ W2,
                                                     const float* __restrict__ b2,
                                                     float* __restrict__ dec,
                                                     const int* __restrict__ counts,
                                                     const float* __restrict__ diffsum,
                                                     const float* __restrict__ colsum,
                                                     const float* __restrict__ w0,
                                                     const float* __restrict__ bf2,
                                                     float* __restrict__ out_diff,
                                                     float* __restrict__ out_perp) {
    if (blockIdx.x < BN / 4) {
        __shared__ float exs[4][DIN];
        __shared__ float h2s[4][DH];
        int t = threadIdx.x;
        int w = t >> 6, l = t & 63;
        int s = blockIdx.x * 4 + w;
        int b = perm[s];
        int k = ind[b];
        exs[w][l] = EX[(size_t)b * DIN + l];
        __syncthreads();
        const float* w1 = W1 + (size_t)k * (DIN * DH);
        float h = b1[(size_t)k * DH + l];
        #pragma unroll
        for (int j = 0; j < DIN; ++j)
            h = fmaf(exs[w][j], w1[(size_t)j * DH + l], h);
        h2s[w][l] = fmaxf(h, 0.f);
        __syncthreads();
        if (l < DY) {
            const float* w2 = W2 + (size_t)k * (DH * DY);
            float d = b2[(size_t)k * DY + l];
            #pragma unroll
            for (int j = 0; j < DH; ++j)
                d = fmaf(h2s[w][j], w2[(size_t)j * DY + l], d);
            dec[(size_t)b * DY + l] = d;
        }
        return;
    }
    // ---- finalize (single block) ----
    __shared__ float sf[256];
    int t = threadIdx.x;
    float term = 0.f, dotp = 0.f, bbp = 0.f;
    #pragma unroll
    for (int i = 0; i < 2; ++i) {
        int k = t + 256 * i;
        int c = counts[k];
        double p = (double)c / (double)BN;
        term += (float)(-p * log(p + 1e-10));
        dotp += colsum[k] * w0[k];
    }
    for (int d = t; d < ED; d += 256) { float v = bf2[d]; bbp = fmaf(v, v, bbp); }
    sf[t] = dotp; __syncthreads();
    for (int s = 128; s > 0; s >>= 1) { if (t < s) sf[t] += sf[t + s]; __syncthreads(); }
    float dot_all = sf[0];
    __syncthreads();
    sf[t] = bbp; __syncthreads();
    for (int s = 128; s > 0; s >>= 1) { if (t < s) sf[t] += sf[t + s]; __syncthreads(); }
    float bb = sf[0];
    __syncthreads();
    sf[t] = term; __syncthreads();
    for (int s = 128; s > 0; s >>= 1) { if (t < s) sf[t] += sf[t + s]; __syncthreads(); }
    if (t == 0) {
        *out_perp = expf(sf[0]);
        *out_diff = (diffsum[0] + 2.f * dot_all + (float)BN * bb) /
                    ((float)BN * (float)ED);
    }
}

// ---------------------------------------------------------------------------
extern "C" void kernel_launch(void* const* d_in, const int* in_sizes, int n_in,
                              void* d_out, int out_size, void* d_ws, size_t ws_size,
                              hipStream_t stream) {
    const float* x     = (const float*)d_in[0];
    const float* Wf1   = (const float*)d_in[1];
    const float* bf1   = (const float*)d_in[2];
    const float* Wf2   = (const float*)d_in[3];
    const float* bf2   = (const float*)d_in[4];
    const float* Wx1   = (const float*)d_in[5];
    const float* bx1   = (const float*)d_in[6];
    const float* Wx2   = (const float*)d_in[7];
    const float* bx2   = (const float*)d_in[8];
    const float* embed = (const float*)d_in[9];
    const float* W1    = (const float*)d_in[10];
    const float* b1    = (const float*)d_in[11];
    const float* W2    = (const float*)d_in[12];
    const float* b2    = (const float*)d_in[13];
    float* out = (float*)d_out;

    char* ws = (char*)d_ws;
    size_t off = 0;
    auto carve = [&](size_t bytes) -> void* {
        void* p = ws + off;
        off += (bytes + 255) & ~(size_t)255;
        return p;
    };
    _Float16* XPs   = (_Float16*)carve((size_t)BN * INC * 2);    // 4.2 MB
    _Float16* XPl   = (_Float16*)carve((size_t)BN * INC * 2);
    _Float16* WfxPs = (_Float16*)carve((size_t)1024 * INC * 2);
    _Float16* WfxPl = (_Float16*)carve((size_t)1024 * INC * 2);
    float*    bfx   = (float*)carve(1024 * 4);
    _Float16* Wx2Ps = (_Float16*)carve((size_t)DIN * CH * 2);
    _Float16* Wx2Pl = (_Float16*)carve((size_t)DIN * CH * 2);
    _Float16* WfPs  = (_Float16*)carve((size_t)CH * ED * 2);     // 6.4 MB
    _Float16* WfPl  = (_Float16*)carve((size_t)CH * ED * 2);
    _Float16* EmPs  = (_Float16*)carve((size_t)KN * ED * 2);
    _Float16* EmPl  = (_Float16*)carve((size_t)KN * ED * 2);
    // WeP[24] + GP[8] partial buffers (32 MB, dead after wepackgred).
    float*    WeP = (float*)carve((size_t)(NZWE + NZG) * KN * KN * 4);
    float*    GP  = WeP + (size_t)NZWE * KN * KN;
    _Float16* WeI  = (_Float16*)carve((size_t)KN * CH * 4);      // 1 MB interleaved hi|lo
    _Float16* GhPs = (_Float16*)carve((size_t)KN * KN * 2);      // 0.5 MB
    float*    EX   = (float*)carve((size_t)BN * DIN * 4);        // 4.2 MB
    float*    s2p  = (float*)carve(8 * KN * 4);
    float*    bep  = (float*)carve(8 * KN * 4);
    float*    s2   = (float*)carve(KN * 4);
    float*    be   = (float*)carve(KN * 4);
    char* zbase = ws + off;                                      // ---- zero region ----
    float* w0    = (float*)carve(CH * 4);
    float* colsum= (float*)carve(CH * 4);
    int*   counts= (int*)carve(KN * 4);
    int*   cursors=(int*)carve(KN * 4);
    float* diffsum=(float*)carve(256);
    size_t zbytes = (size_t)(ws + off - zbase);                  // ---- end zero region ----
    int*   ind     = (int*)carve(BN * 4);
    int*   perm    = (int*)carve(BN * 4);
    (void)in_sizes; (void)n_in; (void)out_size; (void)ws_size;

    hipMemsetAsync(zbase, 0, zbytes, stream);
    packall_kernel<<<5388, 256, 0, stream>>>(x, Wf1, Wx1, bf1, bx1, Wx2, Wf2, bf2,
                                             embed, XPs, XPl, WfxPs, WfxPl, bfx,
                                             Wx2Ps, Wx2Pl, WfPs, WfPl, EmPs, EmPl,
                                             s2p, bep, w0);
    mfma_weg_kernel<<<dim3(4, 4, NZWE + NZG), 512, 0, stream>>>(WfPs, WfPl,
                                                                EmPs, EmPl,
                                                                WeP, GP);
    wepackgred_kernel<<<2049, 256, 0, stream>>>(WeP, GP, s2p, bep,
                                                WeI, GhPs, s2, be);
    enc1_kernel<<<dim3(BN / 32, 2), 512, 0, stream>>>(XPs, XPl, WfxPs, WfxPl, bfx,
                                                      Wx2Ps, Wx2Pl, bx2,
                                                      WeI, GhPs, s2, be,
                                                      colsum, EX,
                                                      ind, out + OUT_IND, counts,
                                                      diffsum);
    scatter_kernel<<<BN / 256, 256, 0, stream>>>(ind, counts, cursors, perm);
    decode_kernel<<<BN / 4 + 1, 256, 0, stream>>>(EX, perm, ind, W1, b1, W2, b2,
                                                  out + OUT_DEC,
                                                  counts, diffsum, colsum, w0, bf2,
                                                  out + OUT_DIFF, out + OUT_PERP);
}

// Round 14
// 296.797 us; speedup vs baseline: 1.0521x; 1.0338x over previous
//
#include <hip/hip_runtime.h>
#include <math.h>

// Problem constants
#define BN     16384
#define INC    128
#define CH     512
#define ED     6240
#define KN     512      // NUM_EMB
#define DIN    64
#define DH     64
#define DY     32
#define NCW    195      // ED/32 k-chunks for Wf2/embed packing
#define CHP    (CH + 8) // padded LDS row stride (halves)
#define NZWE   24       // We K-slices (3-pass -> ~24.4 work units each)
#define NZG    8        // G  K-slices (1-pass -> ~24.4 work units each)

// d_out layout (float32): dec[16384*32] | diff[1] | embed_ind[16384] | perplexity[1]
#define OUT_DEC   0
#define OUT_DIFF  (BN*DY)
#define OUT_IND   (BN*DY + 1)
#define OUT_PERP  (BN*DY + 1 + BN)

typedef _Float16 half8 __attribute__((ext_vector_type(8)));
typedef float    f32x4 __attribute__((ext_vector_type(4)));
#define MFMA16(a, b, c) __builtin_amdgcn_mfma_f32_16x16x32_f16(a, b, c, 0, 0, 0)

// asm-pinned 16B global load: compiler cannot sink/fold the issue point.
#define GLOAD16(dst, addr) \
    asm volatile("global_load_dwordx4 %0, %1, off" \
                 : "=v"(dst) : "v"(addr) : "memory")

// Packed fragment-tile layout: element (row r within 16-row tile `tile`,
// k-dim index d) lives at ((tile*NC + d/32)*64 + ((d%32)/8)*16 + (r%16))*8 + d%8.
__device__ __forceinline__ size_t paddr(int tile, int NC, int c, int lane, int e) {
    return ((size_t)(tile * NC + c) * 64 + lane) * 8 + e;
}

// ---------------------------------------------------------------------------
// packall (R16): vectorized-store packers.
// Block ranges: [0,1560) splitwf2 | [..,4680) embt | [..,4808) s2bep |
// [..,5320) xpack | [..,5384) wfxpack | [..,5388) wx2pack.
// ---------------------------------------------------------------------------
__global__ __launch_bounds__(256) void packall_kernel(
        const float* __restrict__ x,
        const float* __restrict__ Wf1, const float* __restrict__ Wx1,
        const float* __restrict__ bf1, const float* __restrict__ bx1,
        const float* __restrict__ Wx2,
        const float* __restrict__ Wf2, const float* __restrict__ bf2,
        const float* __restrict__ embed,
        _Float16* __restrict__ XPs, _Float16* __restrict__ XPl,
        _Float16* __restrict__ WfxPs, _Float16* __restrict__ WfxPl,
        float* __restrict__ bfx,
        _Float16* __restrict__ Wx2Ps, _Float16* __restrict__ Wx2Pl,
        _Float16* __restrict__ WfPs, _Float16* __restrict__ WfPl,
        _Float16* __restrict__ EmPs, _Float16* __restrict__ EmPl,
        float* __restrict__ s2p, float* __restrict__ bep,
        float* __restrict__ w0) {
    __shared__ __align__(16) char smem[16384];
    int id = blockIdx.x;
    int t = threadIdx.x;
    if (id < 1560) {
        // ---- splitwf2: Wf2 -> packed hi/lo (half8 stores) + w0 partials ----
        int bx = id % NCW, by = id / NCW;       // by in [0,8)
        int jl = t >> 2, e8 = t & 3;
        int j = by * 64 + jl;
        int d0 = bx * 32 + e8 * 8;
        float4 v0 = *(const float4*)&Wf2[(size_t)j * ED + d0];
        float4 v1 = *(const float4*)&Wf2[(size_t)j * ED + d0 + 4];
        float4 b0 = *(const float4*)&bf2[d0];
        float4 b1 = *(const float4*)&bf2[d0 + 4];
        float vv[8] = {v0.x, v0.y, v0.z, v0.w, v1.x, v1.y, v1.z, v1.w};
        float bb[8] = {b0.x, b0.y, b0.z, b0.w, b1.x, b1.y, b1.z, b1.w};
        half8 hh, ll;
        float s = 0.f;
        #pragma unroll
        for (int e = 0; e < 8; ++e) {
            float v = vv[e];
            _Float16 hi = (_Float16)v;
            hh[e] = hi;
            ll[e] = (_Float16)(v - (float)hi);
            s = fmaf(v, bb[e], s);
        }
        size_t a = paddr(j >> 4, NCW, bx, e8 * 16 + (j & 15), 0);
        *(half8*)(WfPs + a) = hh;
        *(half8*)(WfPl + a) = ll;
        s += __shfl_xor(s, 1);
        s += __shfl_xor(s, 2);
        if (e8 == 0) atomicAdd(&w0[j], s);
    } else if (id < 4680) {
        // ---- embt: embed transpose+split (half8 stores) ----
        float (*tile)[33] = (float(*)[33])smem; // tile[di][ki]
        int sub = id - 1560;
        int bx = sub % NCW, by = sub / NCW;
        int dl = t >> 5, kl = t & 31;
        #pragma unroll
        for (int r = 0; r < 4; ++r)
            tile[dl + 8 * r][kl] = embed[(size_t)(bx * 32 + dl + 8 * r) * KN
                                         + by * 32 + kl];
        __syncthreads();
        if (t < 128) {
            int g = t >> 5, kl2 = t & 31;       // g: d-group 0..3
            int k = by * 32 + kl2;
            half8 hh, ll;
            #pragma unroll
            for (int e = 0; e < 8; ++e) {
                float v = tile[g * 8 + e][kl2];
                _Float16 hi = (_Float16)v;
                hh[e] = hi;
                ll[e] = (_Float16)(v - (float)hi);
            }
            size_t a = paddr(k >> 4, NCW, bx, g * 16 + (k & 15), 0);
            *(half8*)(EmPs + a) = hh;
            *(half8*)(EmPl + a) = ll;
        }
    } else if (id < 4808) {
        // ---- s2bep: deterministic s2/be partials (fixed-order, no atomics) ----
        float (*rs)[33] = (float(*)[33])smem;
        float (*rb)[33] = (float(*)[33])(smem + 8 * 33 * 4);
        int sub = id - 4680;
        int bx = sub % 16, by = sub / 16;
        int kl = t & 31, dl = t >> 5;
        int kb = bx * 32;
        int d0 = by * 780;
        float s = 0.f, b = 0.f;
        for (int d = d0 + dl; d < d0 + 780; d += 8) {
            float e = embed[(size_t)d * KN + kb + kl];
            s = fmaf(e, e, s);
            b = fmaf(bf2[d], e, b);
        }
        rs[dl][kl] = s; rb[dl][kl] = b;
        __syncthreads();
        if (t < 32) {
            float ss = 0.f, bb = 0.f;
            #pragma unroll
            for (int i = 0; i < 8; ++i) { ss += rs[i][t]; bb += rb[i][t]; }
            s2p[by * KN + kb + t] = ss;
            bep[by * KN + kb + t] = bb;
        }
    } else if (id < 5320) {
        // ---- xpack: x -> XPs/XPl ----
        float (*xt)[INC] = (float(*)[INC])smem;
        int m0 = (id - 4808) * 32;
        for (int i = t; i < 32 * (INC / 4); i += 256) {
            int row = i >> 5, c4 = (i & 31) << 2;
            *(float4*)&xt[row][c4] = *(const float4*)&x[(size_t)(m0 + row) * INC + c4];
        }
        __syncthreads();
        int ta = m0 >> 4;
        #pragma unroll
        for (int i = 0; i < 2; ++i) {
            int idx = t + 256 * i;
            int tile2 = idx >> 8;
            int c = (idx >> 6) & 3;
            int lane = idx & 63;
            int m = tile2 * 16 + (lane & 15);
            int d0 = c * 32 + ((lane >> 4) << 3);
            half8 hh, ll;
            #pragma unroll
            for (int e = 0; e < 8; ++e) {
                float v = xt[m][d0 + e];
                _Float16 hi = (_Float16)v;
                hh[e] = hi;
                ll[e] = (_Float16)(v - (float)hi);
            }
            *(half8*)(XPs + paddr(ta + tile2, 4, c, lane, 0)) = hh;
            *(half8*)(XPl + paddr(ta + tile2, 4, c, lane, 0)) = ll;
        }
    } else if (id < 5384) {
        // ---- wfxpack: fused Wf1|Wx1 cols + bfx ----
        int tile = id - 5320;
        for (int i = t; i < 2048; i += 256) {
            int c = i >> 9, lane = (i >> 3) & 63, e = i & 7;
            int n = tile * 16 + (lane & 15);
            int d = c * 32 + ((lane >> 4) << 3) + e;
            float v = (n < 512) ? Wf1[(size_t)d * CH + n] : Wx1[(size_t)d * CH + n - 512];
            _Float16 hi = (_Float16)v;
            size_t a = paddr(tile, 4, c, lane, e);
            WfxPs[a] = hi;
            WfxPl[a] = (_Float16)(v - (float)hi);
        }
        if (tile == 0)
            for (int j = t; j < 512; j += 256) { bfx[j] = bf1[j]; bfx[512 + j] = bx1[j]; }
    } else {
        // ---- wx2pack ----
        int tile = id - 5384;
        for (int i = t; i < 8192; i += 256) {
            int c = i >> 9, lane = (i >> 3) & 63, e = i & 7;
            int n = tile * 16 + (lane & 15);
            int d = c * 32 + ((lane >> 4) << 3) + e;
            float v = Wx2[(size_t)d * DIN + n];
            _Float16 hi = (_Float16)v;
            size_t a = paddr(tile, 16, c, lane, e);
            Wx2Ps[a] = hi;
            Wx2Pl[a] = (_Float16)(v - (float)hi);
        }
    }
}

// ---------------------------------------------------------------------------
// Merged precompute GEMMs (R19): grid (4,4,32), block 512 -> 512 blocks =
// 2 blocks/CU. Work-balanced z-split: z<24 -> We slice (3-pass); z>=24 ->
// G slice (1-pass). Partials: (24+8) MB = 32 MB.
// ---------------------------------------------------------------------------
__global__ __launch_bounds__(512) void mfma_weg_kernel(
        const _Float16* __restrict__ WfPs, const _Float16* __restrict__ WfPl,
        const _Float16* __restrict__ EmPs, const _Float16* __restrict__ EmPl,
        float* __restrict__ WeP, float* __restrict__ GP) {
    int t = threadIdx.x;
    int w = t >> 6, L = t & 63;
    int lane16 = L & 15, quad = L >> 4;
    int m0 = blockIdx.x * 128 + (w & 3) * 32;
    int n0 = blockIdx.y * 128 + (w >> 2) * 64;
    int ta = m0 >> 4, tb = n0 >> 4;
    int zraw = blockIdx.z;
    bool isWe = zraw < NZWE;
    int z, c0, cnt;
    if (isWe) {
        z = zraw;
        int base = NCW / NZWE, rem = NCW % NZWE;    // 8, 3
        c0 = z * base + (z < rem ? z : rem);
        cnt = base + (z < rem ? 1 : 0);
    } else {
        z = zraw - NZWE;
        int base = NCW / NZG, rem = NCW % NZG;      // 24, 3
        c0 = z * base + (z < rem ? z : rem);
        cnt = base + (z < rem ? 1 : 0);
    }
    f32x4 acc[2][4];
    #pragma unroll
    for (int rt = 0; rt < 2; ++rt)
        #pragma unroll
        for (int tt = 0; tt < 4; ++tt) acc[rt][tt] = (f32x4){0.f, 0.f, 0.f, 0.f};
    if (isWe) {
        for (int ci = 0; ci < cnt; ++ci) {
            int c = c0 + ci;
            size_t oa0 = paddr(ta, NCW, c, L, 0), oa1 = paddr(ta + 1, NCW, c, L, 0);
            half8 A0h = *(const half8*)(WfPs + oa0);
            half8 A0l = *(const half8*)(WfPl + oa0);
            half8 A1h = *(const half8*)(WfPs + oa1);
            half8 A1l = *(const half8*)(WfPl + oa1);
            #pragma unroll
            for (int tt = 0; tt < 4; ++tt) {
                size_t ob = paddr(tb + tt, NCW, c, L, 0);
                half8 Bh = *(const half8*)(EmPs + ob);
                half8 Bl8 = *(const half8*)(EmPl + ob);
                acc[0][tt] = MFMA16(A0h, Bl8, MFMA16(A0l, Bh, MFMA16(A0h, Bh, acc[0][tt])));
                acc[1][tt] = MFMA16(A1h, Bl8, MFMA16(A1l, Bh, MFMA16(A1h, Bh, acc[1][tt])));
            }
        }
    } else {
        for (int ci = 0; ci < cnt; ++ci) {
            int c = c0 + ci;
            half8 A0h = *(const half8*)(WfPs + paddr(ta, NCW, c, L, 0));
            half8 A1h = *(const half8*)(WfPs + paddr(ta + 1, NCW, c, L, 0));
            #pragma unroll
            for (int tt = 0; tt < 4; ++tt) {
                half8 Bh = *(const half8*)(WfPs + paddr(tb + tt, NCW, c, L, 0));
                acc[0][tt] = MFMA16(A0h, Bh, acc[0][tt]);
                acc[1][tt] = MFMA16(A1h, Bh, acc[1][tt]);
            }
        }
    }
    float* C = (isWe ? WeP : GP) + (size_t)z * KN * KN;
    #pragma unroll
    for (int rt = 0; rt < 2; ++rt)
        #pragma unroll
        for (int tt = 0; tt < 4; ++tt)
            #pragma unroll
            for (int r = 0; r < 4; ++r)
                C[(size_t)(m0 + rt * 16 + quad * 4 + r) * KN
                  + n0 + tt * 16 + lane16] = acc[rt][tt][r];
}

// ---------------------------------------------------------------------------
// Merged reducers (R23): blocks [0,1024) wepack (24 partials, fixed order ->
// deterministic; writes the hi/lo pair INTERLEAVED into one buffer WeI:
// hi half8 at base*16, lo half8 at base*16+8); [1024,2048) gred (8 partials,
// packs G to fp16-hi B-frags); block 2048 sbered.
// ---------------------------------------------------------------------------
__global__ __launch_bounds__(256) void wepackgred_kernel(
        const float* __restrict__ WeP, const float* __restrict__ GP,
        const float* __restrict__ s2p, const float* __restrict__ bep,
        _Float16* __restrict__ WeI,
        _Float16* __restrict__ GhPs, float* __restrict__ s2,
        float* __restrict__ be) {
    int id = blockIdx.x;
    int t = threadIdx.x;
    if (id < 1024) {
        int g = id * 256 + t;                   // j*512 + k
        int j = g >> 9, k = g & 511;
        float v = 0.f;
        #pragma unroll
        for (int z = 0; z < NZWE; ++z) v += WeP[(size_t)z * KN * KN + g];
        _Float16 hi = (_Float16)v;
        size_t a = paddr(k >> 4, 16, j >> 5, ((j & 31) >> 3) * 16 + (k & 15), j & 7);
        size_t ab = a & ~(size_t)7;             // half8 base
        size_t e  = a & 7;
        WeI[2 * ab + e]     = hi;
        WeI[2 * ab + 8 + e] = (_Float16)(v - (float)hi);
    } else if (id < 2048) {
        int g = (id - 1024) * 256 + t;          // m*512 + n (G symmetric)
        int m = g >> 9, n = g & 511;
        float v = 0.f;
        #pragma unroll
        for (int z = 0; z < NZG; ++z) v += GP[(size_t)z * KN * KN + g];
        GhPs[paddr(n >> 4, 16, m >> 5, ((m & 31) >> 3) * 16 + (n & 15), m & 7)]
            = (_Float16)v;
    } else {
        #pragma unroll
        for (int i = 0; i < 2; ++i) {
            int k = t + 256 * i;
            float s = 0.f, b = 0.f;
            #pragma unroll
            for (int y = 0; y < 8; ++y) {
                s += s2p[y * KN + k];
                b += bep[y * KN + k];
            }
            s2[k] = s;
            be[k] = b;
        }
    }
}

// ---------------------------------------------------------------------------
// Fused MFMA encoder + SCORE + hGh (R24 = R23 body with the score loop
// software-pipelined via asm-pinned global_load_dwordx4 + counted
// s_waitcnt vmcnt(8) + sched_barrier(0): the compiler cannot sink asm
// loads (unlike R15's C++ rotation, which it folded away). Fully unrolled
// c-loop; named A/B double buffers with static indices. Same values, same
// MFMA order -> bit-identical outputs.
// ---------------------------------------------------------------------------
__global__ __launch_bounds__(512) void enc1_kernel(
        const _Float16* __restrict__ XPs, const _Float16* __restrict__ XPl,
        const _Float16* __restrict__ WfxPs, const _Float16* __restrict__ WfxPl,
        const float* __restrict__ bfx,
        const _Float16* __restrict__ Wx2Ps, const _Float16* __restrict__ Wx2Pl,
        const float* __restrict__ bx2,
        const _Float16* __restrict__ WeI,
        const _Float16* __restrict__ GhPs,
        const float* __restrict__ s2, const float* __restrict__ be,
        float* __restrict__ colsum,
        float* __restrict__ EX,
        int* __restrict__ ind, float* __restrict__ out_ind,
        int* __restrict__ counts, float* __restrict__ diffsum) {
    __shared__ _Float16 hhi[32][CHP];
    __shared__ _Float16 hlo[32][CHP];
    __shared__ float redv[8][32];
    __shared__ int   redi[8][32];
    __shared__ float fin[32];
    __shared__ float gpart[8];
    int t = threadIdx.x;
    int w = t >> 6, L = t & 63;
    int l16 = L & 15, quad = L >> 4;
    int m0 = blockIdx.x * 32;
    int ta = m0 >> 4;
    int enc = blockIdx.y;
    int n0 = enc * 512 + w * 64;
    int tb = n0 >> 4;
    f32x4 acc[2][4];
    #pragma unroll
    for (int rt = 0; rt < 2; ++rt)
        #pragma unroll
        for (int tt = 0; tt < 4; ++tt) acc[rt][tt] = (f32x4){0.f, 0.f, 0.f, 0.f};
    #pragma unroll
    for (int c = 0; c < 4; ++c) {
        size_t oa0 = paddr(ta, 4, c, L, 0), oa1 = paddr(ta + 1, 4, c, L, 0);
        half8 A0h = *(const half8*)(XPs + oa0);
        half8 A0l = *(const half8*)(XPl + oa0);
        half8 A1h = *(const half8*)(XPs + oa1);
        half8 A1l = *(const half8*)(XPl + oa1);
        #pragma unroll
        for (int tt = 0; tt < 4; ++tt) {
            size_t ob = paddr(tb + tt, 4, c, L, 0);
            half8 Bh = *(const half8*)(WfxPs + ob);
            half8 Bl8 = *(const half8*)(WfxPl + ob);
            acc[0][tt] = MFMA16(A0h, Bl8, MFMA16(A0l, Bh, MFMA16(A0h, Bh, acc[0][tt])));
            acc[1][tt] = MFMA16(A1h, Bl8, MFMA16(A1l, Bh, MFMA16(A1h, Bh, acc[1][tt])));
        }
    }
    #pragma unroll
    for (int rt = 0; rt < 2; ++rt)
        #pragma unroll
        for (int tt = 0; tt < 4; ++tt) {
            int col = w * 64 + tt * 16 + l16;
            float bias = bfx[enc * 512 + col];
            #pragma unroll
            for (int r = 0; r < 4; ++r) {
                int row = rt * 16 + quad * 4 + r;
                float v = fmaxf(acc[rt][tt][r] + bias, 0.f);
                _Float16 hi = (_Float16)v;
                hhi[row][col] = hi;
                hlo[row][col] = (_Float16)(v - (float)hi);
            }
        }
    __syncthreads();
    if (enc == 0) {
        float s = 0.f;
        #pragma unroll
        for (int r = 0; r < 32; ++r) s += (float)hhi[r][t] + (float)hlo[r][t];
        atomicAdd(&colsum[t], s);
        int colbase = w * 64;
        int tbs = w * 4;
        float cks[4];
        #pragma unroll
        for (int tt = 0; tt < 4; ++tt) {
            int c = colbase + tt * 16 + l16;
            cks[tt] = 0.5f * s2[c] - be[c];
        }
        #pragma unroll
        for (int rt = 0; rt < 2; ++rt)
            #pragma unroll
            for (int tt = 0; tt < 4; ++tt) acc[rt][tt] = (f32x4){0.f, 0.f, 0.f, 0.f};
        const _Float16* hA0 = &hhi[l16][quad << 3];
        const _Float16* lA0 = &hlo[l16][quad << 3];
        const _Float16* hA1 = &hhi[16 + l16][quad << 3];
        const _Float16* lA1 = &hlo[16 + l16][quad << 3];
        // ---- score loop: asm-pinned 1-deep pipeline, counted vmcnt ----
        const char* bbase[4];
        #pragma unroll
        for (int tt = 0; tt < 4; ++tt)
            bbase[tt] = (const char*)WeI
                        + (((size_t)(tbs + tt) * 16 * 64 + L) * 32);
        f32x4 BhA[4], BlA[4], BhB[4], BlB[4];
        #pragma unroll
        for (int tt = 0; tt < 4; ++tt) {            // prologue: issue c=0
            const char* p = bbase[tt];
            GLOAD16(BhA[tt], p);
            GLOAD16(BlA[tt], p + 16);
        }
        #pragma unroll
        for (int c = 0; c < 16; ++c) {
            f32x4* Bh4 = (c & 1) ? BhB : BhA;
            f32x4* Bl4 = (c & 1) ? BlB : BlA;
            f32x4* Nh4 = (c & 1) ? BhA : BhB;
            f32x4* Nl4 = (c & 1) ? BlA : BlB;
            if (c < 15) {
                #pragma unroll
                for (int tt = 0; tt < 4; ++tt) {
                    const char* p = bbase[tt] + (size_t)(c + 1) * 2048;
                    GLOAD16(Nh4[tt], p);
                    GLOAD16(Nl4[tt], p + 16);
                }
                asm volatile("s_waitcnt vmcnt(8)" ::: "memory");
            } else {
                asm volatile("s_waitcnt vmcnt(0)" ::: "memory");
            }
            __builtin_amdgcn_sched_barrier(0);
            int d0 = c * 32;
            half8 A0h = *(const half8*)(hA0 + d0);
            half8 A0l = *(const half8*)(lA0 + d0);
            half8 A1h = *(const half8*)(hA1 + d0);
            half8 A1l = *(const half8*)(lA1 + d0);
            #pragma unroll
            for (int tt = 0; tt < 4; ++tt) {
                half8 Bh  = __builtin_bit_cast(half8, Bh4[tt]);
                half8 Bl8 = __builtin_bit_cast(half8, Bl4[tt]);
                acc[0][tt] = MFMA16(A0h, Bl8, MFMA16(A0l, Bh, MFMA16(A0h, Bh, acc[0][tt])));
                acc[1][tt] = MFMA16(A1h, Bl8, MFMA16(A1l, Bh, MFMA16(A1h, Bh, acc[1][tt])));
            }
        }
        #pragma unroll
        for (int rt = 0; rt < 2; ++rt) {
            #pragma unroll
            for (int r = 0; r < 4; ++r) {
                float mv = cks[0] - acc[rt][0][r];
                int mi = colbase + l16;
                #pragma unroll
                for (int tt = 1; tt < 4; ++tt) {
                    float v = cks[tt] - acc[rt][tt][r];
                    int c = colbase + tt * 16 + l16;
                    if (v < mv || (v == mv && c < mi)) { mv = v; mi = c; }
                }
                #pragma unroll
                for (int d = 1; d < 16; d <<= 1) {
                    float ov = __shfl_xor(mv, d);
                    int oi = __shfl_xor(mi, d);
                    if (ov < mv || (ov == mv && oi < mi)) { mv = ov; mi = oi; }
                }
                if (l16 == 0) {
                    int row = rt * 16 + quad * 4 + r;
                    redv[w][row] = mv; redi[w][row] = mi;
                }
            }
        }
        // ---- hGh pass (separate loop, reuses acc after argmin consumed) ----
        #pragma unroll
        for (int rt = 0; rt < 2; ++rt)
            #pragma unroll
            for (int tt = 0; tt < 4; ++tt) acc[rt][tt] = (f32x4){0.f, 0.f, 0.f, 0.f};
        for (int c = 0; c < 16; ++c) {
            int d0 = c * 32;
            half8 A0h = *(const half8*)(hA0 + d0);
            half8 A1h = *(const half8*)(hA1 + d0);
            #pragma unroll
            for (int tt = 0; tt < 4; ++tt) {
                half8 Gh = *(const half8*)(GhPs + paddr(tbs + tt, 16, c, L, 0));
                acc[0][tt] = MFMA16(A0h, Gh, acc[0][tt]);
                acc[1][tt] = MFMA16(A1h, Gh, acc[1][tt]);
            }
        }
        float gs = 0.f;
        #pragma unroll
        for (int rt = 0; rt < 2; ++rt)
            #pragma unroll
            for (int tt = 0; tt < 4; ++tt) {
                int col = colbase + tt * 16 + l16;
                #pragma unroll
                for (int r = 0; r < 4; ++r) {
                    int row = rt * 16 + quad * 4 + r;
                    gs += acc[rt][tt][r] * (float)hhi[row][col];
                }
            }
        #pragma unroll
        for (int d = 1; d < 64; d <<= 1) gs += __shfl_xor(gs, d);
        if (L == 0) gpart[w] = gs;
        __syncthreads();
        if (t < 32) {
            float mv = redv[0][t]; int mi = redi[0][t];
            #pragma unroll
            for (int w2 = 1; w2 < 8; ++w2) {
                float ov = redv[w2][t]; int oi = redi[w2][t];
                if (ov < mv || (ov == mv && oi < mi)) { mv = ov; mi = oi; }
            }
            int b = m0 + t;
            ind[b] = mi;
            out_ind[b] = (float)mi;
            atomicAdd(&counts[mi], 1);
            fin[t] = 2.f * mv;
        }
        __syncthreads();
        if (t == 0) {
            float s = 0.f;
            #pragma unroll
            for (int i = 0; i < 32; ++i) s += fin[i];
            #pragma unroll
            for (int w2 = 0; w2 < 8; ++w2) s += gpart[w2];
            atomicAdd(diffsum, s);
        }
    } else {
        int rt = w & 1, ct = w >> 1;
        f32x4 eacc = (f32x4){0.f, 0.f, 0.f, 0.f};
        for (int c = 0; c < 16; ++c) {
            int d0 = c * 32 + (quad << 3);
            int m = rt * 16 + l16;
            half8 Ah = *(half8*)(&hhi[m][d0]);
            half8 Al = *(half8*)(&hlo[m][d0]);
            size_t ob = paddr(ct, 16, c, L, 0);
            half8 Bh = *(const half8*)(Wx2Ps + ob);
            half8 Bl8 = *(const half8*)(Wx2Pl + ob);
            eacc = MFMA16(Ah, Bl8, MFMA16(Al, Bh, MFMA16(Ah, Bh, eacc)));
        }
        int col = ct * 16 + l16;
        float bias = bx2[col];
        #pragma unroll
        for (int r = 0; r < 4; ++r) {
            int row = m0 + rt * 16 + quad * 4 + r;
            EX[(size_t)row * DIN + col] = eacc[r] + bias;
        }
    }
}

// ---------------------------------------------------------------------------
// Scatter (R22): Hillis-Steele parallel prefix scan over counts (integer
// adds -> order-independent, bit-exact). Block-aggregated cursors.
// ---------------------------------------------------------------------------
__global__ __launch_bounds__(256) void scatter_kernel(const int* __restrict__ ind,
                                                      const int* __restrict__ counts,
                                                      int* __restrict__ cursors,
                                                      int* __restrict__ perm) {
    __shared__ int sc[KN], soff[KN], lcount[KN], lbase[KN], lcur[KN];
    int t = threadIdx.x;
    for (int i = t; i < KN; i += 256) {
        sc[i] = counts[i];
        lcount[i] = 0; lcur[i] = 0;
    }
    __syncthreads();
    // inclusive scan of sc[0..511], 2 elements/thread
    #pragma unroll
    for (int st = 1; st < KN; st <<= 1) {
        int i0 = t, i1 = t + 256;
        int v0 = (i0 >= st) ? sc[i0 - st] : 0;
        int v1 = (i1 >= st) ? sc[i1 - st] : 0;
        __syncthreads();
        sc[i0] += v0;
        sc[i1] += v1;
        __syncthreads();
    }
    #pragma unroll
    for (int half = 0; half < 2; ++half) {
        int i = t + 256 * half;
        soff[i] = (i == 0) ? 0 : sc[i - 1];
    }
    __syncthreads();
    int b = blockIdx.x * 256 + t;
    int k = ind[b];
    atomicAdd(&lcount[k], 1);
    __syncthreads();
    for (int i = t; i < KN; i += 256) {
        int c = lcount[i];
        if (c > 0) lbase[i] = atomicAdd(&cursors[i], c);
    }
    __syncthreads();
    int pos = soff[k] + lbase[k] + atomicAdd(&lcur[k], 1);
    perm[pos] = b;
}

// ---------------------------------------------------------------------------
// Decoder + fused finalize: blocks [0, BN/4) decode one wave per sample
// (load-balanced under histogram skew); block BN/4 runs finalize.
// ---------------------------------------------------------------------------
__global__ __launch_bounds__(256) void decode_kernel(const float* __restrict__ EX,
                                                     const int* __restrict__ perm,
                                                     const int* __restrict__ ind,
                                                     const float* __restrict__ W1,
                                                     const float* __restrict__ b1,
                                                     const float* __restrict__ W2,
                                                     const float* __restrict__ b2,
                                                     float* __restrict__ dec,
                                                     const int* __restrict__ counts,
                                                     const float* __restrict__ diffsum,
                                                     const float* __restrict__ colsum,
                                                     const float* __restrict__ w0,
                                                     const float* __restrict__ bf2,
                                                     float* __restrict__ out_diff,
                                                     float* __restrict__ out_perp) {
    if (blockIdx.x < BN / 4) {
        __shared__ float exs[4][DIN];
        __shared__ float h2s[4][DH];
        int t = threadIdx.x;
        int w = t >> 6, l = t & 63;
        int s = blockIdx.x * 4 + w;
        int b = perm[s];
        int k = ind[b];
        exs[w][l] = EX[(size_t)b * DIN + l];
        __syncthreads();
        const float* w1 = W1 + (size_t)k * (DIN * DH);
        float h = b1[(size_t)k * DH + l];
        #pragma unroll
        for (int j = 0; j < DIN; ++j)
            h = fmaf(exs[w][j], w1[(size_t)j * DH + l], h);
        h2s[w][l] = fmaxf(h, 0.f);
        __syncthreads();
        if (l < DY) {
            const float* w2 = W2 + (size_t)k * (DH * DY);
            float d = b2[(size_t)k * DY + l];
            #pragma unroll
            for (int j = 0; j < DH; ++j)
                d = fmaf(h2s[w][j], w2[(size_t)j * DY + l], d);
            dec[(size_t)b * DY + l] = d;
        }
        return;
    }
    // ---- finalize (single block) ----
    __shared__ float sf[256];
    int t = threadIdx.x;
    float term = 0.f, dotp = 0.f, bbp = 0.f;
    #pragma unroll
    for (int i = 0; i < 2; ++i) {
        int k = t + 256 * i;
        int c = counts[k];
        double p = (double)c / (double)BN;
        term += (float)(-p * log(p + 1e-10));
        dotp += colsum[k] * w0[k];
    }
    for (int d = t; d < ED; d += 256) { float v = bf2[d]; bbp = fmaf(v, v, bbp); }
    sf[t] = dotp; __syncthreads();
    for (int s = 128; s > 0; s >>= 1) { if (t < s) sf[t] += sf[t + s]; __syncthreads(); }
    float dot_all = sf[0];
    __syncthreads();
    sf[t] = bbp; __syncthreads();
    for (int s = 128; s > 0; s >>= 1) { if (t < s) sf[t] += sf[t + s]; __syncthreads(); }
    float bb = sf[0];
    __syncthreads();
    sf[t] = term; __syncthreads();
    for (int s = 128; s > 0; s >>= 1) { if (t < s) sf[t] += sf[t + s]; __syncthreads(); }
    if (t == 0) {
        *out_perp = expf(sf[0]);
        *out_diff = (diffsum[0] + 2.f * dot_all + (float)BN * bb) /
                    ((float)BN * (float)ED);
    }
}

// ---------------------------------------------------------------------------
extern "C" void kernel_launch(void* const* d_in, const int* in_sizes, int n_in,
                              void* d_out, int out_size, void* d_ws, size_t ws_size,
                              hipStream_t stream) {
    const float* x     = (const float*)d_in[0];
    const float* Wf1   = (const float*)d_in[1];
    const float* bf1   = (const float*)d_in[2];
    const float* Wf2   = (const float*)d_in[3];
    const float* bf2   = (const float*)d_in[4];
    const float* Wx1   = (const float*)d_in[5];
    const float* bx1   = (const float*)d_in[6];
    const float* Wx2   = (const float*)d_in[7];
    const float* bx2   = (const float*)d_in[8];
    const float* embed = (const float*)d_in[9];
    const float* W1    = (const float*)d_in[10];
    const float* b1    = (const float*)d_in[11];
    const float* W2    = (const float*)d_in[12];
    const float* b2    = (const float*)d_in[13];
    float* out = (float*)d_out;

    char* ws = (char*)d_ws;
    size_t off = 0;
    auto carve = [&](size_t bytes) -> void* {
        void* p = ws + off;
        off += (bytes + 255) & ~(size_t)255;
        return p;
    };
    _Float16* XPs   = (_Float16*)carve((size_t)BN * INC * 2);    // 4.2 MB
    _Float16* XPl   = (_Float16*)carve((size_t)BN * INC * 2);
    _Float16* WfxPs = (_Float16*)carve((size_t)1024 * INC * 2);
    _Float16* WfxPl = (_Float16*)carve((size_t)1024 * INC * 2);
    float*    bfx   = (float*)carve(1024 * 4);
    _Float16* Wx2Ps = (_Float16*)carve((size_t)DIN * CH * 2);
    _Float16* Wx2Pl = (_Float16*)carve((size_t)DIN * CH * 2);
    _Float16* WfPs  = (_Float16*)carve((size_t)CH * ED * 2);     // 6.4 MB
    _Float16* WfPl  = (_Float16*)carve((size_t)CH * ED * 2);
    _Float16* EmPs  = (_Float16*)carve((size_t)KN * ED * 2);
    _Float16* EmPl  = (_Float16*)carve((size_t)KN * ED * 2);
    // WeP[24] + GP[8] partial buffers (32 MB, dead after wepackgred).
    float*    WeP = (float*)carve((size_t)(NZWE + NZG) * KN * KN * 4);
    float*    GP  = WeP + (size_t)NZWE * KN * KN;
    _Float16* WeI  = (_Float16*)carve((size_t)KN * CH * 4);      // 1 MB interleaved hi|lo
    _Float16* GhPs = (_Float16*)carve((size_t)KN * KN * 2);      // 0.5 MB
    float*    EX   = (float*)carve((size_t)BN * DIN * 4);        // 4.2 MB
    float*    s2p  = (float*)carve(8 * KN * 4);
    float*    bep  = (float*)carve(8 * KN * 4);
    float*    s2   = (float*)carve(KN * 4);
    float*    be   = (float*)carve(KN * 4);
    char* zbase = ws + off;                                      // ---- zero region ----
    float* w0    = (float*)carve(CH * 4);
    float* colsum= (float*)carve(CH * 4);
    int*   counts= (int*)carve(KN * 4);
    int*   cursors=(int*)carve(KN * 4);
    float* diffsum=(float*)carve(256);
    size_t zbytes = (size_t)(ws + off - zbase);                  // ---- end zero region ----
    int*   ind     = (int*)carve(BN * 4);
    int*   perm    = (int*)carve(BN * 4);
    (void)in_sizes; (void)n_in; (void)out_size; (void)ws_size;

    hipMemsetAsync(zbase, 0, zbytes, stream);
    packall_kernel<<<5388, 256, 0, stream>>>(x, Wf1, Wx1, bf1, bx1, Wx2, Wf2, bf2,
                                             embed, XPs, XPl, WfxPs, WfxPl, bfx,
                                             Wx2Ps, Wx2Pl, WfPs, WfPl, EmPs, EmPl,
                                             s2p, bep, w0);
    mfma_weg_kernel<<<dim3(4, 4, NZWE + NZG), 512, 0, stream>>>(WfPs, WfPl,
                                                                EmPs, EmPl,
                                                                WeP, GP);
    wepackgred_kernel<<<2049, 256, 0, stream>>>(WeP, GP, s2p, bep,
                                                WeI, GhPs, s2, be);
    enc1_kernel<<<dim3(BN / 32, 2), 512, 0, stream>>>(XPs, XPl, WfxPs, WfxPl, bfx,
                                                      Wx2Ps, Wx2Pl, bx2,
                                                      WeI, GhPs, s2, be,
                                                      colsum, EX,
                                                      ind, out + OUT_IND, counts,
                                                      diffsum);
    scatter_kernel<<<BN / 256, 256, 0, stream>>>(ind, counts, cursors, perm);
    decode_kernel<<<BN / 4 + 1, 256, 0, stream>>>(EX, perm, ind, W1, b1, W2, b2,
                                                  out + OUT_DEC,
                                                  counts, diffsum, colsum, w0, bf2,
                                                  out + OUT_DIFF, out + OUT_PERP);
}

// Round 15
// 296.766 us; speedup vs baseline: 1.0522x; 1.0001x over previous
//
#include <hip/hip_runtime.h>
#include <math.h>

// Problem constants
#define BN     16384
#define INC    128
#define CH     512
#define ED     6240
#define KN     512      // NUM_EMB
#define DIN    64
#define DH     64
#define DY     32
#define NCW    195      // ED/32 k-chunks for Wf2/embed packing
#define CHP    (CH + 8) // padded LDS row stride (halves)
#define NZWE   24       // We K-slices (3-pass -> ~24.4 work units each)
#define NZG    8        // G  K-slices (1-pass -> ~24.4 work units each)

// d_out layout (float32): dec[16384*32] | diff[1] | embed_ind[16384] | perplexity[1]
#define OUT_DEC   0
#define OUT_DIFF  (BN*DY)
#define OUT_IND   (BN*DY + 1)
#define OUT_PERP  (BN*DY + 1 + BN)

typedef _Float16 half8 __attribute__((ext_vector_type(8)));
typedef float    f32x4 __attribute__((ext_vector_type(4)));
#define MFMA16(a, b, c) __builtin_amdgcn_mfma_f32_16x16x32_f16(a, b, c, 0, 0, 0)

// asm-pinned 16B global load: compiler cannot sink/fold the issue point.
#define GLOAD16(dst, addr) \
    asm volatile("global_load_dwordx4 %0, %1, off" \
                 : "=v"(dst) : "v"(addr) : "memory")

// Packed fragment-tile layout: element (row r within 16-row tile `tile`,
// k-dim index d) lives at ((tile*NC + d/32)*64 + ((d%32)/8)*16 + (r%16))*8 + d%8.
__device__ __forceinline__ size_t paddr(int tile, int NC, int c, int lane, int e) {
    return ((size_t)(tile * NC + c) * 64 + lane) * 8 + e;
}

// ---------------------------------------------------------------------------
// packall (R16): vectorized-store packers.
// Block ranges: [0,1560) splitwf2 | [..,4680) embt | [..,4808) s2bep |
// [..,5320) xpack | [..,5384) wfxpack | [..,5388) wx2pack.
// ---------------------------------------------------------------------------
__global__ __launch_bounds__(256) void packall_kernel(
        const float* __restrict__ x,
        const float* __restrict__ Wf1, const float* __restrict__ Wx1,
        const float* __restrict__ bf1, const float* __restrict__ bx1,
        const float* __restrict__ Wx2,
        const float* __restrict__ Wf2, const float* __restrict__ bf2,
        const float* __restrict__ embed,
        _Float16* __restrict__ XPs, _Float16* __restrict__ XPl,
        _Float16* __restrict__ WfxPs, _Float16* __restrict__ WfxPl,
        float* __restrict__ bfx,
        _Float16* __restrict__ Wx2Ps, _Float16* __restrict__ Wx2Pl,
        _Float16* __restrict__ WfPs, _Float16* __restrict__ WfPl,
        _Float16* __restrict__ EmPs, _Float16* __restrict__ EmPl,
        float* __restrict__ s2p, float* __restrict__ bep,
        float* __restrict__ w0) {
    __shared__ __align__(16) char smem[16384];
    int id = blockIdx.x;
    int t = threadIdx.x;
    if (id < 1560) {
        // ---- splitwf2: Wf2 -> packed hi/lo (half8 stores) + w0 partials ----
        int bx = id % NCW, by = id / NCW;       // by in [0,8)
        int jl = t >> 2, e8 = t & 3;
        int j = by * 64 + jl;
        int d0 = bx * 32 + e8 * 8;
        float4 v0 = *(const float4*)&Wf2[(size_t)j * ED + d0];
        float4 v1 = *(const float4*)&Wf2[(size_t)j * ED + d0 + 4];
        float4 b0 = *(const float4*)&bf2[d0];
        float4 b1 = *(const float4*)&bf2[d0 + 4];
        float vv[8] = {v0.x, v0.y, v0.z, v0.w, v1.x, v1.y, v1.z, v1.w};
        float bb[8] = {b0.x, b0.y, b0.z, b0.w, b1.x, b1.y, b1.z, b1.w};
        half8 hh, ll;
        float s = 0.f;
        #pragma unroll
        for (int e = 0; e < 8; ++e) {
            float v = vv[e];
            _Float16 hi = (_Float16)v;
            hh[e] = hi;
            ll[e] = (_Float16)(v - (float)hi);
            s = fmaf(v, bb[e], s);
        }
        size_t a = paddr(j >> 4, NCW, bx, e8 * 16 + (j & 15), 0);
        *(half8*)(WfPs + a) = hh;
        *(half8*)(WfPl + a) = ll;
        s += __shfl_xor(s, 1);
        s += __shfl_xor(s, 2);
        if (e8 == 0) atomicAdd(&w0[j], s);
    } else if (id < 4680) {
        // ---- embt: embed transpose+split (half8 stores) ----
        float (*tile)[33] = (float(*)[33])smem; // tile[di][ki]
        int sub = id - 1560;
        int bx = sub % NCW, by = sub / NCW;
        int dl = t >> 5, kl = t & 31;
        #pragma unroll
        for (int r = 0; r < 4; ++r)
            tile[dl + 8 * r][kl] = embed[(size_t)(bx * 32 + dl + 8 * r) * KN
                                         + by * 32 + kl];
        __syncthreads();
        if (t < 128) {
            int g = t >> 5, kl2 = t & 31;       // g: d-group 0..3
            int k = by * 32 + kl2;
            half8 hh, ll;
            #pragma unroll
            for (int e = 0; e < 8; ++e) {
                float v = tile[g * 8 + e][kl2];
                _Float16 hi = (_Float16)v;
                hh[e] = hi;
                ll[e] = (_Float16)(v - (float)hi);
            }
            size_t a = paddr(k >> 4, NCW, bx, g * 16 + (k & 15), 0);
            *(half8*)(EmPs + a) = hh;
            *(half8*)(EmPl + a) = ll;
        }
    } else if (id < 4808) {
        // ---- s2bep: deterministic s2/be partials (fixed-order, no atomics) ----
        float (*rs)[33] = (float(*)[33])smem;
        float (*rb)[33] = (float(*)[33])(smem + 8 * 33 * 4);
        int sub = id - 4680;
        int bx = sub % 16, by = sub / 16;
        int kl = t & 31, dl = t >> 5;
        int kb = bx * 32;
        int d0 = by * 780;
        float s = 0.f, b = 0.f;
        for (int d = d0 + dl; d < d0 + 780; d += 8) {
            float e = embed[(size_t)d * KN + kb + kl];
            s = fmaf(e, e, s);
            b = fmaf(bf2[d], e, b);
        }
        rs[dl][kl] = s; rb[dl][kl] = b;
        __syncthreads();
        if (t < 32) {
            float ss = 0.f, bb = 0.f;
            #pragma unroll
            for (int i = 0; i < 8; ++i) { ss += rs[i][t]; bb += rb[i][t]; }
            s2p[by * KN + kb + t] = ss;
            bep[by * KN + kb + t] = bb;
        }
    } else if (id < 5320) {
        // ---- xpack: x -> XPs/XPl ----
        float (*xt)[INC] = (float(*)[INC])smem;
        int m0 = (id - 4808) * 32;
        for (int i = t; i < 32 * (INC / 4); i += 256) {
            int row = i >> 5, c4 = (i & 31) << 2;
            *(float4*)&xt[row][c4] = *(const float4*)&x[(size_t)(m0 + row) * INC + c4];
        }
        __syncthreads();
        int ta = m0 >> 4;
        #pragma unroll
        for (int i = 0; i < 2; ++i) {
            int idx = t + 256 * i;
            int tile2 = idx >> 8;
            int c = (idx >> 6) & 3;
            int lane = idx & 63;
            int m = tile2 * 16 + (lane & 15);
            int d0 = c * 32 + ((lane >> 4) << 3);
            half8 hh, ll;
            #pragma unroll
            for (int e = 0; e < 8; ++e) {
                float v = xt[m][d0 + e];
                _Float16 hi = (_Float16)v;
                hh[e] = hi;
                ll[e] = (_Float16)(v - (float)hi);
            }
            *(half8*)(XPs + paddr(ta + tile2, 4, c, lane, 0)) = hh;
            *(half8*)(XPl + paddr(ta + tile2, 4, c, lane, 0)) = ll;
        }
    } else if (id < 5384) {
        // ---- wfxpack: fused Wf1|Wx1 cols + bfx ----
        int tile = id - 5320;
        for (int i = t; i < 2048; i += 256) {
            int c = i >> 9, lane = (i >> 3) & 63, e = i & 7;
            int n = tile * 16 + (lane & 15);
            int d = c * 32 + ((lane >> 4) << 3) + e;
            float v = (n < 512) ? Wf1[(size_t)d * CH + n] : Wx1[(size_t)d * CH + n - 512];
            _Float16 hi = (_Float16)v;
            size_t a = paddr(tile, 4, c, lane, e);
            WfxPs[a] = hi;
            WfxPl[a] = (_Float16)(v - (float)hi);
        }
        if (tile == 0)
            for (int j = t; j < 512; j += 256) { bfx[j] = bf1[j]; bfx[512 + j] = bx1[j]; }
    } else {
        // ---- wx2pack ----
        int tile = id - 5384;
        for (int i = t; i < 8192; i += 256) {
            int c = i >> 9, lane = (i >> 3) & 63, e = i & 7;
            int n = tile * 16 + (lane & 15);
            int d = c * 32 + ((lane >> 4) << 3) + e;
            float v = Wx2[(size_t)d * DIN + n];
            _Float16 hi = (_Float16)v;
            size_t a = paddr(tile, 16, c, lane, e);
            Wx2Ps[a] = hi;
            Wx2Pl[a] = (_Float16)(v - (float)hi);
        }
    }
}

// ---------------------------------------------------------------------------
// Merged precompute GEMMs (R19): grid (4,4,32), block 512 -> 512 blocks =
// 2 blocks/CU. Work-balanced z-split: z<24 -> We slice (3-pass); z>=24 ->
// G slice (1-pass). Partials: (24+8) MB = 32 MB.
// ---------------------------------------------------------------------------
__global__ __launch_bounds__(512) void mfma_weg_kernel(
        const _Float16* __restrict__ WfPs, const _Float16* __restrict__ WfPl,
        const _Float16* __restrict__ EmPs, const _Float16* __restrict__ EmPl,
        float* __restrict__ WeP, float* __restrict__ GP) {
    int t = threadIdx.x;
    int w = t >> 6, L = t & 63;
    int lane16 = L & 15, quad = L >> 4;
    int m0 = blockIdx.x * 128 + (w & 3) * 32;
    int n0 = blockIdx.y * 128 + (w >> 2) * 64;
    int ta = m0 >> 4, tb = n0 >> 4;
    int zraw = blockIdx.z;
    bool isWe = zraw < NZWE;
    int z, c0, cnt;
    if (isWe) {
        z = zraw;
        int base = NCW / NZWE, rem = NCW % NZWE;    // 8, 3
        c0 = z * base + (z < rem ? z : rem);
        cnt = base + (z < rem ? 1 : 0);
    } else {
        z = zraw - NZWE;
        int base = NCW / NZG, rem = NCW % NZG;      // 24, 3
        c0 = z * base + (z < rem ? z : rem);
        cnt = base + (z < rem ? 1 : 0);
    }
    f32x4 acc[2][4];
    #pragma unroll
    for (int rt = 0; rt < 2; ++rt)
        #pragma unroll
        for (int tt = 0; tt < 4; ++tt) acc[rt][tt] = (f32x4){0.f, 0.f, 0.f, 0.f};
    if (isWe) {
        for (int ci = 0; ci < cnt; ++ci) {
            int c = c0 + ci;
            size_t oa0 = paddr(ta, NCW, c, L, 0), oa1 = paddr(ta + 1, NCW, c, L, 0);
            half8 A0h = *(const half8*)(WfPs + oa0);
            half8 A0l = *(const half8*)(WfPl + oa0);
            half8 A1h = *(const half8*)(WfPs + oa1);
            half8 A1l = *(const half8*)(WfPl + oa1);
            #pragma unroll
            for (int tt = 0; tt < 4; ++tt) {
                size_t ob = paddr(tb + tt, NCW, c, L, 0);
                half8 Bh = *(const half8*)(EmPs + ob);
                half8 Bl8 = *(const half8*)(EmPl + ob);
                acc[0][tt] = MFMA16(A0h, Bl8, MFMA16(A0l, Bh, MFMA16(A0h, Bh, acc[0][tt])));
                acc[1][tt] = MFMA16(A1h, Bl8, MFMA16(A1l, Bh, MFMA16(A1h, Bh, acc[1][tt])));
            }
        }
    } else {
        for (int ci = 0; ci < cnt; ++ci) {
            int c = c0 + ci;
            half8 A0h = *(const half8*)(WfPs + paddr(ta, NCW, c, L, 0));
            half8 A1h = *(const half8*)(WfPs + paddr(ta + 1, NCW, c, L, 0));
            #pragma unroll
            for (int tt = 0; tt < 4; ++tt) {
                half8 Bh = *(const half8*)(WfPs + paddr(tb + tt, NCW, c, L, 0));
                acc[0][tt] = MFMA16(A0h, Bh, acc[0][tt]);
                acc[1][tt] = MFMA16(A1h, Bh, acc[1][tt]);
            }
        }
    }
    float* C = (isWe ? WeP : GP) + (size_t)z * KN * KN;
    #pragma unroll
    for (int rt = 0; rt < 2; ++rt)
        #pragma unroll
        for (int tt = 0; tt < 4; ++tt)
            #pragma unroll
            for (int r = 0; r < 4; ++r)
                C[(size_t)(m0 + rt * 16 + quad * 4 + r) * KN
                  + n0 + tt * 16 + lane16] = acc[rt][tt][r];
}

// ---------------------------------------------------------------------------
// Merged reducers (R23): blocks [0,1024) wepack (24 partials, fixed order ->
// deterministic; writes the hi/lo pair INTERLEAVED into one buffer WeI:
// hi half8 at base*16, lo half8 at base*16+8); [1024,2048) gred (8 partials,
// packs G to fp16-hi B-frags); block 2048 sbered.
// ---------------------------------------------------------------------------
__global__ __launch_bounds__(256) void wepackgred_kernel(
        const float* __restrict__ WeP, const float* __restrict__ GP,
        const float* __restrict__ s2p, const float* __restrict__ bep,
        _Float16* __restrict__ WeI,
        _Float16* __restrict__ GhPs, float* __restrict__ s2,
        float* __restrict__ be) {
    int id = blockIdx.x;
    int t = threadIdx.x;
    if (id < 1024) {
        int g = id * 256 + t;                   // j*512 + k
        int j = g >> 9, k = g & 511;
        float v = 0.f;
        #pragma unroll
        for (int z = 0; z < NZWE; ++z) v += WeP[(size_t)z * KN * KN + g];
        _Float16 hi = (_Float16)v;
        size_t a = paddr(k >> 4, 16, j >> 5, ((j & 31) >> 3) * 16 + (k & 15), j & 7);
        size_t ab = a & ~(size_t)7;             // half8 base
        size_t e  = a & 7;
        WeI[2 * ab + e]     = hi;
        WeI[2 * ab + 8 + e] = (_Float16)(v - (float)hi);
    } else if (id < 2048) {
        int g = (id - 1024) * 256 + t;          // m*512 + n (G symmetric)
        int m = g >> 9, n = g & 511;
        float v = 0.f;
        #pragma unroll
        for (int z = 0; z < NZG; ++z) v += GP[(size_t)z * KN * KN + g];
        GhPs[paddr(n >> 4, 16, m >> 5, ((m & 31) >> 3) * 16 + (n & 15), m & 7)]
            = (_Float16)v;
    } else {
        #pragma unroll
        for (int i = 0; i < 2; ++i) {
            int k = t + 256 * i;
            float s = 0.f, b = 0.f;
            #pragma unroll
            for (int y = 0; y < 8; ++y) {
                s += s2p[y * KN + k];
                b += bep[y * KN + k];
            }
            s2[k] = s;
            be[k] = b;
        }
    }
}

// ---------------------------------------------------------------------------
// Fused MFMA encoder + SCORE + hGh (R25 = R24 + the hGh loop pipelined with
// the same asm-pinned GLOAD16 + counted vmcnt(4) + sched_barrier pattern
// that bought -8.5us on the score loop. Same values, same MFMA order ->
// bit-identical outputs.
// ---------------------------------------------------------------------------
__global__ __launch_bounds__(512) void enc1_kernel(
        const _Float16* __restrict__ XPs, const _Float16* __restrict__ XPl,
        const _Float16* __restrict__ WfxPs, const _Float16* __restrict__ WfxPl,
        const float* __restrict__ bfx,
        const _Float16* __restrict__ Wx2Ps, const _Float16* __restrict__ Wx2Pl,
        const float* __restrict__ bx2,
        const _Float16* __restrict__ WeI,
        const _Float16* __restrict__ GhPs,
        const float* __restrict__ s2, const float* __restrict__ be,
        float* __restrict__ colsum,
        float* __restrict__ EX,
        int* __restrict__ ind, float* __restrict__ out_ind,
        int* __restrict__ counts, float* __restrict__ diffsum) {
    __shared__ _Float16 hhi[32][CHP];
    __shared__ _Float16 hlo[32][CHP];
    __shared__ float redv[8][32];
    __shared__ int   redi[8][32];
    __shared__ float fin[32];
    __shared__ float gpart[8];
    int t = threadIdx.x;
    int w = t >> 6, L = t & 63;
    int l16 = L & 15, quad = L >> 4;
    int m0 = blockIdx.x * 32;
    int ta = m0 >> 4;
    int enc = blockIdx.y;
    int n0 = enc * 512 + w * 64;
    int tb = n0 >> 4;
    f32x4 acc[2][4];
    #pragma unroll
    for (int rt = 0; rt < 2; ++rt)
        #pragma unroll
        for (int tt = 0; tt < 4; ++tt) acc[rt][tt] = (f32x4){0.f, 0.f, 0.f, 0.f};
    #pragma unroll
    for (int c = 0; c < 4; ++c) {
        size_t oa0 = paddr(ta, 4, c, L, 0), oa1 = paddr(ta + 1, 4, c, L, 0);
        half8 A0h = *(const half8*)(XPs + oa0);
        half8 A0l = *(const half8*)(XPl + oa0);
        half8 A1h = *(const half8*)(XPs + oa1);
        half8 A1l = *(const half8*)(XPl + oa1);
        #pragma unroll
        for (int tt = 0; tt < 4; ++tt) {
            size_t ob = paddr(tb + tt, 4, c, L, 0);
            half8 Bh = *(const half8*)(WfxPs + ob);
            half8 Bl8 = *(const half8*)(WfxPl + ob);
            acc[0][tt] = MFMA16(A0h, Bl8, MFMA16(A0l, Bh, MFMA16(A0h, Bh, acc[0][tt])));
            acc[1][tt] = MFMA16(A1h, Bl8, MFMA16(A1l, Bh, MFMA16(A1h, Bh, acc[1][tt])));
        }
    }
    #pragma unroll
    for (int rt = 0; rt < 2; ++rt)
        #pragma unroll
        for (int tt = 0; tt < 4; ++tt) {
            int col = w * 64 + tt * 16 + l16;
            float bias = bfx[enc * 512 + col];
            #pragma unroll
            for (int r = 0; r < 4; ++r) {
                int row = rt * 16 + quad * 4 + r;
                float v = fmaxf(acc[rt][tt][r] + bias, 0.f);
                _Float16 hi = (_Float16)v;
                hhi[row][col] = hi;
                hlo[row][col] = (_Float16)(v - (float)hi);
            }
        }
    __syncthreads();
    if (enc == 0) {
        float s = 0.f;
        #pragma unroll
        for (int r = 0; r < 32; ++r) s += (float)hhi[r][t] + (float)hlo[r][t];
        atomicAdd(&colsum[t], s);
        int colbase = w * 64;
        int tbs = w * 4;
        float cks[4];
        #pragma unroll
        for (int tt = 0; tt < 4; ++tt) {
            int c = colbase + tt * 16 + l16;
            cks[tt] = 0.5f * s2[c] - be[c];
        }
        #pragma unroll
        for (int rt = 0; rt < 2; ++rt)
            #pragma unroll
            for (int tt = 0; tt < 4; ++tt) acc[rt][tt] = (f32x4){0.f, 0.f, 0.f, 0.f};
        const _Float16* hA0 = &hhi[l16][quad << 3];
        const _Float16* lA0 = &hlo[l16][quad << 3];
        const _Float16* hA1 = &hhi[16 + l16][quad << 3];
        const _Float16* lA1 = &hlo[16 + l16][quad << 3];
        // ---- score loop: asm-pinned 1-deep pipeline, counted vmcnt ----
        const char* bbase[4];
        #pragma unroll
        for (int tt = 0; tt < 4; ++tt)
            bbase[tt] = (const char*)WeI
                        + (((size_t)(tbs + tt) * 16 * 64 + L) * 32);
        f32x4 BhA[4], BlA[4], BhB[4], BlB[4];
        #pragma unroll
        for (int tt = 0; tt < 4; ++tt) {            // prologue: issue c=0
            const char* p = bbase[tt];
            GLOAD16(BhA[tt], p);
            GLOAD16(BlA[tt], p + 16);
        }
        #pragma unroll
        for (int c = 0; c < 16; ++c) {
            f32x4* Bh4 = (c & 1) ? BhB : BhA;
            f32x4* Bl4 = (c & 1) ? BlB : BlA;
            f32x4* Nh4 = (c & 1) ? BhA : BhB;
            f32x4* Nl4 = (c & 1) ? BlA : BlB;
            if (c < 15) {
                #pragma unroll
                for (int tt = 0; tt < 4; ++tt) {
                    const char* p = bbase[tt] + (size_t)(c + 1) * 2048;
                    GLOAD16(Nh4[tt], p);
                    GLOAD16(Nl4[tt], p + 16);
                }
                asm volatile("s_waitcnt vmcnt(8)" ::: "memory");
            } else {
                asm volatile("s_waitcnt vmcnt(0)" ::: "memory");
            }
            __builtin_amdgcn_sched_barrier(0);
            int d0 = c * 32;
            half8 A0h = *(const half8*)(hA0 + d0);
            half8 A0l = *(const half8*)(lA0 + d0);
            half8 A1h = *(const half8*)(hA1 + d0);
            half8 A1l = *(const half8*)(lA1 + d0);
            #pragma unroll
            for (int tt = 0; tt < 4; ++tt) {
                half8 Bh  = __builtin_bit_cast(half8, Bh4[tt]);
                half8 Bl8 = __builtin_bit_cast(half8, Bl4[tt]);
                acc[0][tt] = MFMA16(A0h, Bl8, MFMA16(A0l, Bh, MFMA16(A0h, Bh, acc[0][tt])));
                acc[1][tt] = MFMA16(A1h, Bl8, MFMA16(A1l, Bh, MFMA16(A1h, Bh, acc[1][tt])));
            }
        }
        #pragma unroll
        for (int rt = 0; rt < 2; ++rt) {
            #pragma unroll
            for (int r = 0; r < 4; ++r) {
                float mv = cks[0] - acc[rt][0][r];
                int mi = colbase + l16;
                #pragma unroll
                for (int tt = 1; tt < 4; ++tt) {
                    float v = cks[tt] - acc[rt][tt][r];
                    int c = colbase + tt * 16 + l16;
                    if (v < mv || (v == mv && c < mi)) { mv = v; mi = c; }
                }
                #pragma unroll
                for (int d = 1; d < 16; d <<= 1) {
                    float ov = __shfl_xor(mv, d);
                    int oi = __shfl_xor(mi, d);
                    if (ov < mv || (ov == mv && oi < mi)) { mv = ov; mi = oi; }
                }
                if (l16 == 0) {
                    int row = rt * 16 + quad * 4 + r;
                    redv[w][row] = mv; redi[w][row] = mi;
                }
            }
        }
        // ---- hGh pass: asm-pinned 1-deep pipeline, counted vmcnt(4) ----
        #pragma unroll
        for (int rt = 0; rt < 2; ++rt)
            #pragma unroll
            for (int tt = 0; tt < 4; ++tt) acc[rt][tt] = (f32x4){0.f, 0.f, 0.f, 0.f};
        const char* gbase[4];
        #pragma unroll
        for (int tt = 0; tt < 4; ++tt)
            gbase[tt] = (const char*)GhPs
                        + (((size_t)(tbs + tt) * 16 * 64 + L) * 16);
        f32x4 GhA4[4], GhB4[4];
        #pragma unroll
        for (int tt = 0; tt < 4; ++tt)              // prologue: issue c=0
            GLOAD16(GhA4[tt], gbase[tt]);
        #pragma unroll
        for (int c = 0; c < 16; ++c) {
            f32x4* G4 = (c & 1) ? GhB4 : GhA4;
            f32x4* N4 = (c & 1) ? GhA4 : GhB4;
            if (c < 15) {
                #pragma unroll
                for (int tt = 0; tt < 4; ++tt)
                    GLOAD16(N4[tt], gbase[tt] + (size_t)(c + 1) * 1024);
                asm volatile("s_waitcnt vmcnt(4)" ::: "memory");
            } else {
                asm volatile("s_waitcnt vmcnt(0)" ::: "memory");
            }
            __builtin_amdgcn_sched_barrier(0);
            int d0 = c * 32;
            half8 A0h = *(const half8*)(hA0 + d0);
            half8 A1h = *(const half8*)(hA1 + d0);
            #pragma unroll
            for (int tt = 0; tt < 4; ++tt) {
                half8 Gh = __builtin_bit_cast(half8, G4[tt]);
                acc[0][tt] = MFMA16(A0h, Gh, acc[0][tt]);
                acc[1][tt] = MFMA16(A1h, Gh, acc[1][tt]);
            }
        }
        float gs = 0.f;
        #pragma unroll
        for (int rt = 0; rt < 2; ++rt)
            #pragma unroll
            for (int tt = 0; tt < 4; ++tt) {
                int col = colbase + tt * 16 + l16;
                #pragma unroll
                for (int r = 0; r < 4; ++r) {
                    int row = rt * 16 + quad * 4 + r;
                    gs += acc[rt][tt][r] * (float)hhi[row][col];
                }
            }
        #pragma unroll
        for (int d = 1; d < 64; d <<= 1) gs += __shfl_xor(gs, d);
        if (L == 0) gpart[w] = gs;
        __syncthreads();
        if (t < 32) {
            float mv = redv[0][t]; int mi = redi[0][t];
            #pragma unroll
            for (int w2 = 1; w2 < 8; ++w2) {
                float ov = redv[w2][t]; int oi = redi[w2][t];
                if (ov < mv || (ov == mv && oi < mi)) { mv = ov; mi = oi; }
            }
            int b = m0 + t;
            ind[b] = mi;
            out_ind[b] = (float)mi;
            atomicAdd(&counts[mi], 1);
            fin[t] = 2.f * mv;
        }
        __syncthreads();
        if (t == 0) {
            float s = 0.f;
            #pragma unroll
            for (int i = 0; i < 32; ++i) s += fin[i];
            #pragma unroll
            for (int w2 = 0; w2 < 8; ++w2) s += gpart[w2];
            atomicAdd(diffsum, s);
        }
    } else {
        int rt = w & 1, ct = w >> 1;
        f32x4 eacc = (f32x4){0.f, 0.f, 0.f, 0.f};
        for (int c = 0; c < 16; ++c) {
            int d0 = c * 32 + (quad << 3);
            int m = rt * 16 + l16;
            half8 Ah = *(half8*)(&hhi[m][d0]);
            half8 Al = *(half8*)(&hlo[m][d0]);
            size_t ob = paddr(ct, 16, c, L, 0);
            half8 Bh = *(const half8*)(Wx2Ps + ob);
            half8 Bl8 = *(const half8*)(Wx2Pl + ob);
            eacc = MFMA16(Ah, Bl8, MFMA16(Al, Bh, MFMA16(Ah, Bh, eacc)));
        }
        int col = ct * 16 + l16;
        float bias = bx2[col];
        #pragma unroll
        for (int r = 0; r < 4; ++r) {
            int row = m0 + rt * 16 + quad * 4 + r;
            EX[(size_t)row * DIN + col] = eacc[r] + bias;
        }
    }
}

// ---------------------------------------------------------------------------
// Scatter (R22): Hillis-Steele parallel prefix scan over counts (integer
// adds -> order-independent, bit-exact). Block-aggregated cursors.
// ---------------------------------------------------------------------------
__global__ __launch_bounds__(256) void scatter_kernel(const int* __restrict__ ind,
                                                      const int* __restrict__ counts,
                                                      int* __restrict__ cursors,
                                                      int* __restrict__ perm) {
    __shared__ int sc[KN], soff[KN], lcount[KN], lbase[KN], lcur[KN];
    int t = threadIdx.x;
    for (int i = t; i < KN; i += 256) {
        sc[i] = counts[i];
        lcount[i] = 0; lcur[i] = 0;
    }
    __syncthreads();
    // inclusive scan of sc[0..511], 2 elements/thread
    #pragma unroll
    for (int st = 1; st < KN; st <<= 1) {
        int i0 = t, i1 = t + 256;
        int v0 = (i0 >= st) ? sc[i0 - st] : 0;
        int v1 = (i1 >= st) ? sc[i1 - st] : 0;
        __syncthreads();
        sc[i0] += v0;
        sc[i1] += v1;
        __syncthreads();
    }
    #pragma unroll
    for (int half = 0; half < 2; ++half) {
        int i = t + 256 * half;
        soff[i] = (i == 0) ? 0 : sc[i - 1];
    }
    __syncthreads();
    int b = blockIdx.x * 256 + t;
    int k = ind[b];
    atomicAdd(&lcount[k], 1);
    __syncthreads();
    for (int i = t; i < KN; i += 256) {
        int c = lcount[i];
        if (c > 0) lbase[i] = atomicAdd(&cursors[i], c);
    }
    __syncthreads();
    int pos = soff[k] + lbase[k] + atomicAdd(&lcur[k], 1);
    perm[pos] = b;
}

// ---------------------------------------------------------------------------
// Decoder + fused finalize: blocks [0, BN/4) decode one wave per sample
// (load-balanced under histogram skew); block BN/4 runs finalize.
// ---------------------------------------------------------------------------
__global__ __launch_bounds__(256) void decode_kernel(const float* __restrict__ EX,
                                                     const int* __restrict__ perm,
                                                     const int* __restrict__ ind,
                                                     const float* __restrict__ W1,
                                                     const float* __restrict__ b1,
                                                     const float* __restrict__ W2,
                                                     const float* __restrict__ b2,
                                                     float* __restrict__ dec,
                                                     const int* __restrict__ counts,
                                                     const float* __restrict__ diffsum,
                                                     const float* __restrict__ colsum,
                                                     const float* __restrict__ w0,
                                                     const float* __restrict__ bf2,
                                                     float* __restrict__ out_diff,
                                                     float* __restrict__ out_perp) {
    if (blockIdx.x < BN / 4) {
        __shared__ float exs[4][DIN];
        __shared__ float h2s[4][DH];
        int t = threadIdx.x;
        int w = t >> 6, l = t & 63;
        int s = blockIdx.x * 4 + w;
        int b = perm[s];
        int k = ind[b];
        exs[w][l] = EX[(size_t)b * DIN + l];
        __syncthreads();
        const float* w1 = W1 + (size_t)k * (DIN * DH);
        float h = b1[(size_t)k * DH + l];
        #pragma unroll
        for (int j = 0; j < DIN; ++j)
            h = fmaf(exs[w][j], w1[(size_t)j * DH + l], h);
        h2s[w][l] = fmaxf(h, 0.f);
        __syncthreads();
        if (l < DY) {
            const float* w2 = W2 + (size_t)k * (DH * DY);
            float d = b2[(size_t)k * DY + l];
            #pragma unroll
            for (int j = 0; j < DH; ++j)
                d = fmaf(h2s[w][j], w2[(size_t)j * DY + l], d);
            dec[(size_t)b * DY + l] = d;
        }
        return;
    }
    // ---- finalize (single block) ----
    __shared__ float sf[256];
    int t = threadIdx.x;
    float term = 0.f, dotp = 0.f, bbp = 0.f;
    #pragma unroll
    for (int i = 0; i < 2; ++i) {
        int k = t + 256 * i;
        int c = counts[k];
        double p = (double)c / (double)BN;
        term += (float)(-p * log(p + 1e-10));
        dotp += colsum[k] * w0[k];
    }
    for (int d = t; d < ED; d += 256) { float v = bf2[d]; bbp = fmaf(v, v, bbp); }
    sf[t] = dotp; __syncthreads();
    for (int s = 128; s > 0; s >>= 1) { if (t < s) sf[t] += sf[t + s]; __syncthreads(); }
    float dot_all = sf[0];
    __syncthreads();
    sf[t] = bbp; __syncthreads();
    for (int s = 128; s > 0; s >>= 1) { if (t < s) sf[t] += sf[t + s]; __syncthreads(); }
    float bb = sf[0];
    __syncthreads();
    sf[t] = term; __syncthreads();
    for (int s = 128; s > 0; s >>= 1) { if (t < s) sf[t] += sf[t + s]; __syncthreads(); }
    if (t == 0) {
        *out_perp = expf(sf[0]);
        *out_diff = (diffsum[0] + 2.f * dot_all + (float)BN * bb) /
                    ((float)BN * (float)ED);
    }
}

// ---------------------------------------------------------------------------
extern "C" void kernel_launch(void* const* d_in, const int* in_sizes, int n_in,
                              void* d_out, int out_size, void* d_ws, size_t ws_size,
                              hipStream_t stream) {
    const float* x     = (const float*)d_in[0];
    const float* Wf1   = (const float*)d_in[1];
    const float* bf1   = (const float*)d_in[2];
    const float* Wf2   = (const float*)d_in[3];
    const float* bf2   = (const float*)d_in[4];
    const float* Wx1   = (const float*)d_in[5];
    const float* bx1   = (const float*)d_in[6];
    const float* Wx2   = (const float*)d_in[7];
    const float* bx2   = (const float*)d_in[8];
    const float* embed = (const float*)d_in[9];
    const float* W1    = (const float*)d_in[10];
    const float* b1    = (const float*)d_in[11];
    const float* W2    = (const float*)d_in[12];
    const float* b2    = (const float*)d_in[13];
    float* out = (float*)d_out;

    char* ws = (char*)d_ws;
    size_t off = 0;
    auto carve = [&](size_t bytes) -> void* {
        void* p = ws + off;
        off += (bytes + 255) & ~(size_t)255;
        return p;
    };
    _Float16* XPs   = (_Float16*)carve((size_t)BN * INC * 2);    // 4.2 MB
    _Float16* XPl   = (_Float16*)carve((size_t)BN * INC * 2);
    _Float16* WfxPs = (_Float16*)carve((size_t)1024 * INC * 2);
    _Float16* WfxPl = (_Float16*)carve((size_t)1024 * INC * 2);
    float*    bfx   = (float*)carve(1024 * 4);
    _Float16* Wx2Ps = (_Float16*)carve((size_t)DIN * CH * 2);
    _Float16* Wx2Pl = (_Float16*)carve((size_t)DIN * CH * 2);
    _Float16* WfPs  = (_Float16*)carve((size_t)CH * ED * 2);     // 6.4 MB
    _Float16* WfPl  = (_Float16*)carve((size_t)CH * ED * 2);
    _Float16* EmPs  = (_Float16*)carve((size_t)KN * ED * 2);
    _Float16* EmPl  = (_Float16*)carve((size_t)KN * ED * 2);
    // WeP[24] + GP[8] partial buffers (32 MB, dead after wepackgred).
    float*    WeP = (float*)carve((size_t)(NZWE + NZG) * KN * KN * 4);
    float*    GP  = WeP + (size_t)NZWE * KN * KN;
    _Float16* WeI  = (_Float16*)carve((size_t)KN * CH * 4);      // 1 MB interleaved hi|lo
    _Float16* GhPs = (_Float16*)carve((size_t)KN * KN * 2);      // 0.5 MB
    float*    EX   = (float*)carve((size_t)BN * DIN * 4);        // 4.2 MB
    float*    s2p  = (float*)carve(8 * KN * 4);
    float*    bep  = (float*)carve(8 * KN * 4);
    float*    s2   = (float*)carve(KN * 4);
    float*    be   = (float*)carve(KN * 4);
    char* zbase = ws + off;                                      // ---- zero region ----
    float* w0    = (float*)carve(CH * 4);
    float* colsum= (float*)carve(CH * 4);
    int*   counts= (int*)carve(KN * 4);
    int*   cursors=(int*)carve(KN * 4);
    float* diffsum=(float*)carve(256);
    size_t zbytes = (size_t)(ws + off - zbase);                  // ---- end zero region ----
    int*   ind     = (int*)carve(BN * 4);
    int*   perm    = (int*)carve(BN * 4);
    (void)in_sizes; (void)n_in; (void)out_size; (void)ws_size;

    hipMemsetAsync(zbase, 0, zbytes, stream);
    packall_kernel<<<5388, 256, 0, stream>>>(x, Wf1, Wx1, bf1, bx1, Wx2, Wf2, bf2,
                                             embed, XPs, XPl, WfxPs, WfxPl, bfx,
                                             Wx2Ps, Wx2Pl, WfPs, WfPl, EmPs, EmPl,
                                             s2p, bep, w0);
    mfma_weg_kernel<<<dim3(4, 4, NZWE + NZG), 512, 0, stream>>>(WfPs, WfPl,
                                                                EmPs, EmPl,
                                                                WeP, GP);
    wepackgred_kernel<<<2049, 256, 0, stream>>>(WeP, GP, s2p, bep,
                                                WeI, GhPs, s2, be);
    enc1_kernel<<<dim3(BN / 32, 2), 512, 0, stream>>>(XPs, XPl, WfxPs, WfxPl, bfx,
                                                      Wx2Ps, Wx2Pl, bx2,
                                                      WeI, GhPs, s2, be,
                                                      colsum, EX,
                                                      ind, out + OUT_IND, counts,
                                                      diffsum);
    scatter_kernel<<<BN / 256, 256, 0, stream>>>(ind, counts, cursors, perm);
    decode_kernel<<<BN / 4 + 1, 256, 0, stream>>>(EX, perm, ind, W1, b1, W2, b2,
                                                  out + OUT_DEC,
                                                  counts, diffsum, colsum, w0, bf2,
                                                  out + OUT_DIFF, out + OUT_PERP);
}

// Round 17
// 296.036 us; speedup vs baseline: 1.0548x; 1.0025x over previous
//
#include <hip/hip_runtime.h>
#include <math.h>

// Problem constants
#define BN     16384
#define INC    128
#define CH     512
#define ED     6240
#define KN     512      // NUM_EMB
#define DIN    64
#define DH     64
#define DY     32
#define NCW    195      // ED/32 k-chunks for Wf2/embed packing
#define CHP    (CH + 8) // padded LDS row stride (halves)
#define NZWE   24       // We K-slices (3-pass -> ~24.4 work units each)
#define NZG    8        // G  K-slices (1-pass -> ~24.4 work units each)

// d_out layout (float32): dec[16384*32] | diff[1] | embed_ind[16384] | perplexity[1]
#define OUT_DEC   0
#define OUT_DIFF  (BN*DY)
#define OUT_IND   (BN*DY + 1)
#define OUT_PERP  (BN*DY + 1 + BN)

typedef _Float16 half8 __attribute__((ext_vector_type(8)));
typedef float    f32x4 __attribute__((ext_vector_type(4)));
#define MFMA16(a, b, c) __builtin_amdgcn_mfma_f32_16x16x32_f16(a, b, c, 0, 0, 0)

// asm-pinned 16B global load: compiler cannot sink/fold the issue point.
#define GLOAD16(dst, addr) \
    asm volatile("global_load_dwordx4 %0, %1, off" \
                 : "=v"(dst) : "v"(addr) : "memory")

// Packed fragment-tile layout: element (row r within 16-row tile `tile`,
// k-dim index d) lives at ((tile*NC + d/32)*64 + ((d%32)/8)*16 + (r%16))*8 + d%8.
__device__ __forceinline__ size_t paddr(int tile, int NC, int c, int lane, int e) {
    return ((size_t)(tile * NC + c) * 64 + lane) * 8 + e;
}

// ---------------------------------------------------------------------------
// packall (R16): vectorized-store packers.
// Block ranges: [0,1560) splitwf2 | [..,4680) embt | [..,4808) s2bep |
// [..,5320) xpack | [..,5384) wfxpack | [..,5388) wx2pack.
// ---------------------------------------------------------------------------
__global__ __launch_bounds__(256) void packall_kernel(
        const float* __restrict__ x,
        const float* __restrict__ Wf1, const float* __restrict__ Wx1,
        const float* __restrict__ bf1, const float* __restrict__ bx1,
        const float* __restrict__ Wx2,
        const float* __restrict__ Wf2, const float* __restrict__ bf2,
        const float* __restrict__ embed,
        _Float16* __restrict__ XPs, _Float16* __restrict__ XPl,
        _Float16* __restrict__ WfxPs, _Float16* __restrict__ WfxPl,
        float* __restrict__ bfx,
        _Float16* __restrict__ Wx2Ps, _Float16* __restrict__ Wx2Pl,
        _Float16* __restrict__ WfPs, _Float16* __restrict__ WfPl,
        _Float16* __restrict__ EmPs, _Float16* __restrict__ EmPl,
        float* __restrict__ s2p, float* __restrict__ bep,
        float* __restrict__ w0) {
    __shared__ __align__(16) char smem[16384];
    int id = blockIdx.x;
    int t = threadIdx.x;
    if (id < 1560) {
        // ---- splitwf2: Wf2 -> packed hi/lo (half8 stores) + w0 partials ----
        int bx = id % NCW, by = id / NCW;       // by in [0,8)
        int jl = t >> 2, e8 = t & 3;
        int j = by * 64 + jl;
        int d0 = bx * 32 + e8 * 8;
        float4 v0 = *(const float4*)&Wf2[(size_t)j * ED + d0];
        float4 v1 = *(const float4*)&Wf2[(size_t)j * ED + d0 + 4];
        float4 b0 = *(const float4*)&bf2[d0];
        float4 b1 = *(const float4*)&bf2[d0 + 4];
        float vv[8] = {v0.x, v0.y, v0.z, v0.w, v1.x, v1.y, v1.z, v1.w};
        float bb[8] = {b0.x, b0.y, b0.z, b0.w, b1.x, b1.y, b1.z, b1.w};
        half8 hh, ll;
        float s = 0.f;
        #pragma unroll
        for (int e = 0; e < 8; ++e) {
            float v = vv[e];
            _Float16 hi = (_Float16)v;
            hh[e] = hi;
            ll[e] = (_Float16)(v - (float)hi);
            s = fmaf(v, bb[e], s);
        }
        size_t a = paddr(j >> 4, NCW, bx, e8 * 16 + (j & 15), 0);
        *(half8*)(WfPs + a) = hh;
        *(half8*)(WfPl + a) = ll;
        s += __shfl_xor(s, 1);
        s += __shfl_xor(s, 2);
        if (e8 == 0) atomicAdd(&w0[j], s);
    } else if (id < 4680) {
        // ---- embt: embed transpose+split (half8 stores) ----
        float (*tile)[33] = (float(*)[33])smem; // tile[di][ki]
        int sub = id - 1560;
        int bx = sub % NCW, by = sub / NCW;
        int dl = t >> 5, kl = t & 31;
        #pragma unroll
        for (int r = 0; r < 4; ++r)
            tile[dl + 8 * r][kl] = embed[(size_t)(bx * 32 + dl + 8 * r) * KN
                                         + by * 32 + kl];
        __syncthreads();
        if (t < 128) {
            int g = t >> 5, kl2 = t & 31;       // g: d-group 0..3
            int k = by * 32 + kl2;
            half8 hh, ll;
            #pragma unroll
            for (int e = 0; e < 8; ++e) {
                float v = tile[g * 8 + e][kl2];
                _Float16 hi = (_Float16)v;
                hh[e] = hi;
                ll[e] = (_Float16)(v - (float)hi);
            }
            size_t a = paddr(k >> 4, NCW, bx, g * 16 + (k & 15), 0);
            *(half8*)(EmPs + a) = hh;
            *(half8*)(EmPl + a) = ll;
        }
    } else if (id < 4808) {
        // ---- s2bep: deterministic s2/be partials (fixed-order, no atomics) ----
        float (*rs)[33] = (float(*)[33])smem;
        float (*rb)[33] = (float(*)[33])(smem + 8 * 33 * 4);
        int sub = id - 4680;
        int bx = sub % 16, by = sub / 16;
        int kl = t & 31, dl = t >> 5;
        int kb = bx * 32;
        int d0 = by * 780;
        float s = 0.f, b = 0.f;
        for (int d = d0 + dl; d < d0 + 780; d += 8) {
            float e = embed[(size_t)d * KN + kb + kl];
            s = fmaf(e, e, s);
            b = fmaf(bf2[d], e, b);
        }
        rs[dl][kl] = s; rb[dl][kl] = b;
        __syncthreads();
        if (t < 32) {
            float ss = 0.f, bb = 0.f;
            #pragma unroll
            for (int i = 0; i < 8; ++i) { ss += rs[i][t]; bb += rb[i][t]; }
            s2p[by * KN + kb + t] = ss;
            bep[by * KN + kb + t] = bb;
        }
    } else if (id < 5320) {
        // ---- xpack: x -> XPs/XPl ----
        float (*xt)[INC] = (float(*)[INC])smem;
        int m0 = (id - 4808) * 32;
        for (int i = t; i < 32 * (INC / 4); i += 256) {
            int row = i >> 5, c4 = (i & 31) << 2;
            *(float4*)&xt[row][c4] = *(const float4*)&x[(size_t)(m0 + row) * INC + c4];
        }
        __syncthreads();
        int ta = m0 >> 4;
        #pragma unroll
        for (int i = 0; i < 2; ++i) {
            int idx = t + 256 * i;
            int tile2 = idx >> 8;
            int c = (idx >> 6) & 3;
            int lane = idx & 63;
            int m = tile2 * 16 + (lane & 15);
            int d0 = c * 32 + ((lane >> 4) << 3);
            half8 hh, ll;
            #pragma unroll
            for (int e = 0; e < 8; ++e) {
                float v = xt[m][d0 + e];
                _Float16 hi = (_Float16)v;
                hh[e] = hi;
                ll[e] = (_Float16)(v - (float)hi);
            }
            *(half8*)(XPs + paddr(ta + tile2, 4, c, lane, 0)) = hh;
            *(half8*)(XPl + paddr(ta + tile2, 4, c, lane, 0)) = ll;
        }
    } else if (id < 5384) {
        // ---- wfxpack: fused Wf1|Wx1 cols + bfx ----
        int tile = id - 5320;
        for (int i = t; i < 2048; i += 256) {
            int c = i >> 9, lane = (i >> 3) & 63, e = i & 7;
            int n = tile * 16 + (lane & 15);
            int d = c * 32 + ((lane >> 4) << 3) + e;
            float v = (n < 512) ? Wf1[(size_t)d * CH + n] : Wx1[(size_t)d * CH + n - 512];
            _Float16 hi = (_Float16)v;
            size_t a = paddr(tile, 4, c, lane, e);
            WfxPs[a] = hi;
            WfxPl[a] = (_Float16)(v - (float)hi);
        }
        if (tile == 0)
            for (int j = t; j < 512; j += 256) { bfx[j] = bf1[j]; bfx[512 + j] = bx1[j]; }
    } else {
        // ---- wx2pack ----
        int tile = id - 5384;
        for (int i = t; i < 8192; i += 256) {
            int c = i >> 9, lane = (i >> 3) & 63, e = i & 7;
            int n = tile * 16 + (lane & 15);
            int d = c * 32 + ((lane >> 4) << 3) + e;
            float v = Wx2[(size_t)d * DIN + n];
            _Float16 hi = (_Float16)v;
            size_t a = paddr(tile, 16, c, lane, e);
            Wx2Ps[a] = hi;
            Wx2Pl[a] = (_Float16)(v - (float)hi);
        }
    }
}

// ---------------------------------------------------------------------------
// Merged precompute GEMMs (R19): grid (4,4,32), block 512 -> 512 blocks =
// 2 blocks/CU. Work-balanced z-split: z<24 -> We slice (3-pass); z>=24 ->
// G slice (1-pass). Partials: (24+8) MB = 32 MB.
// ---------------------------------------------------------------------------
__global__ __launch_bounds__(512) void mfma_weg_kernel(
        const _Float16* __restrict__ WfPs, const _Float16* __restrict__ WfPl,
        const _Float16* __restrict__ EmPs, const _Float16* __restrict__ EmPl,
        float* __restrict__ WeP, float* __restrict__ GP) {
    int t = threadIdx.x;
    int w = t >> 6, L = t & 63;
    int lane16 = L & 15, quad = L >> 4;
    int m0 = blockIdx.x * 128 + (w & 3) * 32;
    int n0 = blockIdx.y * 128 + (w >> 2) * 64;
    int ta = m0 >> 4, tb = n0 >> 4;
    int zraw = blockIdx.z;
    bool isWe = zraw < NZWE;
    int z, c0, cnt;
    if (isWe) {
        z = zraw;
        int base = NCW / NZWE, rem = NCW % NZWE;    // 8, 3
        c0 = z * base + (z < rem ? z : rem);
        cnt = base + (z < rem ? 1 : 0);
    } else {
        z = zraw - NZWE;
        int base = NCW / NZG, rem = NCW % NZG;      // 24, 3
        c0 = z * base + (z < rem ? z : rem);
        cnt = base + (z < rem ? 1 : 0);
    }
    f32x4 acc[2][4];
    #pragma unroll
    for (int rt = 0; rt < 2; ++rt)
        #pragma unroll
        for (int tt = 0; tt < 4; ++tt) acc[rt][tt] = (f32x4){0.f, 0.f, 0.f, 0.f};
    if (isWe) {
        for (int ci = 0; ci < cnt; ++ci) {
            int c = c0 + ci;
            size_t oa0 = paddr(ta, NCW, c, L, 0), oa1 = paddr(ta + 1, NCW, c, L, 0);
            half8 A0h = *(const half8*)(WfPs + oa0);
            half8 A0l = *(const half8*)(WfPl + oa0);
            half8 A1h = *(const half8*)(WfPs + oa1);
            half8 A1l = *(const half8*)(WfPl + oa1);
            #pragma unroll
            for (int tt = 0; tt < 4; ++tt) {
                size_t ob = paddr(tb + tt, NCW, c, L, 0);
                half8 Bh = *(const half8*)(EmPs + ob);
                half8 Bl8 = *(const half8*)(EmPl + ob);
                acc[0][tt] = MFMA16(A0h, Bl8, MFMA16(A0l, Bh, MFMA16(A0h, Bh, acc[0][tt])));
                acc[1][tt] = MFMA16(A1h, Bl8, MFMA16(A1l, Bh, MFMA16(A1h, Bh, acc[1][tt])));
            }
        }
    } else {
        for (int ci = 0; ci < cnt; ++ci) {
            int c = c0 + ci;
            half8 A0h = *(const half8*)(WfPs + paddr(ta, NCW, c, L, 0));
            half8 A1h = *(const half8*)(WfPs + paddr(ta + 1, NCW, c, L, 0));
            #pragma unroll
            for (int tt = 0; tt < 4; ++tt) {
                half8 Bh = *(const half8*)(WfPs + paddr(tb + tt, NCW, c, L, 0));
                acc[0][tt] = MFMA16(A0h, Bh, acc[0][tt]);
                acc[1][tt] = MFMA16(A1h, Bh, acc[1][tt]);
            }
        }
    }
    float* C = (isWe ? WeP : GP) + (size_t)z * KN * KN;
    #pragma unroll
    for (int rt = 0; rt < 2; ++rt)
        #pragma unroll
        for (int tt = 0; tt < 4; ++tt)
            #pragma unroll
            for (int r = 0; r < 4; ++r)
                C[(size_t)(m0 + rt * 16 + quad * 4 + r) * KN
                  + n0 + tt * 16 + lane16] = acc[rt][tt][r];
}

// ---------------------------------------------------------------------------
// Merged reducers (R23): blocks [0,1024) wepack (24 partials, fixed order ->
// deterministic; writes the hi/lo pair INTERLEAVED into one buffer WeI:
// hi half8 at base*16, lo half8 at base*16+8); [1024,2048) gred (8 partials,
// packs G to fp16-hi B-frags); block 2048 sbered.
// ---------------------------------------------------------------------------
__global__ __launch_bounds__(256) void wepackgred_kernel(
        const float* __restrict__ WeP, const float* __restrict__ GP,
        const float* __restrict__ s2p, const float* __restrict__ bep,
        _Float16* __restrict__ WeI,
        _Float16* __restrict__ GhPs, float* __restrict__ s2,
        float* __restrict__ be) {
    int id = blockIdx.x;
    int t = threadIdx.x;
    if (id < 1024) {
        int g = id * 256 + t;                   // j*512 + k
        int j = g >> 9, k = g & 511;
        float v = 0.f;
        #pragma unroll
        for (int z = 0; z < NZWE; ++z) v += WeP[(size_t)z * KN * KN + g];
        _Float16 hi = (_Float16)v;
        size_t a = paddr(k >> 4, 16, j >> 5, ((j & 31) >> 3) * 16 + (k & 15), j & 7);
        size_t ab = a & ~(size_t)7;             // half8 base
        size_t e  = a & 7;
        WeI[2 * ab + e]     = hi;
        WeI[2 * ab + 8 + e] = (_Float16)(v - (float)hi);
    } else if (id < 2048) {
        int g = (id - 1024) * 256 + t;          // m*512 + n (G symmetric)
        int m = g >> 9, n = g & 511;
        float v = 0.f;
        #pragma unroll
        for (int z = 0; z < NZG; ++z) v += GP[(size_t)z * KN * KN + g];
        GhPs[paddr(n >> 4, 16, m >> 5, ((m & 31) >> 3) * 16 + (n & 15), m & 7)]
            = (_Float16)v;
    } else {
        #pragma unroll
        for (int i = 0; i < 2; ++i) {
            int k = t + 256 * i;
            float s = 0.f, b = 0.f;
            #pragma unroll
            for (int y = 0; y < 8; ++y) {
                s += s2p[y * KN + k];
                b += bep[y * KN + k];
            }
            s2[k] = s;
            be[k] = b;
        }
    }
}

// ---------------------------------------------------------------------------
// Fused MFMA encoder + SCORE + hGh (R26 = R25 with the score/hGh pipelines
// deepened to 2 (3-way static buffer rotation, steady vmcnt(16)/vmcnt(8))
// and the A-fragment ds_reads moved BEFORE the vmcnt wait so LDS latency
// overlaps the B-wait. Same values, same MFMA order -> bit-identical.
// ---------------------------------------------------------------------------
__global__ __launch_bounds__(512) void enc1_kernel(
        const _Float16* __restrict__ XPs, const _Float16* __restrict__ XPl,
        const _Float16* __restrict__ WfxPs, const _Float16* __restrict__ WfxPl,
        const float* __restrict__ bfx,
        const _Float16* __restrict__ Wx2Ps, const _Float16* __restrict__ Wx2Pl,
        const float* __restrict__ bx2,
        const _Float16* __restrict__ WeI,
        const _Float16* __restrict__ GhPs,
        const float* __restrict__ s2, const float* __restrict__ be,
        float* __restrict__ colsum,
        float* __restrict__ EX,
        int* __restrict__ ind, float* __restrict__ out_ind,
        int* __restrict__ counts, float* __restrict__ diffsum) {
    __shared__ _Float16 hhi[32][CHP];
    __shared__ _Float16 hlo[32][CHP];
    __shared__ float redv[8][32];
    __shared__ int   redi[8][32];
    __shared__ float fin[32];
    __shared__ float gpart[8];
    int t = threadIdx.x;
    int w = t >> 6, L = t & 63;
    int l16 = L & 15, quad = L >> 4;
    int m0 = blockIdx.x * 32;
    int ta = m0 >> 4;
    int enc = blockIdx.y;
    int n0 = enc * 512 + w * 64;
    int tb = n0 >> 4;
    f32x4 acc[2][4];
    #pragma unroll
    for (int rt = 0; rt < 2; ++rt)
        #pragma unroll
        for (int tt = 0; tt < 4; ++tt) acc[rt][tt] = (f32x4){0.f, 0.f, 0.f, 0.f};
    #pragma unroll
    for (int c = 0; c < 4; ++c) {
        size_t oa0 = paddr(ta, 4, c, L, 0), oa1 = paddr(ta + 1, 4, c, L, 0);
        half8 A0h = *(const half8*)(XPs + oa0);
        half8 A0l = *(const half8*)(XPl + oa0);
        half8 A1h = *(const half8*)(XPs + oa1);
        half8 A1l = *(const half8*)(XPl + oa1);
        #pragma unroll
        for (int tt = 0; tt < 4; ++tt) {
            size_t ob = paddr(tb + tt, 4, c, L, 0);
            half8 Bh = *(const half8*)(WfxPs + ob);
            half8 Bl8 = *(const half8*)(WfxPl + ob);
            acc[0][tt] = MFMA16(A0h, Bl8, MFMA16(A0l, Bh, MFMA16(A0h, Bh, acc[0][tt])));
            acc[1][tt] = MFMA16(A1h, Bl8, MFMA16(A1l, Bh, MFMA16(A1h, Bh, acc[1][tt])));
        }
    }
    #pragma unroll
    for (int rt = 0; rt < 2; ++rt)
        #pragma unroll
        for (int tt = 0; tt < 4; ++tt) {
            int col = w * 64 + tt * 16 + l16;
            float bias = bfx[enc * 512 + col];
            #pragma unroll
            for (int r = 0; r < 4; ++r) {
                int row = rt * 16 + quad * 4 + r;
                float v = fmaxf(acc[rt][tt][r] + bias, 0.f);
                _Float16 hi = (_Float16)v;
                hhi[row][col] = hi;
                hlo[row][col] = (_Float16)(v - (float)hi);
            }
        }
    __syncthreads();
    if (enc == 0) {
        float s = 0.f;
        #pragma unroll
        for (int r = 0; r < 32; ++r) s += (float)hhi[r][t] + (float)hlo[r][t];
        atomicAdd(&colsum[t], s);
        int colbase = w * 64;
        int tbs = w * 4;
        float cks[4];
        #pragma unroll
        for (int tt = 0; tt < 4; ++tt) {
            int c = colbase + tt * 16 + l16;
            cks[tt] = 0.5f * s2[c] - be[c];
        }
        #pragma unroll
        for (int rt = 0; rt < 2; ++rt)
            #pragma unroll
            for (int tt = 0; tt < 4; ++tt) acc[rt][tt] = (f32x4){0.f, 0.f, 0.f, 0.f};
        const _Float16* hA0 = &hhi[l16][quad << 3];
        const _Float16* lA0 = &hlo[l16][quad << 3];
        const _Float16* hA1 = &hhi[16 + l16][quad << 3];
        const _Float16* lA1 = &hlo[16 + l16][quad << 3];
        // ---- score loop: asm-pinned 2-deep pipeline, counted vmcnt ----
        const char* bbase[4];
        #pragma unroll
        for (int tt = 0; tt < 4; ++tt)
            bbase[tt] = (const char*)WeI
                        + (((size_t)(tbs + tt) * 16 * 64 + L) * 32);
        f32x4 BhA[4], BlA[4], BhB[4], BlB[4], BhC[4], BlC[4];
        #pragma unroll
        for (int tt = 0; tt < 4; ++tt) {            // prologue: issue c=0
            GLOAD16(BhA[tt], bbase[tt]);
            GLOAD16(BlA[tt], bbase[tt] + 16);
        }
        #pragma unroll
        for (int tt = 0; tt < 4; ++tt) {            // prologue: issue c=1
            GLOAD16(BhB[tt], bbase[tt] + 2048);
            GLOAD16(BlB[tt], bbase[tt] + 2048 + 16);
        }
        #pragma unroll
        for (int c = 0; c < 16; ++c) {
            f32x4 *curh, *curl, *nh, *nl;
            if (c % 3 == 0)      { curh = BhA; curl = BlA; nh = BhC; nl = BlC; }
            else if (c % 3 == 1) { curh = BhB; curl = BlB; nh = BhA; nl = BlA; }
            else                 { curh = BhC; curl = BlC; nh = BhB; nl = BlB; }
            if (c < 14) {
                #pragma unroll
                for (int tt = 0; tt < 4; ++tt) {
                    const char* p = bbase[tt] + (size_t)(c + 2) * 2048;
                    GLOAD16(nh[tt], p);
                    GLOAD16(nl[tt], p + 16);
                }
            }
            int d0 = c * 32;
            half8 A0h = *(const half8*)(hA0 + d0);   // ds_reads before vmcnt:
            half8 A0l = *(const half8*)(lA0 + d0);   // LDS latency overlaps B-wait
            half8 A1h = *(const half8*)(hA1 + d0);
            half8 A1l = *(const half8*)(lA1 + d0);
            if (c < 14)       asm volatile("s_waitcnt vmcnt(16)" ::: "memory");
            else if (c == 14) asm volatile("s_waitcnt vmcnt(8)"  ::: "memory");
            else              asm volatile("s_waitcnt vmcnt(0)"  ::: "memory");
            __builtin_amdgcn_sched_barrier(0);
            #pragma unroll
            for (int tt = 0; tt < 4; ++tt) {
                half8 Bh  = __builtin_bit_cast(half8, curh[tt]);
                half8 Bl8 = __builtin_bit_cast(half8, curl[tt]);
                acc[0][tt] = MFMA16(A0h, Bl8, MFMA16(A0l, Bh, MFMA16(A0h, Bh, acc[0][tt])));
                acc[1][tt] = MFMA16(A1h, Bl8, MFMA16(A1l, Bh, MFMA16(A1h, Bh, acc[1][tt])));
            }
        }
        #pragma unroll
        for (int rt = 0; rt < 2; ++rt) {
            #pragma unroll
            for (int r = 0; r < 4; ++r) {
                float mv = cks[0] - acc[rt][0][r];
                int mi = colbase + l16;
                #pragma unroll
                for (int tt = 1; tt < 4; ++tt) {
                    float v = cks[tt] - acc[rt][tt][r];
                    int c = colbase + tt * 16 + l16;
                    if (v < mv || (v == mv && c < mi)) { mv = v; mi = c; }
                }
                #pragma unroll
                for (int d = 1; d < 16; d <<= 1) {
                    float ov = __shfl_xor(mv, d);
                    int oi = __shfl_xor(mi, d);
                    if (ov < mv || (ov == mv && oi < mi)) { mv = ov; mi = oi; }
                }
                if (l16 == 0) {
                    int row = rt * 16 + quad * 4 + r;
                    redv[w][row] = mv; redi[w][row] = mi;
                }
            }
        }
        // ---- hGh pass: asm-pinned 2-deep pipeline, counted vmcnt ----
        #pragma unroll
        for (int rt = 0; rt < 2; ++rt)
            #pragma unroll
            for (int tt = 0; tt < 4; ++tt) acc[rt][tt] = (f32x4){0.f, 0.f, 0.f, 0.f};
        const char* gbase[4];
        #pragma unroll
        for (int tt = 0; tt < 4; ++tt)
            gbase[tt] = (const char*)GhPs
                        + (((size_t)(tbs + tt) * 16 * 64 + L) * 16);
        f32x4 GhA4[4], GhB4[4], GhC4[4];
        #pragma unroll
        for (int tt = 0; tt < 4; ++tt)              // prologue: issue c=0
            GLOAD16(GhA4[tt], gbase[tt]);
        #pragma unroll
        for (int tt = 0; tt < 4; ++tt)              // prologue: issue c=1
            GLOAD16(GhB4[tt], gbase[tt] + 1024);
        #pragma unroll
        for (int c = 0; c < 16; ++c) {
            f32x4 *g4, *n4;
            if (c % 3 == 0)      { g4 = GhA4; n4 = GhC4; }
            else if (c % 3 == 1) { g4 = GhB4; n4 = GhA4; }
            else                 { g4 = GhC4; n4 = GhB4; }
            if (c < 14) {
                #pragma unroll
                for (int tt = 0; tt < 4; ++tt)
                    GLOAD16(n4[tt], gbase[tt] + (size_t)(c + 2) * 1024);
            }
            int d0 = c * 32;
            half8 A0h = *(const half8*)(hA0 + d0);
            half8 A1h = *(const half8*)(hA1 + d0);
            if (c < 14)       asm volatile("s_waitcnt vmcnt(8)" ::: "memory");
            else if (c == 14) asm volatile("s_waitcnt vmcnt(4)" ::: "memory");
            else              asm volatile("s_waitcnt vmcnt(0)" ::: "memory");
            __builtin_amdgcn_sched_barrier(0);
            #pragma unroll
            for (int tt = 0; tt < 4; ++tt) {
                half8 Gh = __builtin_bit_cast(half8, g4[tt]);
                acc[0][tt] = MFMA16(A0h, Gh, acc[0][tt]);
                acc[1][tt] = MFMA16(A1h, Gh, acc[1][tt]);
            }
        }
        float gs = 0.f;
        #pragma unroll
        for (int rt = 0; rt < 2; ++rt)
            #pragma unroll
            for (int tt = 0; tt < 4; ++tt) {
                int col = colbase + tt * 16 + l16;
                #pragma unroll
                for (int r = 0; r < 4; ++r) {
                    int row = rt * 16 + quad * 4 + r;
                    gs += acc[rt][tt][r] * (float)hhi[row][col];
                }
            }
        #pragma unroll
        for (int d = 1; d < 64; d <<= 1) gs += __shfl_xor(gs, d);
        if (L == 0) gpart[w] = gs;
        __syncthreads();
        if (t < 32) {
            float mv = redv[0][t]; int mi = redi[0][t];
            #pragma unroll
            for (int w2 = 1; w2 < 8; ++w2) {
                float ov = redv[w2][t]; int oi = redi[w2][t];
                if (ov < mv || (ov == mv && oi < mi)) { mv = ov; mi = oi; }
            }
            int b = m0 + t;
            ind[b] = mi;
            out_ind[b] = (float)mi;
            atomicAdd(&counts[mi], 1);
            fin[t] = 2.f * mv;
        }
        __syncthreads();
        if (t == 0) {
            float s = 0.f;
            #pragma unroll
            for (int i = 0; i < 32; ++i) s += fin[i];
            #pragma unroll
            for (int w2 = 0; w2 < 8; ++w2) s += gpart[w2];
            atomicAdd(diffsum, s);
        }
    } else {
        int rt = w & 1, ct = w >> 1;
        f32x4 eacc = (f32x4){0.f, 0.f, 0.f, 0.f};
        for (int c = 0; c < 16; ++c) {
            int d0 = c * 32 + (quad << 3);
            int m = rt * 16 + l16;
            half8 Ah = *(half8*)(&hhi[m][d0]);
            half8 Al = *(half8*)(&hlo[m][d0]);
            size_t ob = paddr(ct, 16, c, L, 0);
            half8 Bh = *(const half8*)(Wx2Ps + ob);
            half8 Bl8 = *(const half8*)(Wx2Pl + ob);
            eacc = MFMA16(Ah, Bl8, MFMA16(Al, Bh, MFMA16(Ah, Bh, eacc)));
        }
        int col = ct * 16 + l16;
        float bias = bx2[col];
        #pragma unroll
        for (int r = 0; r < 4; ++r) {
            int row = m0 + rt * 16 + quad * 4 + r;
            EX[(size_t)row * DIN + col] = eacc[r] + bias;
        }
    }
}

// ---------------------------------------------------------------------------
// Scatter (R22): Hillis-Steele parallel prefix scan over counts (integer
// adds -> order-independent, bit-exact). Block-aggregated cursors.
// ---------------------------------------------------------------------------
__global__ __launch_bounds__(256) void scatter_kernel(const int* __restrict__ ind,
                                                      const int* __restrict__ counts,
                                                      int* __restrict__ cursors,
                                                      int* __restrict__ perm) {
    __shared__ int sc[KN], soff[KN], lcount[KN], lbase[KN], lcur[KN];
    int t = threadIdx.x;
    for (int i = t; i < KN; i += 256) {
        sc[i] = counts[i];
        lcount[i] = 0; lcur[i] = 0;
    }
    __syncthreads();
    // inclusive scan of sc[0..511], 2 elements/thread
    #pragma unroll
    for (int st = 1; st < KN; st <<= 1) {
        int i0 = t, i1 = t + 256;
        int v0 = (i0 >= st) ? sc[i0 - st] : 0;
        int v1 = (i1 >= st) ? sc[i1 - st] : 0;
        __syncthreads();
        sc[i0] += v0;
        sc[i1] += v1;
        __syncthreads();
    }
    #pragma unroll
    for (int half = 0; half < 2; ++half) {
        int i = t + 256 * half;
        soff[i] = (i == 0) ? 0 : sc[i - 1];
    }
    __syncthreads();
    int b = blockIdx.x * 256 + t;
    int k = ind[b];
    atomicAdd(&lcount[k], 1);
    __syncthreads();
    for (int i = t; i < KN; i += 256) {
        int c = lcount[i];
        if (c > 0) lbase[i] = atomicAdd(&cursors[i], c);
    }
    __syncthreads();
    int pos = soff[k] + lbase[k] + atomicAdd(&lcur[k], 1);
    perm[pos] = b;
}

// ---------------------------------------------------------------------------
// Decoder + fused finalize: blocks [0, BN/4) decode one wave per sample
// (load-balanced under histogram skew); block BN/4 runs finalize.
// ---------------------------------------------------------------------------
__global__ __launch_bounds__(256) void decode_kernel(const float* __restrict__ EX,
                                                     const int* __restrict__ perm,
                                                     const int* __restrict__ ind,
                                                     const float* __restrict__ W1,
                                                     const float* __restrict__ b1,
                                                     const float* __restrict__ W2,
                                                     const float* __restrict__ b2,
                                                     float* __restrict__ dec,
                                                     const int* __restrict__ counts,
                                                     const float* __restrict__ diffsum,
                                                     const float* __restrict__ colsum,
                                                     const float* __restrict__ w0,
                                                     const float* __restrict__ bf2,
                                                     float* __restrict__ out_diff,
                                                     float* __restrict__ out_perp) {
    if (blockIdx.x < BN / 4) {
        __shared__ float exs[4][DIN];
        __shared__ float h2s[4][DH];
        int t = threadIdx.x;
        int w = t >> 6, l = t & 63;
        int s = blockIdx.x * 4 + w;
        int b = perm[s];
        int k = ind[b];
        exs[w][l] = EX[(size_t)b * DIN + l];
        __syncthreads();
        const float* w1 = W1 + (size_t)k * (DIN * DH);
        float h = b1[(size_t)k * DH + l];
        #pragma unroll
        for (int j = 0; j < DIN; ++j)
            h = fmaf(exs[w][j], w1[(size_t)j * DH + l], h);
        h2s[w][l] = fmaxf(h, 0.f);
        __syncthreads();
        if (l < DY) {
            const float* w2 = W2 + (size_t)k * (DH * DY);
            float d = b2[(size_t)k * DY + l];
            #pragma unroll
            for (int j = 0; j < DH; ++j)
                d = fmaf(h2s[w][j], w2[(size_t)j * DY + l], d);
            dec[(size_t)b * DY + l] = d;
        }
        return;
    }
    // ---- finalize (single block) ----
    __shared__ float sf[256];
    int t = threadIdx.x;
    float term = 0.f, dotp = 0.f, bbp = 0.f;
    #pragma unroll
    for (int i = 0; i < 2; ++i) {
        int k = t + 256 * i;
        int c = counts[k];
        double p = (double)c / (double)BN;
        term += (float)(-p * log(p + 1e-10));
        dotp += colsum[k] * w0[k];
    }
    for (int d = t; d < ED; d += 256) { float v = bf2[d]; bbp = fmaf(v, v, bbp); }
    sf[t] = dotp; __syncthreads();
    for (int s = 128; s > 0; s >>= 1) { if (t < s) sf[t] += sf[t + s]; __syncthreads(); }
    float dot_all = sf[0];
    __syncthreads();
    sf[t] = bbp; __syncthreads();
    for (int s = 128; s > 0; s >>= 1) { if (t < s) sf[t] += sf[t + s]; __syncthreads(); }
    float bb = sf[0];
    __syncthreads();
    sf[t] = term; __syncthreads();
    for (int s = 128; s > 0; s >>= 1) { if (t < s) sf[t] += sf[t + s]; __syncthreads(); }
    if (t == 0) {
        *out_perp = expf(sf[0]);
        *out_diff = (diffsum[0] + 2.f * dot_all + (float)BN * bb) /
                    ((float)BN * (float)ED);
    }
}

// ---------------------------------------------------------------------------
extern "C" void kernel_launch(void* const* d_in, const int* in_sizes, int n_in,
                              void* d_out, int out_size, void* d_ws, size_t ws_size,
                              hipStream_t stream) {
    const float* x     = (const float*)d_in[0];
    const float* Wf1   = (const float*)d_in[1];
    const float* bf1   = (const float*)d_in[2];
    const float* Wf2   = (const float*)d_in[3];
    const float* bf2   = (const float*)d_in[4];
    const float* Wx1   = (const float*)d_in[5];
    const float* bx1   = (const float*)d_in[6];
    const float* Wx2   = (const float*)d_in[7];
    const float* bx2   = (const float*)d_in[8];
    const float* embed = (const float*)d_in[9];
    const float* W1    = (const float*)d_in[10];
    const float* b1    = (const float*)d_in[11];
    const float* W2    = (const float*)d_in[12];
    const float* b2    = (const float*)d_in[13];
    float* out = (float*)d_out;

    char* ws = (char*)d_ws;
    size_t off = 0;
    auto carve = [&](size_t bytes) -> void* {
        void* p = ws + off;
        off += (bytes + 255) & ~(size_t)255;
        return p;
    };
    _Float16* XPs   = (_Float16*)carve((size_t)BN * INC * 2);    // 4.2 MB
    _Float16* XPl   = (_Float16*)carve((size_t)BN * INC * 2);
    _Float16* WfxPs = (_Float16*)carve((size_t)1024 * INC * 2);
    _Float16* WfxPl = (_Float16*)carve((size_t)1024 * INC * 2);
    float*    bfx   = (float*)carve(1024 * 4);
    _Float16* Wx2Ps = (_Float16*)carve((size_t)DIN * CH * 2);
    _Float16* Wx2Pl = (_Float16*)carve((size_t)DIN * CH * 2);
    _Float16* WfPs  = (_Float16*)carve((size_t)CH * ED * 2);     // 6.4 MB
    _Float16* WfPl  = (_Float16*)carve((size_t)CH * ED * 2);
    _Float16* EmPs  = (_Float16*)carve((size_t)KN * ED * 2);
    _Float16* EmPl  = (_Float16*)carve((size_t)KN * ED * 2);
    // WeP[24] + GP[8] partial buffers (32 MB, dead after wepackgred).
    float*    WeP = (float*)carve((size_t)(NZWE + NZG) * KN * KN * 4);
    float*    GP  = WeP + (size_t)NZWE * KN * KN;
    _Float16* WeI  = (_Float16*)carve((size_t)KN * CH * 4);      // 1 MB interleaved hi|lo
    _Float16* GhPs = (_Float16*)carve((size_t)KN * KN * 2);      // 0.5 MB
    float*    EX   = (float*)carve((size_t)BN * DIN * 4);        // 4.2 MB
    float*    s2p  = (float*)carve(8 * KN * 4);
    float*    bep  = (float*)carve(8 * KN * 4);
    float*    s2   = (float*)carve(KN * 4);
    float*    be   = (float*)carve(KN * 4);
    char* zbase = ws + off;                                      // ---- zero region ----
    float* w0    = (float*)carve(CH * 4);
    float* colsum= (float*)carve(CH * 4);
    int*   counts= (int*)carve(KN * 4);
    int*   cursors=(int*)carve(KN * 4);
    float* diffsum=(float*)carve(256);
    size_t zbytes = (size_t)(ws + off - zbase);                  // ---- end zero region ----
    int*   ind     = (int*)carve(BN * 4);
    int*   perm    = (int*)carve(BN * 4);
    (void)in_sizes; (void)n_in; (void)out_size; (void)ws_size;

    hipMemsetAsync(zbase, 0, zbytes, stream);
    packall_kernel<<<5388, 256, 0, stream>>>(x, Wf1, Wx1, bf1, bx1, Wx2, Wf2, bf2,
                                             embed, XPs, XPl, WfxPs, WfxPl, bfx,
                                             Wx2Ps, Wx2Pl, WfPs, WfPl, EmPs, EmPl,
                                             s2p, bep, w0);
    mfma_weg_kernel<<<dim3(4, 4, NZWE + NZG), 512, 0, stream>>>(WfPs, WfPl,
                                                                EmPs, EmPl,
                                                                WeP, GP);
    wepackgred_kernel<<<2049, 256, 0, stream>>>(WeP, GP, s2p, bep,
                                                WeI, GhPs, s2, be);
    enc1_kernel<<<dim3(BN / 32, 2), 512, 0, stream>>>(XPs, XPl, WfxPs, WfxPl, bfx,
                                                      Wx2Ps, Wx2Pl, bx2,
                                                      WeI, GhPs, s2, be,
                                                      colsum, EX,
                                                      ind, out + OUT_IND, counts,
                                                      diffsum);
    scatter_kernel<<<BN / 256, 256, 0, stream>>>(ind, counts, cursors, perm);
    decode_kernel<<<BN / 4 + 1, 256, 0, stream>>>(EX, perm, ind, W1, b1, W2, b2,
                                                  out + OUT_DEC,
                                                  counts, diffsum, colsum, w0, bf2,
                                                  out + OUT_DIFF, out + OUT_PERP);
}